// Round 3
// baseline (9256.181 us; speedup 1.0000x reference)
//
#include <hip/hip_runtime.h>
#include <hip/hip_bf16.h>

typedef __hip_bfloat16 bf16;

#define T_  1024
#define D_  2048
#define H_  32
#define HD_ 64

static const size_t TT_ = (size_t)T_ * T_;
static const size_t TD_ = (size_t)T_ * D_;

__device__ __forceinline__ float toF(float x) { return x; }
__device__ __forceinline__ float toF(bf16 x) { return __bfloat162float(x); }

template <typename T> __device__ __forceinline__ T fromF(float v);
template <> __device__ __forceinline__ float fromF<float>(float v) { return v; }
template <> __device__ __forceinline__ bf16 fromF<bf16>(float v) { return __float2bfloat16(v); }

typedef __attribute__((ext_vector_type(8))) short frag8;
typedef __attribute__((ext_vector_type(4))) float f32x4;

// ---------------------------------------------------------------------------
// MFMA GEMM: C[M,N] f32 = A[M,K]bf16 @ Bt[N,K]bf16^T. 128x128 tile, BK=32,
// 4 waves (2x2 of 64x64), global_load_lds 16B staging, 16x16x32 bf16 MFMA.
// M,N multiples of 128; K multiple of 32.
// ---------------------------------------------------------------------------
__global__ __launch_bounds__(256) void mfma_gemm(
    const bf16* __restrict__ A, const bf16* __restrict__ Bt,
    float* __restrict__ C, int M, int N, int K)
{
    __shared__ short Al[128 * 32];
    __shared__ short Bl[128 * 32];
    int tid = threadIdx.x;
    int w = tid >> 6, l = tid & 63;
    int row0 = blockIdx.y * 128, col0 = blockIdx.x * 128;
    int mq = (w >> 1) * 64, nq = (w & 1) * 64;
    int lm = l & 15, kq = l >> 4;
    f32x4 acc[4][4] = {};
    const bf16* Ap = A + (size_t)row0 * K;
    const bf16* Bp = Bt + (size_t)col0 * K;
    for (int kk = 0; kk < K; kk += 32) {
        __syncthreads();
#pragma unroll
        for (int r = 0; r < 2; r++) {
            int c = r * 256 + w * 64 + l;
            int row = c >> 2, kc = (c & 3) * 8;
            const bf16* ga = Ap + (size_t)row * K + kk + kc;
            const bf16* gb = Bp + (size_t)row * K + kk + kc;
            short* la = Al + (size_t)(r * 256 + w * 64) * 8;
            short* lb = Bl + (size_t)(r * 256 + w * 64) * 8;
            __builtin_amdgcn_global_load_lds((const __attribute__((address_space(1))) void*)ga,
                                             (__attribute__((address_space(3))) void*)la, 16, 0, 0);
            __builtin_amdgcn_global_load_lds((const __attribute__((address_space(1))) void*)gb,
                                             (__attribute__((address_space(3))) void*)lb, 16, 0, 0);
        }
        __builtin_amdgcn_s_waitcnt(0);
        __syncthreads();
        frag8 af[4], bfg[4];
#pragma unroll
        for (int i = 0; i < 4; i++)
            af[i] = *(const frag8*)&Al[(size_t)(mq + i * 16 + lm) * 32 + kq * 8];
#pragma unroll
        for (int j = 0; j < 4; j++)
            bfg[j] = *(const frag8*)&Bl[(size_t)(nq + j * 16 + lm) * 32 + kq * 8];
#pragma unroll
        for (int i = 0; i < 4; i++)
#pragma unroll
            for (int j = 0; j < 4; j++)
                acc[i][j] = __builtin_amdgcn_mfma_f32_16x16x32_bf16(af[i], bfg[j], acc[i][j], 0, 0, 0);
    }
#pragma unroll
    for (int i = 0; i < 4; i++)
#pragma unroll
        for (int j = 0; j < 4; j++)
#pragma unroll
            for (int r = 0; r < 4; r++) {
                int row = row0 + mq + i * 16 + kq * 4 + r;
                int col = col0 + nq + j * 16 + lm;
                C[(size_t)row * N + col] = acc[i][j][r];
            }
}

// ---------------------------------------------------------------------------
// transpose + convert: Wt[n][k] = (bf16) W[k][n].  R=rows(K), Cc=cols(N).
// ---------------------------------------------------------------------------
__global__ void transpose_convert(const float* __restrict__ W, bf16* __restrict__ Wt,
                                  int R, int Cc)
{
    __shared__ float tile[32][33];
    int bx = blockIdx.x * 32, by = blockIdx.y * 32;
    int tx = threadIdx.x, ty = threadIdx.y;
    for (int i = ty; i < 32; i += 8)
        tile[i][tx] = W[(size_t)(by + i) * Cc + bx + tx];
    __syncthreads();
    for (int i = ty; i < 32; i += 8)
        Wt[(size_t)(bx + i) * R + by + tx] = fromF<bf16>(tile[tx][i]);
}

__global__ void convert_bf16(const float* __restrict__ in, bf16* __restrict__ out, int n)
{
    int i = blockIdx.x * 256 + threadIdx.x;
    if (i < n) out[i] = fromF<bf16>(in[i]);
}

// ---------------------------------------------------------------------------
// Generic tiled f32 GEMM (kept for small/odd shapes): C[M,N] (+)= alpha*A@B
// ---------------------------------------------------------------------------
template <typename TA, typename TB, typename TC, bool ACC>
__global__ void gemm_tiled(int M, int N, int K,
                           const TA* __restrict__ A, int lda, size_t sA,
                           const TB* __restrict__ B, int ldb, size_t sB,
                           TC* __restrict__ C, int ldc, size_t sC, float alpha)
{
    A += (size_t)blockIdx.z * sA;
    B += (size_t)blockIdx.z * sB;
    C += (size_t)blockIdx.z * sC;
    int row0 = blockIdx.y * 64, col0 = blockIdx.x * 64;
    __shared__ float As[16][68];
    __shared__ float Bs[16][68];
    int tid = threadIdx.x;
    int rb = (tid >> 4) << 2;
    int cb = (tid & 15) << 2;
    float acc[4][4] = {};
    for (int kk = 0; kk < K; kk += 16) {
        for (int i = tid; i < 1024; i += 256) {
            int m = i >> 4, k = i & 15;
            int gr = row0 + m, gk = kk + k;
            As[k][m] = (gr < M && gk < K) ? toF(A[(size_t)gr * lda + gk]) : 0.f;
        }
        for (int i = tid; i < 1024; i += 256) {
            int k = i >> 6, n = i & 63;
            int gk = kk + k, gc = col0 + n;
            Bs[k][n] = (gk < K && gc < N) ? toF(B[(size_t)gk * ldb + gc]) : 0.f;
        }
        __syncthreads();
#pragma unroll
        for (int k = 0; k < 16; k++) {
            float a[4], b[4];
#pragma unroll
            for (int j = 0; j < 4; j++) { a[j] = As[k][rb + j]; b[j] = Bs[k][cb + j]; }
#pragma unroll
            for (int i2 = 0; i2 < 4; i2++)
#pragma unroll
                for (int j = 0; j < 4; j++) acc[i2][j] += a[i2] * b[j];
        }
        __syncthreads();
    }
#pragma unroll
    for (int i2 = 0; i2 < 4; i2++) {
        int gr = row0 + rb + i2;
        if (gr >= M) continue;
#pragma unroll
        for (int j = 0; j < 4; j++) {
            int gc = col0 + cb + j;
            if (gc >= N) continue;
            float v = alpha * acc[i2][j];
            if (ACC) v += toF(C[(size_t)gr * ldc + gc]);
            C[(size_t)gr * ldc + gc] = fromF<TC>(v);
        }
    }
}

// ---------------------------------------------------------------------------
// pairdot3: one pass producing Lb = strict(w.w^T)*beta[s], Cm = strict(w.k^T),
// Em = causal(q.w^T)*beta[s]. Grid (T/32, T/32, NH), block 256.
// ---------------------------------------------------------------------------
__global__ void pairdot3(const float* __restrict__ qf, const float* __restrict__ kf,
                         const float* __restrict__ wf, const float* __restrict__ beta,
                         float* __restrict__ Lb, float* __restrict__ Cm,
                         float* __restrict__ Em, int headStart)
{
    int z = blockIdx.z;
    int head = headStart + z;
    size_t hoff = (size_t)head * HD_;
    int t0 = blockIdx.y * 32, s0 = blockIdx.x * 32;
    __shared__ float Wr[64][33], Qr[64][33], Wc[64][33], Kc[64][33];
    int tid = threadIdx.x;
    for (int i = tid; i < 2048; i += 256) {
        int r = i >> 6, k = i & 63;
        Wr[k][r] = wf[(size_t)(t0 + r) * D_ + hoff + k];
        Qr[k][r] = qf[(size_t)(t0 + r) * D_ + hoff + k];
        Wc[k][r] = wf[(size_t)(s0 + r) * D_ + hoff + k];
        Kc[k][r] = kf[(size_t)(s0 + r) * D_ + hoff + k];
    }
    __syncthreads();
    int row = tid >> 3;
    int cg = (tid & 7) << 2;
    float aL[4] = {}, aS[4] = {}, aE[4] = {};
#pragma unroll 8
    for (int k = 0; k < 64; k++) {
        float xw = Wr[k][row], xq = Qr[k][row];
#pragma unroll
        for (int j = 0; j < 4; j++) {
            float yw = Wc[k][cg + j], yk = Kc[k][cg + j];
            aL[j] += xw * yw;
            aS[j] += xw * yk;
            aE[j] += xq * yw;
        }
    }
    int t = t0 + row;
    size_t base = (size_t)z * TT_ + (size_t)t * T_;
#pragma unroll
    for (int j = 0; j < 4; j++) {
        int s = s0 + cg + j;
        float b = beta[(size_t)s * H_ + head];
        Lb[base + s] = (s < t) ? aL[j] * b : 0.f;
        Cm[base + s] = (s < t) ? aS[j] : 0.f;
        Em[base + s] = (s <= t) ? aE[j] * b : 0.f;
    }
}

// pairdot (unmasked) for Dqk
__global__ void pairdot(const float* __restrict__ X, const float* __restrict__ Y,
                        float* __restrict__ out, int headStart)
{
    int z = blockIdx.z;
    int head = headStart + z;
    size_t hoff = (size_t)head * HD_;
    int t0 = blockIdx.y * 32, s0 = blockIdx.x * 32;
    __shared__ float Xs[64][33];
    __shared__ float Ys[64][33];
    int tid = threadIdx.x;
    for (int i = tid; i < 2048; i += 256) {
        int r = i >> 6, k = i & 63;
        Xs[k][r] = X[(size_t)(t0 + r) * D_ + hoff + k];
        Ys[k][r] = Y[(size_t)(s0 + r) * D_ + hoff + k];
    }
    __syncthreads();
    int row = tid >> 3;
    int cg = (tid & 7) << 2;
    float acc[4] = {};
#pragma unroll 8
    for (int k = 0; k < 64; k++) {
        float x = Xs[k][row];
#pragma unroll
        for (int j = 0; j < 4; j++) acc[j] += x * Ys[k][cg + j];
    }
    float* orow = out + (size_t)z * TT_ + (size_t)(t0 + row) * T_;
#pragma unroll
    for (int j = 0; j < 4; j++) orow[s0 + cg + j] = acc[j];
}

// ---------------------------------------------------------------------------
// diag_inv: invert 64x64 unit-lower diagonal blocks of (I + Lb).
// ---------------------------------------------------------------------------
__global__ void diag_inv(const float* __restrict__ Lb, float* __restrict__ Minv)
{
    int bi = blockIdx.x, z = blockIdx.y;
    const float* Lh = Lb + (size_t)z * TT_;
    __shared__ float Nb[64][65];
    __shared__ float Xc[64][65];
    int tid = threadIdx.x;
    for (int i = tid; i < 4096; i += 64) {
        int r = i >> 6, c = i & 63;
        Nb[r][c] = Lh[(size_t)(bi * 64 + r) * T_ + bi * 64 + c];
    }
    __syncthreads();
    int j = tid;
    for (int t = 0; t < 64; t++) {
        float v = (t == j) ? 1.f : 0.f;
        for (int i = 0; i < t; i++) v -= Nb[t][i] * Xc[i][j];
        Xc[t][j] = v;
    }
    __syncthreads();
    float* Mo = Minv + ((size_t)z * 16 + bi) * 4096;
    for (int i = tid; i < 4096; i += 64) Mo[i] = Xc[i >> 6][i & 63];
}

// ---------------------------------------------------------------------------
// solve_step: fused update (triangular k-window) + Minv apply for block-row bi.
// Grid (bi+1, NH), block 256.
// ---------------------------------------------------------------------------
__global__ void solve_step(float* __restrict__ Cm, const float* __restrict__ Lb,
                           const float* __restrict__ Minv, int bi)
{
    int ct = blockIdx.x, z = blockIdx.y;
    float* Ch = Cm + (size_t)z * TT_;
    const float* Lh = Lb + (size_t)z * TT_;
    __shared__ float As[16][68];
    __shared__ float Bs[16][68];
    __shared__ float Cb[64][65];
    __shared__ float Mi[64][65];
    int tid = threadIdx.x;
    const float* Mo = Minv + ((size_t)z * 16 + bi) * 4096;
    for (int i = tid; i < 4096; i += 256) Mi[i >> 6][i & 63] = Mo[i];
    int rb = (tid >> 4) << 2;
    int cb = (tid & 15) << 2;
    float acc[4][4] = {};
    for (int kk = ct * 64; kk < bi * 64; kk += 16) {
        __syncthreads();
        for (int i = tid; i < 1024; i += 256) {
            int m = i >> 4, k = i & 15;
            As[k][m] = Lh[(size_t)(bi * 64 + m) * T_ + kk + k];
        }
        for (int i = tid; i < 1024; i += 256) {
            int k = i >> 6, n = i & 63;
            Bs[k][n] = Ch[(size_t)(kk + k) * T_ + ct * 64 + n];
        }
        __syncthreads();
#pragma unroll
        for (int k = 0; k < 16; k++) {
            float a[4], b[4];
#pragma unroll
            for (int j = 0; j < 4; j++) { a[j] = As[k][rb + j]; b[j] = Bs[k][cb + j]; }
#pragma unroll
            for (int i2 = 0; i2 < 4; i2++)
#pragma unroll
                for (int j = 0; j < 4; j++) acc[i2][j] += a[i2] * b[j];
        }
    }
    __syncthreads();
#pragma unroll
    for (int i2 = 0; i2 < 4; i2++)
#pragma unroll
        for (int j = 0; j < 4; j++)
            Cb[rb + i2][cb + j] =
                Ch[(size_t)(bi * 64 + rb + i2) * T_ + ct * 64 + cb + j] - acc[i2][j];
    __syncthreads();
    int col = tid & 63, rg = tid >> 6;
    float res[16];
    for (int rr = 0; rr < 16; rr++) {
        int row = rg * 16 + rr;
        float v = 0.f;
#pragma unroll 8
        for (int k = 0; k < 64; k++) v += Mi[row][k] * Cb[k][col];
        res[rr] = v;
    }
    for (int rr = 0; rr < 16; rr++) {
        int row = rg * 16 + rr;
        Ch[(size_t)(bi * 64 + row) * T_ + ct * 64 + col] = res[rr];
    }
}

// ---------------------------------------------------------------------------
// gemm_sub_causal: Ab[t,s] -= sum_k E[t,k]*C[k,s], lower tiles, k in [s0,t0+64)
// ---------------------------------------------------------------------------
__global__ void gemm_sub_causal(const float* __restrict__ E, const float* __restrict__ Cm,
                                float* __restrict__ Ab)
{
    int z = blockIdx.z;
    int t0 = blockIdx.y * 64, s0 = blockIdx.x * 64;
    if (s0 > t0) return;
    const float* Eh = E + (size_t)z * TT_;
    const float* Ch = Cm + (size_t)z * TT_;
    float* Ah = Ab + (size_t)z * TT_;
    __shared__ float As[16][68];
    __shared__ float Bs[16][68];
    int tid = threadIdx.x;
    int rb = (tid >> 4) << 2;
    int cb = (tid & 15) << 2;
    float acc[4][4] = {};
    int kEnd = t0 + 64;
    for (int kk = s0; kk < kEnd; kk += 16) {
        for (int i = tid; i < 1024; i += 256) {
            int m = i >> 4, k = i & 15;
            As[k][m] = Eh[(size_t)(t0 + m) * T_ + kk + k];
        }
        for (int i = tid; i < 1024; i += 256) {
            int k = i >> 6, n = i & 63;
            Bs[k][n] = Ch[(size_t)(kk + k) * T_ + s0 + n];
        }
        __syncthreads();
#pragma unroll
        for (int k = 0; k < 16; k++) {
            float a[4], b[4];
#pragma unroll
            for (int j = 0; j < 4; j++) { a[j] = As[k][rb + j]; b[j] = Bs[k][cb + j]; }
#pragma unroll
            for (int i2 = 0; i2 < 4; i2++)
#pragma unroll
                for (int j = 0; j < 4; j++) acc[i2][j] += a[i2] * b[j];
        }
        __syncthreads();
    }
#pragma unroll
    for (int i2 = 0; i2 < 4; i2++)
#pragma unroll
        for (int j = 0; j < 4; j++)
            Ah[(size_t)(t0 + rb + i2) * T_ + s0 + cb + j] -= acc[i2][j];
}

// ---------------------------------------------------------------------------
// small fused elementwise kernels
// ---------------------------------------------------------------------------
__global__ void bg_fuse(const float* __restrict__ hb, const float* __restrict__ hg,
                        const float* __restrict__ bbt, const float* __restrict__ bgp,
                        float* __restrict__ beta, float* __restrict__ G)
{
    int idx = blockIdx.x * 256 + threadIdx.x;
    if (idx >= T_ * H_) return;
    int hh = idx & (H_ - 1);
    float xb = hb[idx] + bbt[hh];
    beta[idx] = 2.f / (1.f + expf(-xb));
    float xg = hg[idx] + bgp[hh];
    G[idx] = (xg >= 0.f) ? -log1pf(expf(-xg)) : (xg - log1pf(expf(xg)));
}

__global__ void cumsum_g(float* __restrict__ G)
{
    int h = threadIdx.x;
    float acc = 0.f;
    for (int t = 0; t < T_; t++) {
        acc += G[(size_t)t * H_ + h];
        G[(size_t)t * H_ + h] = acc;
    }
}

__global__ void conv_silu_norm(const float* __restrict__ wr, const float* __restrict__ convw,
                               float* __restrict__ wf)
{
    int b = blockIdx.x;
    int t = b >> 5, h = b & 31;
    int d = threadIdx.x;
    int c = h * 64 + d;
    float c0 = convw[c * 3 + 0];
    float c1 = convw[c * 3 + 1];
    float c2 = convw[c * 3 + 2];
    float x = c2 * wr[(size_t)t * D_ + c];
    if (t >= 1) x += c1 * wr[(size_t)(t - 1) * D_ + c];
    if (t >= 2) x += c0 * wr[(size_t)(t - 2) * D_ + c];
    float y = x / (1.f + expf(-x));
    float ss = y * y;
    for (int off = 32; off > 0; off >>= 1) ss += __shfl_xor(ss, off, 64);
    wf[(size_t)t * D_ + c] = y * rsqrtf(ss);
}

__global__ void softmax_rows(float* __restrict__ Ab, const float* __restrict__ G, int headStart)
{
    int t = blockIdx.x, z = blockIdx.y;
    int head = headStart + z;
    float* row = Ab + (size_t)z * TT_ + (size_t)t * T_;
    int tid = threadIdx.x;
    int len = t + 1;
    float lv[4];
    int cnt = 0;
    float m = -1e30f;
    for (int s = tid; s < len; s += 256) {
        float l = row[s] * 0.125f - G[(size_t)s * H_ + head];
        lv[cnt++] = l;
        if (l > m) m = l;
    }
    __shared__ float red[256];
    red[tid] = m; __syncthreads();
    for (int off = 128; off > 0; off >>= 1) {
        if (tid < off) red[tid] = fmaxf(red[tid], red[tid + off]);
        __syncthreads();
    }
    m = red[0]; __syncthreads();
    float sum = 0.f;
    for (int i = 0; i < cnt; i++) { lv[i] = expf(lv[i] - m); sum += lv[i]; }
    red[tid] = sum; __syncthreads();
    for (int off = 128; off > 0; off >>= 1) {
        if (tid < off) red[tid] += red[tid + off];
        __syncthreads();
    }
    float inv = 1.f / red[0];
    cnt = 0;
    for (int s = tid; s < len; s += 256) row[s] = lv[cnt++] * inv;
    for (int s = len + tid; s < T_; s += 256) row[s] = 0.f;
}

// ---------------------------------------------------------------------------
extern "C" void kernel_launch(void* const* d_in, const int* in_sizes, int n_in,
                              void* d_out, int out_size, void* d_ws, size_t ws_size,
                              hipStream_t stream)
{
    const float* h     = (const float*)d_in[0];
    const float* Wq    = (const float*)d_in[1];
    const float* Wk    = (const float*)d_in[2];
    const float* Wv    = (const float*)d_in[3];
    const float* Ww1   = (const float*)d_in[4];
    const float* Ww2   = (const float*)d_in[5];
    const float* convw = (const float*)d_in[6];
    const float* Wbt   = (const float*)d_in[7];
    const float* bbt   = (const float*)d_in[8];
    const float* Wg    = (const float*)d_in[9];
    const float* bgp   = (const float*)d_in[10];
    const float* Wo    = (const float*)d_in[11];
    float* out = (float*)d_out;

    float* ws = (float*)d_ws;
    size_t off = 0;
    auto allocF = [&](size_t nf) { float* p = ws + off; off += (nf + 1023) & ~(size_t)1023; return p; };

    float* qf = allocF(TD_);
    float* kf = allocF(TD_);
    float* vf = allocF(TD_);
    float* wr = allocF(TD_);
    float* wf = allocF(TD_);
    float* of = allocF(TD_);
    float* w1 = allocF((size_t)T_ * 32);
    float* hb = allocF((size_t)T_ * 32);
    float* hg = allocF((size_t)T_ * 32);
    float* betaB = allocF((size_t)T_ * H_);
    float* Gb = allocF((size_t)T_ * H_);
    bf16* h_bf  = (bf16*)allocF(TD_ / 2);
    bf16* of_bf = (bf16*)allocF(TD_ / 2);
    bf16* Wt    = (bf16*)allocF((size_t)D_ * D_ / 2);   // reused for Wq/Wk/Wv/Wo

    size_t fixedF = off;
    size_t capF = ws_size / 4;
    size_t perHead = 3 * TT_ + (size_t)16 * 64 * 64 + 4096;
    int NH = 32;
    while (NH > 1 && fixedF + (size_t)NH * perHead > capF) NH >>= 1;
    float* Lb = allocF((size_t)NH * TT_);
    float* Cm = allocF((size_t)NH * TT_);
    float* Em = allocF((size_t)NH * TT_);
    float* Mv = allocF((size_t)NH * 16 * 64 * 64);

    dim3 blk(256);
    dim3 tcvB(32, 8);
    dim3 tcvG(D_ / 32, D_ / 32);
    dim3 mfmaG(D_ / 128, T_ / 128);

    // bf16 conversions + big projection GEMMs via MFMA
    convert_bf16<<<dim3((TD_ + 255) / 256), blk, 0, stream>>>(h, h_bf, (int)TD_);
    transpose_convert<<<tcvG, tcvB, 0, stream>>>(Wq, Wt, D_, D_);
    mfma_gemm<<<mfmaG, blk, 0, stream>>>(h_bf, Wt, qf, T_, D_, D_);
    transpose_convert<<<tcvG, tcvB, 0, stream>>>(Wk, Wt, D_, D_);
    mfma_gemm<<<mfmaG, blk, 0, stream>>>(h_bf, Wt, kf, T_, D_, D_);
    transpose_convert<<<tcvG, tcvB, 0, stream>>>(Wv, Wt, D_, D_);
    mfma_gemm<<<mfmaG, blk, 0, stream>>>(h_bf, Wt, vf, T_, D_, D_);

    // small projections (f32 VALU)
    gemm_tiled<float, float, float, false><<<dim3(1, 16, 1), blk, 0, stream>>>(
        T_, 32, D_, h, D_, 0, Ww1, 32, 0, w1, 32, 0, 1.f);
    gemm_tiled<float, float, float, false><<<dim3(32, 16, 1), blk, 0, stream>>>(
        T_, D_, 32, w1, 32, 0, Ww2, D_, 0, wr, D_, 0, 1.f);
    gemm_tiled<float, float, float, false><<<dim3(1, 16, 1), blk, 0, stream>>>(
        T_, 32, D_, h, D_, 0, Wbt, 32, 0, hb, 32, 0, 1.f);
    gemm_tiled<float, float, float, false><<<dim3(1, 16, 1), blk, 0, stream>>>(
        T_, 32, D_, h, D_, 0, Wg, 32, 0, hg, 32, 0, 1.f);
    bg_fuse<<<dim3((T_ * H_ + 255) / 256), blk, 0, stream>>>(hb, hg, bbt, bgp, betaB, Gb);
    cumsum_g<<<dim3(1), dim3(32), 0, stream>>>(Gb);
    conv_silu_norm<<<dim3(T_ * H_), dim3(64), 0, stream>>>(wr, convw, wf);

    int nChunks = H_ / NH;
    for (int c = 0; c < nChunks; c++) {
        int hs = c * NH;
        pairdot3<<<dim3(32, 32, NH), blk, 0, stream>>>(qf, kf, wf, betaB, Lb, Cm, Em, hs);
        diag_inv<<<dim3(16, NH), dim3(64), 0, stream>>>(Lb, Mv);
        for (int bi = 0; bi < 16; bi++)
            solve_step<<<dim3(bi + 1, NH), blk, 0, stream>>>(Cm, Lb, Mv, bi);
        pairdot<<<dim3(32, 32, NH), blk, 0, stream>>>(qf, kf, Lb, hs);
        gemm_sub_causal<<<dim3(16, 16, NH), blk, 0, stream>>>(Em, Cm, Lb);
        softmax_rows<<<dim3(T_, NH), blk, 0, stream>>>(Lb, Gb, hs);
        gemm_tiled<float, float, float, false><<<dim3(1, 16, NH), blk, 0, stream>>>(
            T_, 64, T_, Lb, T_, TT_,
            vf + (size_t)hs * 64, D_, 64,
            of + (size_t)hs * 64, D_, 64, 1.f);
    }

    // out = of @ Wo via MFMA
    convert_bf16<<<dim3((TD_ + 255) / 256), blk, 0, stream>>>(of, of_bf, (int)TD_);
    transpose_convert<<<tcvG, tcvB, 0, stream>>>(Wo, Wt, D_, D_);
    mfma_gemm<<<mfmaG, blk, 0, stream>>>(of_bf, Wt, out, T_, D_, D_);
}

// Round 4
// 6890.004 us; speedup vs baseline: 1.3434x; 1.3434x over previous
//
#include <hip/hip_runtime.h>
#include <hip/hip_bf16.h>

typedef __hip_bfloat16 bf16;

#define T_  1024
#define D_  2048
#define H_  32
#define HD_ 64

static const size_t TT_ = (size_t)T_ * T_;
static const size_t TD_ = (size_t)T_ * D_;

__device__ __forceinline__ float toF(float x) { return x; }
__device__ __forceinline__ float toF(bf16 x) { return __bfloat162float(x); }

template <typename T> __device__ __forceinline__ T fromF(float v);
template <> __device__ __forceinline__ float fromF<float>(float v) { return v; }
template <> __device__ __forceinline__ bf16 fromF<bf16>(float v) { return __float2bfloat16(v); }

typedef __attribute__((ext_vector_type(8))) short frag8;
typedef __attribute__((ext_vector_type(4))) float f32x4;

// ---------------------------------------------------------------------------
// MFMA GEMM: C[M,N] f32 = A[M,K]bf16 @ Bt[N,K]bf16^T. 128x128 tile, BK=32.
// ---------------------------------------------------------------------------
__global__ __launch_bounds__(256) void mfma_gemm(
    const bf16* __restrict__ A, const bf16* __restrict__ Bt,
    float* __restrict__ C, int M, int N, int K)
{
    __shared__ short Al[128 * 32];
    __shared__ short Bl[128 * 32];
    int tid = threadIdx.x;
    int w = tid >> 6, l = tid & 63;
    int row0 = blockIdx.y * 128, col0 = blockIdx.x * 128;
    int mq = (w >> 1) * 64, nq = (w & 1) * 64;
    int lm = l & 15, kq = l >> 4;
    f32x4 acc[4][4] = {};
    const bf16* Ap = A + (size_t)row0 * K;
    const bf16* Bp = Bt + (size_t)col0 * K;
    for (int kk = 0; kk < K; kk += 32) {
        __syncthreads();
#pragma unroll
        for (int r = 0; r < 2; r++) {
            int c = r * 256 + w * 64 + l;
            int row = c >> 2, kc = (c & 3) * 8;
            const bf16* ga = Ap + (size_t)row * K + kk + kc;
            const bf16* gb = Bp + (size_t)row * K + kk + kc;
            short* la = Al + (size_t)(r * 256 + w * 64) * 8;
            short* lb = Bl + (size_t)(r * 256 + w * 64) * 8;
            __builtin_amdgcn_global_load_lds((const __attribute__((address_space(1))) void*)ga,
                                             (__attribute__((address_space(3))) void*)la, 16, 0, 0);
            __builtin_amdgcn_global_load_lds((const __attribute__((address_space(1))) void*)gb,
                                             (__attribute__((address_space(3))) void*)lb, 16, 0, 0);
        }
        __builtin_amdgcn_s_waitcnt(0);
        __syncthreads();
        frag8 af[4], bfg[4];
#pragma unroll
        for (int i = 0; i < 4; i++)
            af[i] = *(const frag8*)&Al[(size_t)(mq + i * 16 + lm) * 32 + kq * 8];
#pragma unroll
        for (int j = 0; j < 4; j++)
            bfg[j] = *(const frag8*)&Bl[(size_t)(nq + j * 16 + lm) * 32 + kq * 8];
#pragma unroll
        for (int i = 0; i < 4; i++)
#pragma unroll
            for (int j = 0; j < 4; j++)
                acc[i][j] = __builtin_amdgcn_mfma_f32_16x16x32_bf16(af[i], bfg[j], acc[i][j], 0, 0, 0);
    }
#pragma unroll
    for (int i = 0; i < 4; i++)
#pragma unroll
        for (int j = 0; j < 4; j++)
#pragma unroll
            for (int r = 0; r < 4; r++) {
                int row = row0 + mq + i * 16 + kq * 4 + r;
                int col = col0 + nq + j * 16 + lm;
                C[(size_t)row * N + col] = acc[i][j][r];
            }
}

// ---------------------------------------------------------------------------
// transpose + convert bf16: Wt[n][k] = (bf16) W[k][n].
// ---------------------------------------------------------------------------
__global__ void transpose_convert(const float* __restrict__ W, bf16* __restrict__ Wt,
                                  int R, int Cc)
{
    __shared__ float tile[32][33];
    int bx = blockIdx.x * 32, by = blockIdx.y * 32;
    int tx = threadIdx.x, ty = threadIdx.y;
    for (int i = ty; i < 32; i += 8)
        tile[i][tx] = W[(size_t)(by + i) * Cc + bx + tx];
    __syncthreads();
    for (int i = ty; i < 32; i += 8)
        Wt[(size_t)(bx + i) * R + by + tx] = fromF<bf16>(tile[tx][i]);
}

// f32 transpose (for the small D x 32 weights): Wt[c][r] = W[r][c]
__global__ void transpose_f32(const float* __restrict__ W, float* __restrict__ Wt,
                              int R, int Cc)
{
    __shared__ float tile[32][33];
    int bx = blockIdx.x * 32, by = blockIdx.y * 32;
    int tx = threadIdx.x, ty = threadIdx.y;
    for (int i = ty; i < 32; i += 8)
        tile[i][tx] = W[(size_t)(by + i) * Cc + bx + tx];
    __syncthreads();
    for (int i = ty; i < 32; i += 8)
        Wt[(size_t)(bx + i) * R + by + tx] = tile[tx][i];
}

__global__ void convert_bf16(const float* __restrict__ in, bf16* __restrict__ out, int n)
{
    int i = blockIdx.x * 256 + threadIdx.x;
    if (i < n) out[i] = fromF<bf16>(in[i]);
}

// ---------------------------------------------------------------------------
// Generic tiled f32 GEMM (for Ww2 path): C[M,N] = A@B
// ---------------------------------------------------------------------------
template <typename TA, typename TB, typename TC, bool ACC>
__global__ void gemm_tiled(int M, int N, int K,
                           const TA* __restrict__ A, int lda, size_t sA,
                           const TB* __restrict__ B, int ldb, size_t sB,
                           TC* __restrict__ C, int ldc, size_t sC, float alpha)
{
    A += (size_t)blockIdx.z * sA;
    B += (size_t)blockIdx.z * sB;
    C += (size_t)blockIdx.z * sC;
    int row0 = blockIdx.y * 64, col0 = blockIdx.x * 64;
    __shared__ float As[16][68];
    __shared__ float Bs[16][68];
    int tid = threadIdx.x;
    int rb = (tid >> 4) << 2;
    int cb = (tid & 15) << 2;
    float acc[4][4] = {};
    for (int kk = 0; kk < K; kk += 16) {
        for (int i = tid; i < 1024; i += 256) {
            int m = i >> 4, k = i & 15;
            int gr = row0 + m, gk = kk + k;
            As[k][m] = (gr < M && gk < K) ? toF(A[(size_t)gr * lda + gk]) : 0.f;
        }
        for (int i = tid; i < 1024; i += 256) {
            int k = i >> 6, n = i & 63;
            int gk = kk + k, gc = col0 + n;
            Bs[k][n] = (gk < K && gc < N) ? toF(B[(size_t)gk * ldb + gc]) : 0.f;
        }
        __syncthreads();
#pragma unroll
        for (int k = 0; k < 16; k++) {
            float a[4], b[4];
#pragma unroll
            for (int j = 0; j < 4; j++) { a[j] = As[k][rb + j]; b[j] = Bs[k][cb + j]; }
#pragma unroll
            for (int i2 = 0; i2 < 4; i2++)
#pragma unroll
                for (int j = 0; j < 4; j++) acc[i2][j] += a[i2] * b[j];
        }
        __syncthreads();
    }
#pragma unroll
    for (int i2 = 0; i2 < 4; i2++) {
        int gr = row0 + rb + i2;
        if (gr >= M) continue;
#pragma unroll
        for (int j = 0; j < 4; j++) {
            int gc = col0 + cb + j;
            if (gc >= N) continue;
            float v = alpha * acc[i2][j];
            if (ACC) v += toF(C[(size_t)gr * ldc + gc]);
            C[(size_t)gr * ldc + gc] = fromF<TC>(v);
        }
    }
}

// ---------------------------------------------------------------------------
// proj96: w1 (T x 32), beta (T x H), G(pre-cumsum) in ONE kernel.
// Wsm is [96][2048]: rows 0-31 Ww1^T, 32-63 Wbt^T, 64-95 Wg^T.
// Grid (T_), block 256 (4 waves x 24 outputs).
// ---------------------------------------------------------------------------
__global__ __launch_bounds__(256) void proj96(
    const float* __restrict__ h, const float* __restrict__ Wsm,
    const float* __restrict__ bbt, const float* __restrict__ bgp,
    float* __restrict__ w1, float* __restrict__ betaB, float* __restrict__ Gb)
{
    int t = blockIdx.x;
    __shared__ float hrow[2048];
    int tid = threadIdx.x;
    for (int i = tid; i < 2048; i += 256) hrow[i] = h[(size_t)t * D_ + i];
    __syncthreads();
    int w = tid >> 6, l = tid & 63;
    for (int oi = 0; oi < 24; oi++) {
        int o = w * 24 + oi;
        const float* wrow = Wsm + (size_t)o * 2048;
        float acc = 0.f;
        for (int k = l; k < 2048; k += 64) acc += hrow[k] * wrow[k];
#pragma unroll
        for (int off = 32; off > 0; off >>= 1) acc += __shfl_xor(acc, off, 64);
        if (l == 0) {
            if (o < 32) {
                w1[(size_t)t * 32 + o] = acc;
            } else if (o < 64) {
                float xb = acc + bbt[o - 32];
                betaB[(size_t)t * H_ + (o - 32)] = 2.f / (1.f + expf(-xb));
            } else {
                float xg = acc + bgp[o - 64];
                Gb[(size_t)t * H_ + (o - 64)] =
                    (xg >= 0.f) ? -log1pf(expf(-xg)) : (xg - log1pf(expf(xg)));
            }
        }
    }
}

// ---------------------------------------------------------------------------
// pairdot3: Lb = strict(w.w^T)*beta[s], Cm = strict(w.k^T), Em = causal(q.w^T)*beta[s]
// ---------------------------------------------------------------------------
__global__ void pairdot3(const float* __restrict__ qf, const float* __restrict__ kf,
                         const float* __restrict__ wf, const float* __restrict__ beta,
                         float* __restrict__ Lb, float* __restrict__ Cm,
                         float* __restrict__ Em, int headStart)
{
    int z = blockIdx.z;
    int head = headStart + z;
    size_t hoff = (size_t)head * HD_;
    int t0 = blockIdx.y * 32, s0 = blockIdx.x * 32;
    __shared__ float Wr[64][33], Qr[64][33], Wc[64][33], Kc[64][33];
    int tid = threadIdx.x;
    for (int i = tid; i < 2048; i += 256) {
        int r = i >> 6, k = i & 63;
        Wr[k][r] = wf[(size_t)(t0 + r) * D_ + hoff + k];
        Qr[k][r] = qf[(size_t)(t0 + r) * D_ + hoff + k];
        Wc[k][r] = wf[(size_t)(s0 + r) * D_ + hoff + k];
        Kc[k][r] = kf[(size_t)(s0 + r) * D_ + hoff + k];
    }
    __syncthreads();
    int row = tid >> 3;
    int cg = (tid & 7) << 2;
    float aL[4] = {}, aS[4] = {}, aE[4] = {};
#pragma unroll 8
    for (int k = 0; k < 64; k++) {
        float xw = Wr[k][row], xq = Qr[k][row];
#pragma unroll
        for (int j = 0; j < 4; j++) {
            float yw = Wc[k][cg + j], yk = Kc[k][cg + j];
            aL[j] += xw * yw;
            aS[j] += xw * yk;
            aE[j] += xq * yw;
        }
    }
    int t = t0 + row;
    size_t base = (size_t)z * TT_ + (size_t)t * T_;
#pragma unroll
    for (int j = 0; j < 4; j++) {
        int s = s0 + cg + j;
        float b = beta[(size_t)s * H_ + head];
        Lb[base + s] = (s < t) ? aL[j] * b : 0.f;
        Cm[base + s] = (s < t) ? aS[j] : 0.f;
        Em[base + s] = (s <= t) ? aE[j] * b : 0.f;
    }
}

// pairdot (unmasked) for Dqk
__global__ void pairdot(const float* __restrict__ X, const float* __restrict__ Y,
                        float* __restrict__ out, int headStart)
{
    int z = blockIdx.z;
    int head = headStart + z;
    size_t hoff = (size_t)head * HD_;
    int t0 = blockIdx.y * 32, s0 = blockIdx.x * 32;
    __shared__ float Xs[64][33];
    __shared__ float Ys[64][33];
    int tid = threadIdx.x;
    for (int i = tid; i < 2048; i += 256) {
        int r = i >> 6, k = i & 63;
        Xs[k][r] = X[(size_t)(t0 + r) * D_ + hoff + k];
        Ys[k][r] = Y[(size_t)(s0 + r) * D_ + hoff + k];
    }
    __syncthreads();
    int row = tid >> 3;
    int cg = (tid & 7) << 2;
    float acc[4] = {};
#pragma unroll 8
    for (int k = 0; k < 64; k++) {
        float x = Xs[k][row];
#pragma unroll
        for (int j = 0; j < 4; j++) acc[j] += x * Ys[k][cg + j];
    }
    float* orow = out + (size_t)z * TT_ + (size_t)(t0 + row) * T_;
#pragma unroll
    for (int j = 0; j < 4; j++) orow[s0 + cg + j] = acc[j];
}

// ---------------------------------------------------------------------------
// diag_inv: invert 64x64 unit-lower diagonal blocks of (I + Lb).
// ---------------------------------------------------------------------------
__global__ void diag_inv(const float* __restrict__ Lb, float* __restrict__ Minv)
{
    int bi = blockIdx.x, z = blockIdx.y;
    const float* Lh = Lb + (size_t)z * TT_;
    __shared__ float Nb[64][65];
    __shared__ float Xc[64][65];
    int tid = threadIdx.x;
    for (int i = tid; i < 4096; i += 64) {
        int r = i >> 6, c = i & 63;
        Nb[r][c] = Lh[(size_t)(bi * 64 + r) * T_ + bi * 64 + c];
    }
    __syncthreads();
    int j = tid;
    for (int t = 0; t < 64; t++) {
        float v = (t == j) ? 1.f : 0.f;
        for (int i = 0; i < t; i++) v -= Nb[t][i] * Xc[i][j];
        Xc[t][j] = v;
    }
    __syncthreads();
    float* Mo = Minv + ((size_t)z * 16 + bi) * 4096;
    for (int i = tid; i < 4096; i += 64) Mo[i] = Xc[i >> 6][i & 63];
}

// ---------------------------------------------------------------------------
// solve_colstrip: entire forward block-solve for one column strip ct.
// Column ct depends only on column ct => no cross-block deps.
// Grid (16, NH), block 256.
// ---------------------------------------------------------------------------
__global__ __launch_bounds__(256) void solve_colstrip(
    float* __restrict__ Cm, const float* __restrict__ Lb,
    const float* __restrict__ Minv)
{
    int ct = blockIdx.x, z = blockIdx.y;
    float* Ch = Cm + (size_t)z * TT_;
    const float* Lh = Lb + (size_t)z * TT_;
    __shared__ float As[16][68];
    __shared__ float Bs[16][68];
    __shared__ float Cb[64][65];
    __shared__ float Mi[64][65];
    int tid = threadIdx.x;
    int rb = (tid >> 4) << 2;
    int cb = (tid & 15) << 2;
    int col = tid & 63, rg = tid >> 6;
    for (int bi = ct; bi < 16; bi++) {
        __syncthreads();  // previous iteration done with Mi/Cb; C writes visible
        const float* Mo = Minv + ((size_t)z * 16 + bi) * 4096;
        for (int i = tid; i < 4096; i += 256) Mi[i >> 6][i & 63] = Mo[i];
        float acc[4][4] = {};
        for (int kk = ct * 64; kk < bi * 64; kk += 16) {
            __syncthreads();
            for (int i = tid; i < 1024; i += 256) {
                int m = i >> 4, k = i & 15;
                As[k][m] = Lh[(size_t)(bi * 64 + m) * T_ + kk + k];
            }
            for (int i = tid; i < 1024; i += 256) {
                int k = i >> 6, n = i & 63;
                Bs[k][n] = Ch[(size_t)(kk + k) * T_ + ct * 64 + n];
            }
            __syncthreads();
#pragma unroll
            for (int k = 0; k < 16; k++) {
                float a[4], b[4];
#pragma unroll
                for (int j = 0; j < 4; j++) { a[j] = As[k][rb + j]; b[j] = Bs[k][cb + j]; }
#pragma unroll
                for (int i2 = 0; i2 < 4; i2++)
#pragma unroll
                    for (int j = 0; j < 4; j++) acc[i2][j] += a[i2] * b[j];
            }
        }
        __syncthreads();  // FMA reads of As/Bs done; Mi load visible
#pragma unroll
        for (int i2 = 0; i2 < 4; i2++)
#pragma unroll
            for (int j = 0; j < 4; j++)
                Cb[rb + i2][cb + j] =
                    Ch[(size_t)(bi * 64 + rb + i2) * T_ + ct * 64 + cb + j] - acc[i2][j];
        __syncthreads();
        float res[16];
        for (int rr = 0; rr < 16; rr++) {
            int row = rg * 16 + rr;
            float v = 0.f;
#pragma unroll 8
            for (int k = 0; k < 64; k++) v += Mi[row][k] * Cb[k][col];
            res[rr] = v;
        }
        for (int rr = 0; rr < 16; rr++) {
            int row = rg * 16 + rr;
            Ch[(size_t)(bi * 64 + row) * T_ + ct * 64 + col] = res[rr];
        }
    }
}

// ---------------------------------------------------------------------------
// gemm_sub_causal: Ab[t,s] -= sum_k E[t,k]*C[k,s], lower tiles, k in [s0,t0+64)
// ---------------------------------------------------------------------------
__global__ void gemm_sub_causal(const float* __restrict__ E, const float* __restrict__ Cm,
                                float* __restrict__ Ab)
{
    int z = blockIdx.z;
    int t0 = blockIdx.y * 64, s0 = blockIdx.x * 64;
    if (s0 > t0) return;
    const float* Eh = E + (size_t)z * TT_;
    const float* Ch = Cm + (size_t)z * TT_;
    float* Ah = Ab + (size_t)z * TT_;
    __shared__ float As[16][68];
    __shared__ float Bs[16][68];
    int tid = threadIdx.x;
    int rb = (tid >> 4) << 2;
    int cb = (tid & 15) << 2;
    float acc[4][4] = {};
    int kEnd = t0 + 64;
    for (int kk = s0; kk < kEnd; kk += 16) {
        for (int i = tid; i < 1024; i += 256) {
            int m = i >> 4, k = i & 15;
            As[k][m] = Eh[(size_t)(t0 + m) * T_ + kk + k];
        }
        for (int i = tid; i < 1024; i += 256) {
            int k = i >> 6, n = i & 63;
            Bs[k][n] = Ch[(size_t)(kk + k) * T_ + s0 + n];
        }
        __syncthreads();
#pragma unroll
        for (int k = 0; k < 16; k++) {
            float a[4], b[4];
#pragma unroll
            for (int j = 0; j < 4; j++) { a[j] = As[k][rb + j]; b[j] = Bs[k][cb + j]; }
#pragma unroll
            for (int i2 = 0; i2 < 4; i2++)
#pragma unroll
                for (int j = 0; j < 4; j++) acc[i2][j] += a[i2] * b[j];
        }
        __syncthreads();
    }
#pragma unroll
    for (int i2 = 0; i2 < 4; i2++)
#pragma unroll
        for (int j = 0; j < 4; j++)
            Ah[(size_t)(t0 + rb + i2) * T_ + s0 + cb + j] -= acc[i2][j];
}

// ---------------------------------------------------------------------------
// small fused elementwise kernels
// ---------------------------------------------------------------------------
__global__ void cumsum_g(float* __restrict__ G)
{
    int h = threadIdx.x;
    float acc = 0.f;
    for (int t = 0; t < T_; t++) {
        acc += G[(size_t)t * H_ + h];
        G[(size_t)t * H_ + h] = acc;
    }
}

__global__ void conv_silu_norm(const float* __restrict__ wr, const float* __restrict__ convw,
                               float* __restrict__ wf)
{
    int b = blockIdx.x;
    int t = b >> 5, h = b & 31;
    int d = threadIdx.x;
    int c = h * 64 + d;
    float c0 = convw[c * 3 + 0];
    float c1 = convw[c * 3 + 1];
    float c2 = convw[c * 3 + 2];
    float x = c2 * wr[(size_t)t * D_ + c];
    if (t >= 1) x += c1 * wr[(size_t)(t - 1) * D_ + c];
    if (t >= 2) x += c0 * wr[(size_t)(t - 2) * D_ + c];
    float y = x / (1.f + expf(-x));
    float ss = y * y;
    for (int off = 32; off > 0; off >>= 1) ss += __shfl_xor(ss, off, 64);
    wf[(size_t)t * D_ + c] = y * rsqrtf(ss);
}

__global__ void softmax_rows(float* __restrict__ Ab, const float* __restrict__ G, int headStart)
{
    int t = blockIdx.x, z = blockIdx.y;
    int head = headStart + z;
    float* row = Ab + (size_t)z * TT_ + (size_t)t * T_;
    int tid = threadIdx.x;
    int len = t + 1;
    float lv[4];
    int cnt = 0;
    float m = -1e30f;
    for (int s = tid; s < len; s += 256) {
        float l = row[s] * 0.125f - G[(size_t)s * H_ + head];
        lv[cnt++] = l;
        if (l > m) m = l;
    }
    __shared__ float red[256];
    red[tid] = m; __syncthreads();
    for (int off = 128; off > 0; off >>= 1) {
        if (tid < off) red[tid] = fmaxf(red[tid], red[tid + off]);
        __syncthreads();
    }
    m = red[0]; __syncthreads();
    float sum = 0.f;
    for (int i = 0; i < cnt; i++) { lv[i] = expf(lv[i] - m); sum += lv[i]; }
    red[tid] = sum; __syncthreads();
    for (int off = 128; off > 0; off >>= 1) {
        if (tid < off) red[tid] += red[tid + off];
        __syncthreads();
    }
    float inv = 1.f / red[0];
    cnt = 0;
    for (int s = tid; s < len; s += 256) row[s] = lv[cnt++] * inv;
    for (int s = len + tid; s < T_; s += 256) row[s] = 0.f;
}

// ---------------------------------------------------------------------------
// PV via split-K: pv_partial (16 row-tiles x 8 k-splits x NH), then pv_reduce.
// ---------------------------------------------------------------------------
__global__ void pv_partial(const float* __restrict__ P, const float* __restrict__ vf,
                           float* __restrict__ PVp, int hs)
{
    int rt = blockIdx.x, ks = blockIdx.y, z = blockIdx.z;
    int t0 = rt * 64;
    const float* Ph = P + (size_t)z * TT_;
    const float* Vh = vf + (size_t)(hs + z) * 64;
    float* Op = PVp + ((size_t)z * 8 + ks) * ((size_t)T_ * 64);
    int k0 = ks * 128;
    int k1 = k0 + 128; if (k1 > t0 + 64) k1 = t0 + 64;
    __shared__ float As[16][68];
    __shared__ float Bs[16][68];
    int tid = threadIdx.x;
    int rb = (tid >> 4) << 2;
    int cb = (tid & 15) << 2;
    float acc[4][4] = {};
    for (int kk = k0; kk < k1; kk += 16) {
        __syncthreads();
        for (int i = tid; i < 1024; i += 256) {
            int m = i >> 4, k = i & 15;
            As[k][m] = Ph[(size_t)(t0 + m) * T_ + kk + k];
        }
        for (int i = tid; i < 1024; i += 256) {
            int k = i >> 6, n = i & 63;
            Bs[k][n] = Vh[(size_t)(kk + k) * D_ + n];
        }
        __syncthreads();
#pragma unroll
        for (int k = 0; k < 16; k++) {
            float a[4], b[4];
#pragma unroll
            for (int j = 0; j < 4; j++) { a[j] = As[k][rb + j]; b[j] = Bs[k][cb + j]; }
#pragma unroll
            for (int i2 = 0; i2 < 4; i2++)
#pragma unroll
                for (int j = 0; j < 4; j++) acc[i2][j] += a[i2] * b[j];
        }
    }
#pragma unroll
    for (int i2 = 0; i2 < 4; i2++)
#pragma unroll
        for (int j = 0; j < 4; j++)
            Op[(size_t)(t0 + rb + i2) * 64 + cb + j] = acc[i2][j];
}

__global__ void pv_reduce(const float* __restrict__ PVp, float* __restrict__ of, int hs)
{
    int idx = blockIdx.x * 256 + threadIdx.x;  // over NH*T_*64 via grid
    int z = idx >> 16;                          // T_*64 = 65536
    int rem = idx & 65535;
    int t = rem >> 6, c = rem & 63;
    float s = 0.f;
#pragma unroll
    for (int ks = 0; ks < 8; ks++)
        s += PVp[((size_t)z * 8 + ks) * ((size_t)T_ * 64) + rem];
    of[(size_t)t * D_ + (size_t)(hs + z) * 64 + c] = s;
}

// ---------------------------------------------------------------------------
extern "C" void kernel_launch(void* const* d_in, const int* in_sizes, int n_in,
                              void* d_out, int out_size, void* d_ws, size_t ws_size,
                              hipStream_t stream)
{
    const float* h     = (const float*)d_in[0];
    const float* Wq    = (const float*)d_in[1];
    const float* Wk    = (const float*)d_in[2];
    const float* Wv    = (const float*)d_in[3];
    const float* Ww1   = (const float*)d_in[4];
    const float* Ww2   = (const float*)d_in[5];
    const float* convw = (const float*)d_in[6];
    const float* Wbt   = (const float*)d_in[7];
    const float* bbt   = (const float*)d_in[8];
    const float* Wg    = (const float*)d_in[9];
    const float* bgp   = (const float*)d_in[10];
    const float* Wo    = (const float*)d_in[11];
    float* out = (float*)d_out;

    float* ws = (float*)d_ws;
    size_t off = 0;
    auto allocF = [&](size_t nf) { float* p = ws + off; off += (nf + 1023) & ~(size_t)1023; return p; };

    float* qf = allocF(TD_);
    float* kf = allocF(TD_);
    float* vf = allocF(TD_);
    float* wr = allocF(TD_);
    float* wf = allocF(TD_);
    float* of = allocF(TD_);
    float* w1 = allocF((size_t)T_ * 32);
    float* betaB = allocF((size_t)T_ * H_);
    float* Gb = allocF((size_t)T_ * H_);
    bf16* h_bf  = (bf16*)allocF(TD_ / 2);
    bf16* of_bf = (bf16*)allocF(TD_ / 2);
    bf16* Wt    = (bf16*)allocF((size_t)D_ * D_ / 2);
    float* Wsm  = allocF((size_t)96 * D_);

    size_t fixedF = off;
    size_t capF = ws_size / 4;
    size_t perHead = 3 * TT_ + (size_t)16 * 4096 + (size_t)8 * T_ * 64 + 8192;
    int NH = 32;
    while (NH > 1 && fixedF + (size_t)NH * perHead > capF) NH >>= 1;
    float* Lb  = allocF((size_t)NH * TT_);
    float* Cm  = allocF((size_t)NH * TT_);
    float* Em  = allocF((size_t)NH * TT_);
    float* Mv  = allocF((size_t)NH * 16 * 4096);
    float* PVp = allocF((size_t)NH * 8 * T_ * 64);

    dim3 blk(256);
    dim3 tcvB(32, 8);
    dim3 tcvG(D_ / 32, D_ / 32);
    dim3 mfmaG(D_ / 128, T_ / 128);

    // bf16 conversions + big projection GEMMs via MFMA
    convert_bf16<<<dim3((TD_ + 255) / 256), blk, 0, stream>>>(h, h_bf, (int)TD_);
    transpose_convert<<<tcvG, tcvB, 0, stream>>>(Wq, Wt, D_, D_);
    mfma_gemm<<<mfmaG, blk, 0, stream>>>(h_bf, Wt, qf, T_, D_, D_);
    transpose_convert<<<tcvG, tcvB, 0, stream>>>(Wk, Wt, D_, D_);
    mfma_gemm<<<mfmaG, blk, 0, stream>>>(h_bf, Wt, kf, T_, D_, D_);
    transpose_convert<<<tcvG, tcvB, 0, stream>>>(Wv, Wt, D_, D_);
    mfma_gemm<<<mfmaG, blk, 0, stream>>>(h_bf, Wt, vf, T_, D_, D_);

    // small projections: transpose Ww1/Wbt/Wg into Wsm [96][2048], then proj96
    transpose_f32<<<dim3(1, D_ / 32), tcvB, 0, stream>>>(Ww1, Wsm + 0 * D_, D_, 32);
    transpose_f32<<<dim3(1, D_ / 32), tcvB, 0, stream>>>(Wbt, Wsm + (size_t)32 * D_, D_, 32);
    transpose_f32<<<dim3(1, D_ / 32), tcvB, 0, stream>>>(Wg,  Wsm + (size_t)64 * D_, D_, 32);
    proj96<<<dim3(T_), blk, 0, stream>>>(h, Wsm, bbt, bgp, w1, betaB, Gb);
    cumsum_g<<<dim3(1), dim3(32), 0, stream>>>(Gb);
    gemm_tiled<float, float, float, false><<<dim3(32, 16, 1), blk, 0, stream>>>(
        T_, D_, 32, w1, 32, 0, Ww2, D_, 0, wr, D_, 0, 1.f);
    conv_silu_norm<<<dim3(T_ * H_), dim3(64), 0, stream>>>(wr, convw, wf);

    int nChunks = H_ / NH;
    for (int c = 0; c < nChunks; c++) {
        int hs = c * NH;
        pairdot3<<<dim3(32, 32, NH), blk, 0, stream>>>(qf, kf, wf, betaB, Lb, Cm, Em, hs);
        diag_inv<<<dim3(16, NH), dim3(64), 0, stream>>>(Lb, Mv);
        solve_colstrip<<<dim3(16, NH), blk, 0, stream>>>(Cm, Lb, Mv);
        pairdot<<<dim3(32, 32, NH), blk, 0, stream>>>(qf, kf, Lb, hs);
        gemm_sub_causal<<<dim3(16, 16, NH), blk, 0, stream>>>(Em, Cm, Lb);
        softmax_rows<<<dim3(T_, NH), blk, 0, stream>>>(Lb, Gb, hs);
        pv_partial<<<dim3(16, 8, NH), blk, 0, stream>>>(Lb, vf, PVp, hs);
        pv_reduce<<<dim3(NH * 256), blk, 0, stream>>>(PVp, of, hs);
    }

    // out = of @ Wo via MFMA
    convert_bf16<<<dim3((TD_ + 255) / 256), blk, 0, stream>>>(of, of_bf, (int)TD_);
    transpose_convert<<<tcvG, tcvB, 0, stream>>>(Wo, Wt, D_, D_);
    mfma_gemm<<<mfmaG, blk, 0, stream>>>(of_bf, Wt, out, T_, D_, D_);
}

// Round 5
// 1526.800 us; speedup vs baseline: 6.0625x; 4.5127x over previous
//
#include <hip/hip_runtime.h>
#include <hip/hip_bf16.h>

typedef __hip_bfloat16 bf16;
typedef unsigned short ushort_t;

#define T_  1024
#define D_  2048
#define H_  32
#define HD_ 64

static const size_t TT_ = (size_t)T_ * T_;
static const size_t TD_ = (size_t)T_ * D_;

__device__ __forceinline__ float toF(float x) { return x; }
__device__ __forceinline__ float toF(bf16 x) { return __bfloat162float(x); }

__device__ __forceinline__ ushort_t f2bf(float v) {
    bf16 b = __float2bfloat16(v);
    return *(ushort_t*)&b;
}
__device__ __forceinline__ float bf2f(ushort_t u) {
    bf16 b = *(bf16*)&u;
    return __bfloat162float(b);
}

typedef __attribute__((ext_vector_type(8))) short frag8;
typedef __attribute__((ext_vector_type(4))) float f32x4;
typedef __attribute__((ext_vector_type(4))) unsigned short u16x4;

#define MFMA16(a, b, c) __builtin_amdgcn_mfma_f32_16x16x32_bf16((a), (b), (c), 0, 0, 0)

// ---------------------------------------------------------------------------
// MFMA GEMM: C = A[M,K]bf16 @ Bt[N,K]^T. 128x128 tile, BK=32.
// OUT: 0 = f32 row-major [M,N]; 1 = bf16 head-major [(col>>6)][row][col&63];
//      2 = bf16 head-transposed [(col>>6)][col&63][row]
// ---------------------------------------------------------------------------
template <int OUT>
__global__ __launch_bounds__(256) void mfma_gemm(
    const ushort_t* __restrict__ A, const ushort_t* __restrict__ Bt,
    void* __restrict__ Cout, int M, int N, int K)
{
    __shared__ short Al[128 * 32];
    __shared__ short Bl[128 * 32];
    int tid = threadIdx.x;
    int w = tid >> 6, l = tid & 63;
    int row0 = blockIdx.y * 128, col0 = blockIdx.x * 128;
    int mq = (w >> 1) * 64, nq = (w & 1) * 64;
    int lm = l & 15, kq = l >> 4;
    f32x4 acc[4][4] = {};
    const ushort_t* Ap = A + (size_t)row0 * K;
    const ushort_t* Bp = Bt + (size_t)col0 * K;
    for (int kk = 0; kk < K; kk += 32) {
        __syncthreads();
#pragma unroll
        for (int r = 0; r < 2; r++) {
            int c = r * 256 + w * 64 + l;
            int row = c >> 2, kc = (c & 3) * 8;
            const ushort_t* ga = Ap + (size_t)row * K + kk + kc;
            const ushort_t* gb = Bp + (size_t)row * K + kk + kc;
            short* la = Al + (size_t)(r * 256 + w * 64) * 8;
            short* lb = Bl + (size_t)(r * 256 + w * 64) * 8;
            __builtin_amdgcn_global_load_lds((const __attribute__((address_space(1))) void*)ga,
                                             (__attribute__((address_space(3))) void*)la, 16, 0, 0);
            __builtin_amdgcn_global_load_lds((const __attribute__((address_space(1))) void*)gb,
                                             (__attribute__((address_space(3))) void*)lb, 16, 0, 0);
        }
        __builtin_amdgcn_s_waitcnt(0);
        __syncthreads();
        frag8 af[4], bfg[4];
#pragma unroll
        for (int i = 0; i < 4; i++)
            af[i] = *(const frag8*)&Al[(size_t)(mq + i * 16 + lm) * 32 + kq * 8];
#pragma unroll
        for (int j = 0; j < 4; j++)
            bfg[j] = *(const frag8*)&Bl[(size_t)(nq + j * 16 + lm) * 32 + kq * 8];
#pragma unroll
        for (int i = 0; i < 4; i++)
#pragma unroll
            for (int j = 0; j < 4; j++)
                acc[i][j] = MFMA16(af[i], bfg[j], acc[i][j]);
    }
#pragma unroll
    for (int i = 0; i < 4; i++)
#pragma unroll
        for (int j = 0; j < 4; j++)
#pragma unroll
            for (int r = 0; r < 4; r++) {
                int row = row0 + mq + i * 16 + kq * 4 + r;
                int col = col0 + nq + j * 16 + lm;
                float v = acc[i][j][r];
                if (OUT == 0)
                    ((float*)Cout)[(size_t)row * N + col] = v;
                else if (OUT == 1)
                    ((ushort_t*)Cout)[((size_t)(col >> 6) * M + row) * 64 + (col & 63)] = f2bf(v);
                else
                    ((ushort_t*)Cout)[(size_t)(col >> 6) * 64 * M + (size_t)(col & 63) * M + row] = f2bf(v);
            }
}

// ---------------------------------------------------------------------------
__global__ void transpose_convert(const float* __restrict__ W, ushort_t* __restrict__ Wt,
                                  int R, int Cc)
{
    __shared__ float tile[32][33];
    int bx = blockIdx.x * 32, by = blockIdx.y * 32;
    int tx = threadIdx.x, ty = threadIdx.y;
    for (int i = ty; i < 32; i += 8)
        tile[i][tx] = W[(size_t)(by + i) * Cc + bx + tx];
    __syncthreads();
    for (int i = ty; i < 32; i += 8)
        Wt[(size_t)(bx + i) * R + by + tx] = f2bf(tile[tx][i]);
}

__global__ void transpose_f32(const float* __restrict__ W, float* __restrict__ Wt,
                              int R, int Cc)
{
    __shared__ float tile[32][33];
    int bx = blockIdx.x * 32, by = blockIdx.y * 32;
    int tx = threadIdx.x, ty = threadIdx.y;
    for (int i = ty; i < 32; i += 8)
        tile[i][tx] = W[(size_t)(by + i) * Cc + bx + tx];
    __syncthreads();
    for (int i = ty; i < 32; i += 8)
        Wt[(size_t)(bx + i) * R + by + tx] = tile[tx][i];
}

__global__ void convert_bf16(const float* __restrict__ in, ushort_t* __restrict__ out, int n)
{
    int i = blockIdx.x * 256 + threadIdx.x;
    if (i < n) out[i] = f2bf(in[i]);
}

// ---------------------------------------------------------------------------
// f32 tiled GEMM for wr = w1 @ Ww2 (K=32)
// ---------------------------------------------------------------------------
__global__ void gemm_tiled(int M, int N, int K,
                           const float* __restrict__ A, int lda,
                           const float* __restrict__ B, int ldb,
                           float* __restrict__ C, int ldc)
{
    int row0 = blockIdx.y * 64, col0 = blockIdx.x * 64;
    __shared__ float As[16][68];
    __shared__ float Bs[16][68];
    int tid = threadIdx.x;
    int rb = (tid >> 4) << 2;
    int cb = (tid & 15) << 2;
    float acc[4][4] = {};
    for (int kk = 0; kk < K; kk += 16) {
        for (int i = tid; i < 1024; i += 256) {
            int m = i >> 4, k = i & 15;
            As[k][m] = A[(size_t)(row0 + m) * lda + kk + k];
        }
        for (int i = tid; i < 1024; i += 256) {
            int k = i >> 6, n = i & 63;
            Bs[k][n] = B[(size_t)(kk + k) * ldb + col0 + n];
        }
        __syncthreads();
#pragma unroll
        for (int k = 0; k < 16; k++) {
            float a[4], b[4];
#pragma unroll
            for (int j = 0; j < 4; j++) { a[j] = As[k][rb + j]; b[j] = Bs[k][cb + j]; }
#pragma unroll
            for (int i2 = 0; i2 < 4; i2++)
#pragma unroll
                for (int j = 0; j < 4; j++) acc[i2][j] += a[i2] * b[j];
        }
        __syncthreads();
    }
#pragma unroll
    for (int i2 = 0; i2 < 4; i2++)
#pragma unroll
        for (int j = 0; j < 4; j++)
            C[(size_t)(row0 + rb + i2) * ldc + col0 + cb + j] = acc[i2][j];
}

// ---------------------------------------------------------------------------
// proj96: w1, beta, G(pre-cumsum). Wsm [96][2048] = [Ww1^T; Wbt^T; Wg^T].
// ---------------------------------------------------------------------------
__global__ __launch_bounds__(256) void proj96(
    const float* __restrict__ h, const float* __restrict__ Wsm,
    const float* __restrict__ bbt, const float* __restrict__ bgp,
    float* __restrict__ w1, float* __restrict__ betaB, float* __restrict__ Gb)
{
    int t = blockIdx.x;
    __shared__ float hrow[2048];
    int tid = threadIdx.x;
    for (int i = tid; i < 2048; i += 256) hrow[i] = h[(size_t)t * D_ + i];
    __syncthreads();
    int w = tid >> 6, l = tid & 63;
    for (int oi = 0; oi < 24; oi++) {
        int o = w * 24 + oi;
        const float* wrow = Wsm + (size_t)o * 2048;
        float acc = 0.f;
        for (int k = l; k < 2048; k += 64) acc += hrow[k] * wrow[k];
#pragma unroll
        for (int off = 32; off > 0; off >>= 1) acc += __shfl_xor(acc, off, 64);
        if (l == 0) {
            if (o < 32) {
                w1[(size_t)t * 32 + o] = acc;
            } else if (o < 64) {
                float xb = acc + bbt[o - 32];
                betaB[(size_t)t * H_ + (o - 32)] = 2.f / (1.f + expf(-xb));
            } else {
                float xg = acc + bgp[o - 64];
                Gb[(size_t)t * H_ + (o - 64)] =
                    (xg >= 0.f) ? -log1pf(expf(-xg)) : (xg - log1pf(expf(xg)));
            }
        }
    }
}

__global__ void cumsum_g(float* __restrict__ G)
{
    int h = threadIdx.x;
    float acc = 0.f;
    for (int t = 0; t < T_; t++) {
        acc += G[(size_t)t * H_ + h];
        G[(size_t)t * H_ + h] = acc;
    }
}

// conv(3) + silu + l2norm -> wh bf16 head-major [H][T][64]
__global__ void conv_silu_norm(const float* __restrict__ wr, const float* __restrict__ convw,
                               ushort_t* __restrict__ wh)
{
    int b = blockIdx.x;
    int t = b >> 5, h = b & 31;
    int d = threadIdx.x;
    int c = h * 64 + d;
    float c0 = convw[c * 3 + 0];
    float c1 = convw[c * 3 + 1];
    float c2 = convw[c * 3 + 2];
    float x = c2 * wr[(size_t)t * D_ + c];
    if (t >= 1) x += c1 * wr[(size_t)(t - 1) * D_ + c];
    if (t >= 2) x += c0 * wr[(size_t)(t - 2) * D_ + c];
    float y = x / (1.f + expf(-x));
    float ss = y * y;
    for (int off = 32; off > 0; off >>= 1) ss += __shfl_xor(ss, off, 64);
    wh[((size_t)h * T_ + t) * 64 + d] = f2bf(y * rsqrtf(ss));
}

// ---------------------------------------------------------------------------
// pairdot3_mfma: per lower tile (t0,s0):
//   Lb[t][s] = strict(w_t.w_s)*beta[s]        (bf16, row-major)
//   Ct[s][t] = strict(w_t.k_s)                (bf16, TRANSPOSED: [s][t])
//   Em[t][s] = -causal(q_t.w_s)*beta[s]       (bf16, row-major, pre-negated)
// Grid (16,16,NH) with upper-tile early-out. Block 256.
// ---------------------------------------------------------------------------
__global__ __launch_bounds__(256) void pairdot3_mfma(
    const ushort_t* __restrict__ qh, const ushort_t* __restrict__ kh,
    const ushort_t* __restrict__ wh, const float* __restrict__ betaB,
    ushort_t* __restrict__ Lb, ushort_t* __restrict__ Ct, ushort_t* __restrict__ Em,
    int hs)
{
    int s0 = blockIdx.x * 64, t0 = blockIdx.y * 64, z = blockIdx.z;
    if (s0 > t0) return;
    int head = hs + z;
    const ushort_t* qb = qh + (size_t)head * T_ * 64;
    const ushort_t* kb = kh + (size_t)head * T_ * 64;
    const ushort_t* wb = wh + (size_t)head * T_ * 64;
    ushort_t* Lz = Lb + (size_t)z * TT_;
    ushort_t* Cz = Ct + (size_t)z * TT_;
    ushort_t* Ez = Em + (size_t)z * TT_;
    int tid = threadIdx.x;
    int w = tid >> 6, l = tid & 63;
    int lm = l & 15, kq = l >> 4;
    int rowA = t0 + w * 16 + lm;
    f32x4 accL[4] = {}, accS[4] = {}, accE[4] = {};
#pragma unroll
    for (int kk = 0; kk < 64; kk += 32) {
        frag8 aw = *(const frag8*)&wb[(size_t)rowA * 64 + kk + kq * 8];
        frag8 aq = *(const frag8*)&qb[(size_t)rowA * 64 + kk + kq * 8];
#pragma unroll
        for (int j = 0; j < 4; j++) {
            int colr = s0 + j * 16 + lm;
            frag8 bw = *(const frag8*)&wb[(size_t)colr * 64 + kk + kq * 8];
            frag8 bk = *(const frag8*)&kb[(size_t)colr * 64 + kk + kq * 8];
            accL[j] = MFMA16(aw, bw, accL[j]);
            accS[j] = MFMA16(aw, bk, accS[j]);
            accE[j] = MFMA16(aq, bw, accE[j]);
        }
    }
    int m0 = w * 16 + kq * 4;
#pragma unroll
    for (int j = 0; j < 4; j++) {
        int s = s0 + j * 16 + lm;
        float beta = betaB[(size_t)s * H_ + head];
        ushort_t cl[4];
#pragma unroll
        for (int r = 0; r < 4; r++) {
            int t = t0 + m0 + r;
            Lz[(size_t)t * T_ + s] = f2bf((s < t) ? accL[j][r] * beta : 0.f);
            Ez[(size_t)t * T_ + s] = f2bf((s <= t) ? -accE[j][r] * beta : 0.f);
            cl[r] = f2bf((s < t) ? accS[j][r] : 0.f);
        }
        *(u16x4*)&Cz[(size_t)s * T_ + t0 + m0] = *(u16x4*)cl;
    }
}

// ---------------------------------------------------------------------------
// diag_inv: invert 64x64 unit-lower diag blocks of (I + Lb); Minv bf16 out.
// Grid (16, NH), block 64.
// ---------------------------------------------------------------------------
__global__ void diag_inv(const ushort_t* __restrict__ Lb, ushort_t* __restrict__ Minv)
{
    int bi = blockIdx.x, z = blockIdx.y;
    const ushort_t* Lh = Lb + (size_t)z * TT_;
    __shared__ float Nb[64][65];
    __shared__ float Xc[64][65];
    int tid = threadIdx.x;
    for (int i = tid; i < 4096; i += 64) {
        int r = i >> 6, c = i & 63;
        Nb[r][c] = (c < r) ? bf2f(Lh[(size_t)(bi * 64 + r) * T_ + bi * 64 + c]) : 0.f;
    }
    __syncthreads();
    int j = tid;
    for (int t = 0; t < 64; t++) {
        float v = (t == j) ? 1.f : 0.f;
        for (int i = j; i < t; i++) v -= Nb[t][i] * Xc[i][j];
        Xc[t][j] = v;
    }
    __syncthreads();
    ushort_t* Mo = Minv + ((size_t)z * 16 + bi) * 4096;
    for (int i = tid; i < 4096; i += 64) Mo[i] = f2bf(Xc[i >> 6][i & 63]);
}

// ---------------------------------------------------------------------------
// solve_mfma: block-forward solve for one 64-col strip, all MFMA.
// Ct in/out transposed [s][t] bf16. Grid (16, NH), block 256.
// ---------------------------------------------------------------------------
__global__ __launch_bounds__(256) void solve_mfma(
    ushort_t* __restrict__ Ct, const ushort_t* __restrict__ Lb,
    const ushort_t* __restrict__ Minv)
{
    int ct = blockIdx.x, z = blockIdx.y;
    ushort_t* Cz = Ct + (size_t)z * TT_;
    const ushort_t* Lz = Lb + (size_t)z * TT_;
    __shared__ ushort_t Xbt[64][72];  // [s][j] bf16 (X transposed for B-operand)
    int tid = threadIdx.x;
    int w = tid >> 6, l = tid & 63;
    int lm = l & 15, kq = l >> 4;
    int s0 = ct * 64;
    int m0 = w * 16 + kq * 4;
    for (int bi = ct; bi < 16; bi++) {
        // update: acc = sum_k Lb[bi-rows][k] * C[k][strip]
        f32x4 acc[4] = {};
        int rowA = bi * 64 + w * 16 + lm;
        for (int kk = s0; kk < bi * 64; kk += 32) {
            frag8 a = *(const frag8*)&Lz[(size_t)rowA * T_ + kk + kq * 8];
#pragma unroll
            for (int j = 0; j < 4; j++) {
                frag8 b = *(const frag8*)&Cz[(size_t)(s0 + j * 16 + lm) * T_ + kk + kq * 8];
                acc[j] = MFMA16(a, b, acc[j]);
            }
        }
        // X = rhs - acc -> LDS (transposed, bf16)
#pragma unroll
        for (int j = 0; j < 4; j++) {
            int sc = s0 + j * 16 + lm;
            u16x4 rhs = *(const u16x4*)&Cz[(size_t)sc * T_ + bi * 64 + m0];
            ushort_t xb[4];
#pragma unroll
            for (int r = 0; r < 4; r++) xb[r] = f2bf(bf2f(rhs[r]) - acc[j][r]);
            *(u16x4*)&Xbt[j * 16 + lm][m0] = *(u16x4*)xb;
        }
        __syncthreads();  // Xbt ready
        // apply: C_bi = Minv @ X via MFMA
        f32x4 res[4] = {};
        const ushort_t* Mo = Minv + ((size_t)z * 16 + bi) * 4096;
#pragma unroll
        for (int kk = 0; kk < 64; kk += 32) {
            frag8 a = *(const frag8*)&Mo[(size_t)(w * 16 + lm) * 64 + kk + kq * 8];
#pragma unroll
            for (int j = 0; j < 4; j++) {
                frag8 b = *(const frag8*)&Xbt[j * 16 + lm][kk + kq * 8];
                res[j] = MFMA16(a, b, res[j]);
            }
        }
#pragma unroll
        for (int j = 0; j < 4; j++) {
            int sc = s0 + j * 16 + lm;
            ushort_t cr[4];
#pragma unroll
            for (int r = 0; r < 4; r++) cr[r] = f2bf(res[j][r]);
            *(u16x4*)&Cz[(size_t)sc * T_ + bi * 64 + m0] = *(u16x4*)cr;
        }
        __syncthreads();  // Ct visible to all waves; Xbt consumed
    }
}

// ---------------------------------------------------------------------------
// flash_attn: per (t-tile, head): A = qk^T + Em@C (Em pre-negated), online
// softmax with gate -G[s], O += P@V. No block barriers (waves independent).
// Grid (16, NH), block 256.
// ---------------------------------------------------------------------------
__global__ __launch_bounds__(256) void flash_attn(
    const ushort_t* __restrict__ qh, const ushort_t* __restrict__ kh,
    const ushort_t* __restrict__ vt, const ushort_t* __restrict__ Em,
    const ushort_t* __restrict__ Ct, const float* __restrict__ Gb,
    float* __restrict__ of, int hs)
{
    int tb = blockIdx.x, z = blockIdx.y;
    int t0 = tb * 64;
    int head = hs + z;
    const ushort_t* qb = qh + (size_t)head * T_ * 64;
    const ushort_t* kb = kh + (size_t)head * T_ * 64;
    const ushort_t* vb = vt + (size_t)head * 64 * T_;
    const ushort_t* Ez = Em + (size_t)z * TT_;
    const ushort_t* Cz = Ct + (size_t)z * TT_;
    __shared__ ushort_t Pl[4][16][72];
    int tid = threadIdx.x;
    int w = tid >> 6, l = tid & 63;
    int lm = l & 15, kq = l >> 4;
    int rowA = t0 + w * 16 + lm;
    int m0 = w * 16 + kq * 4;
    f32x4 o[4] = {};
    float mrow[4], lrow[4];
#pragma unroll
    for (int r = 0; r < 4; r++) { mrow[r] = -1e30f; lrow[r] = 0.f; }
    for (int st = 0; st <= tb; st++) {
        int s0 = st * 64;
        f32x4 x[4] = {};
        // Dqk
#pragma unroll
        for (int kk = 0; kk < 64; kk += 32) {
            frag8 a = *(const frag8*)&qb[(size_t)rowA * 64 + kk + kq * 8];
#pragma unroll
            for (int j = 0; j < 4; j++) {
                frag8 b = *(const frag8*)&kb[(size_t)(s0 + j * 16 + lm) * 64 + kk + kq * 8];
                x[j] = MFMA16(a, b, x[j]);
            }
        }
        // correction: += (-E*beta)[t,k] * C[k,s], k window [s0, t0+64)
        for (int kk = s0; kk < t0 + 64; kk += 32) {
            frag8 a = *(const frag8*)&Ez[(size_t)rowA * T_ + kk + kq * 8];
#pragma unroll
            for (int j = 0; j < 4; j++) {
                frag8 b = *(const frag8*)&Cz[(size_t)(s0 + j * 16 + lm) * T_ + kk + kq * 8];
                x[j] = MFMA16(a, b, x[j]);
            }
        }
        // logits with gate, causal mask on diagonal tile
        float lg[4][4];
#pragma unroll
        for (int j = 0; j < 4; j++) {
            int s = s0 + j * 16 + lm;
            float g = Gb[(size_t)s * H_ + head];
#pragma unroll
            for (int r = 0; r < 4; r++) {
                int t = t0 + m0 + r;
                lg[j][r] = (s <= t) ? (x[j][r] * 0.125f - g) : -1e30f;
            }
        }
        // row max over 64 cols (4 tiles x 16 lanes)
        float rmax[4];
#pragma unroll
        for (int r = 0; r < 4; r++)
            rmax[r] = fmaxf(fmaxf(lg[0][r], lg[1][r]), fmaxf(lg[2][r], lg[3][r]));
#pragma unroll
        for (int d = 1; d < 16; d <<= 1)
#pragma unroll
            for (int r = 0; r < 4; r++) rmax[r] = fmaxf(rmax[r], __shfl_xor(rmax[r], d, 64));
        float mnew[4], alpha[4];
#pragma unroll
        for (int r = 0; r < 4; r++) {
            mnew[r] = fmaxf(mrow[r], rmax[r]);
            alpha[r] = __expf(mrow[r] - mnew[r]);
            mrow[r] = mnew[r];
        }
        float rsum[4] = {0.f, 0.f, 0.f, 0.f};
#pragma unroll
        for (int j = 0; j < 4; j++)
#pragma unroll
            for (int r = 0; r < 4; r++) {
                float p = __expf(lg[j][r] - mnew[r]);
                lg[j][r] = p;
                rsum[r] += p;
            }
#pragma unroll
        for (int d = 1; d < 16; d <<= 1)
#pragma unroll
            for (int r = 0; r < 4; r++) rsum[r] += __shfl_xor(rsum[r], d, 64);
#pragma unroll
        for (int r = 0; r < 4; r++) lrow[r] = lrow[r] * alpha[r] + rsum[r];
#pragma unroll
        for (int j = 0; j < 4; j++)
#pragma unroll
            for (int r = 0; r < 4; r++) o[j][r] *= alpha[r];
        // P -> LDS (per-wave slab; same-wave ordering, no barrier needed)
#pragma unroll
        for (int j = 0; j < 4; j++)
#pragma unroll
            for (int r = 0; r < 4; r++)
                Pl[w][kq * 4 + r][j * 16 + lm] = f2bf(lg[j][r]);
        // O += P @ V
#pragma unroll
        for (int kk = 0; kk < 64; kk += 32) {
            frag8 a = *(const frag8*)&Pl[w][lm][kk + kq * 8];
#pragma unroll
            for (int j = 0; j < 4; j++) {
                frag8 b = *(const frag8*)&vb[(size_t)(j * 16 + lm) * T_ + s0 + kk + kq * 8];
                o[j] = MFMA16(a, b, o[j]);
            }
        }
    }
    // epilogue: normalize and store
#pragma unroll
    for (int j = 0; j < 4; j++) {
        int col = head * 64 + j * 16 + lm;
#pragma unroll
        for (int r = 0; r < 4; r++) {
            int t = t0 + m0 + r;
            of[(size_t)t * D_ + col] = o[j][r] / lrow[r];
        }
    }
}

// ---------------------------------------------------------------------------
extern "C" void kernel_launch(void* const* d_in, const int* in_sizes, int n_in,
                              void* d_out, int out_size, void* d_ws, size_t ws_size,
                              hipStream_t stream)
{
    const float* h     = (const float*)d_in[0];
    const float* Wq    = (const float*)d_in[1];
    const float* Wk    = (const float*)d_in[2];
    const float* Wv    = (const float*)d_in[3];
    const float* Ww1   = (const float*)d_in[4];
    const float* Ww2   = (const float*)d_in[5];
    const float* convw = (const float*)d_in[6];
    const float* Wbt   = (const float*)d_in[7];
    const float* bbt   = (const float*)d_in[8];
    const float* Wg    = (const float*)d_in[9];
    const float* bgp   = (const float*)d_in[10];
    const float* Wo    = (const float*)d_in[11];
    float* out = (float*)d_out;

    float* ws = (float*)d_ws;
    size_t off = 0;
    auto allocF = [&](size_t nf) { float* p = ws + off; off += (nf + 1023) & ~(size_t)1023; return p; };

    float*    wr    = allocF(TD_);
    float*    of    = allocF(TD_);
    float*    w1    = allocF((size_t)T_ * 32);
    float*    betaB = allocF((size_t)T_ * H_);
    float*    Gb    = allocF((size_t)T_ * H_);
    float*    Wsm   = allocF((size_t)96 * D_);
    ushort_t* h_bf  = (ushort_t*)allocF(TD_ / 2);
    ushort_t* of_bf = (ushort_t*)allocF(TD_ / 2);
    ushort_t* Wt    = (ushort_t*)allocF((size_t)D_ * D_ / 2);
    ushort_t* qh    = (ushort_t*)allocF(TD_ / 2);
    ushort_t* kh    = (ushort_t*)allocF(TD_ / 2);
    ushort_t* wh    = (ushort_t*)allocF(TD_ / 2);
    ushort_t* vt    = (ushort_t*)allocF(TD_ / 2);

    size_t fixedF = off;
    size_t capF = ws_size / 4;
    size_t perHead = 3 * (TT_ / 2) + ((size_t)16 * 4096) / 2 + 4096;
    int NH = 32;
    while (NH > 1 && fixedF + (size_t)NH * perHead > capF) NH >>= 1;
    ushort_t* Lb = (ushort_t*)allocF((size_t)NH * TT_ / 2);
    ushort_t* Ct = (ushort_t*)allocF((size_t)NH * TT_ / 2);
    ushort_t* Em = (ushort_t*)allocF((size_t)NH * TT_ / 2);
    ushort_t* Mv = (ushort_t*)allocF((size_t)NH * 16 * 4096 / 2);

    dim3 blk(256);
    dim3 tcvB(32, 8);
    dim3 tcvG(D_ / 32, D_ / 32);
    dim3 mfmaG(D_ / 128, T_ / 128);

    // projections via MFMA (bf16), writing head-major layouts
    convert_bf16<<<dim3((TD_ + 255) / 256), blk, 0, stream>>>(h, h_bf, (int)TD_);
    transpose_convert<<<tcvG, tcvB, 0, stream>>>(Wq, Wt, D_, D_);
    mfma_gemm<1><<<mfmaG, blk, 0, stream>>>(h_bf, Wt, qh, T_, D_, D_);
    transpose_convert<<<tcvG, tcvB, 0, stream>>>(Wk, Wt, D_, D_);
    mfma_gemm<1><<<mfmaG, blk, 0, stream>>>(h_bf, Wt, kh, T_, D_, D_);
    transpose_convert<<<tcvG, tcvB, 0, stream>>>(Wv, Wt, D_, D_);
    mfma_gemm<2><<<mfmaG, blk, 0, stream>>>(h_bf, Wt, vt, T_, D_, D_);

    // small projections + gates
    transpose_f32<<<dim3(1, D_ / 32), tcvB, 0, stream>>>(Ww1, Wsm + 0 * D_, D_, 32);
    transpose_f32<<<dim3(1, D_ / 32), tcvB, 0, stream>>>(Wbt, Wsm + (size_t)32 * D_, D_, 32);
    transpose_f32<<<dim3(1, D_ / 32), tcvB, 0, stream>>>(Wg,  Wsm + (size_t)64 * D_, D_, 32);
    proj96<<<dim3(T_), blk, 0, stream>>>(h, Wsm, bbt, bgp, w1, betaB, Gb);
    cumsum_g<<<dim3(1), dim3(32), 0, stream>>>(Gb);
    gemm_tiled<<<dim3(32, 16), blk, 0, stream>>>(T_, D_, 32, w1, 32, Ww2, D_, wr, D_);
    conv_silu_norm<<<dim3(T_ * H_), dim3(64), 0, stream>>>(wr, convw, wh);

    int nChunks = H_ / NH;
    for (int c = 0; c < nChunks; c++) {
        int hs = c * NH;
        pairdot3_mfma<<<dim3(16, 16, NH), blk, 0, stream>>>(qh, kh, wh, betaB, Lb, Ct, Em, hs);
        diag_inv<<<dim3(16, NH), dim3(64), 0, stream>>>(Lb, Mv);
        solve_mfma<<<dim3(16, NH), blk, 0, stream>>>(Ct, Lb, Mv);
        flash_attn<<<dim3(16, NH), blk, 0, stream>>>(qh, kh, vt, Em, Ct, Gb, of, hs);
    }

    // out = of @ Wo via MFMA
    convert_bf16<<<dim3((TD_ + 255) / 256), blk, 0, stream>>>(of, of_bf, (int)TD_);
    transpose_convert<<<tcvG, tcvB, 0, stream>>>(Wo, Wt, D_, D_);
    mfma_gemm<0><<<mfmaG, blk, 0, stream>>>(of_bf, Wt, out, T_, D_, D_);
}

// Round 6
// 1488.660 us; speedup vs baseline: 6.2178x; 1.0256x over previous
//
#include <hip/hip_runtime.h>
#include <hip/hip_bf16.h>

typedef __hip_bfloat16 bf16;
typedef unsigned short ushort_t;

#define T_  1024
#define D_  2048
#define H_  32
#define HD_ 64

static const size_t TT_ = (size_t)T_ * T_;
static const size_t TD_ = (size_t)T_ * D_;

__device__ __forceinline__ ushort_t f2bf(float v) {
    bf16 b = __float2bfloat16(v);
    return *(ushort_t*)&b;
}
__device__ __forceinline__ float bf2f(ushort_t u) {
    bf16 b = *(bf16*)&u;
    return __bfloat162float(b);
}

typedef __attribute__((ext_vector_type(8))) short frag8;
typedef __attribute__((ext_vector_type(4))) float f32x4;
typedef __attribute__((ext_vector_type(4))) unsigned short u16x4;
typedef __attribute__((ext_vector_type(8))) unsigned short u16x8;

#define MFMA16(a, b, c) __builtin_amdgcn_mfma_f32_16x16x32_bf16((a), (b), (c), 0, 0, 0)

// ---------------------------------------------------------------------------
// MFMA GEMM: C = A[M,K]bf16 @ Bt[N,K]^T. 128x128 tile, BK=32.
// OUT: 0 = f32 row-major [M,N]
//      3 = packed QKV bf16: col<2048 -> qh head-major; <4096 -> kh; else vt
//          (vt stored transposed [head][64][T]); Cout = qkv base (3*T*D/... )
// ---------------------------------------------------------------------------
template <int OUT>
__global__ __launch_bounds__(256) void mfma_gemm(
    const ushort_t* __restrict__ A, const ushort_t* __restrict__ Bt,
    void* __restrict__ Cout, int M, int N, int K)
{
    __shared__ short Al[128 * 32];
    __shared__ short Bl[128 * 32];
    int tid = threadIdx.x;
    int w = tid >> 6, l = tid & 63;
    int row0 = blockIdx.y * 128, col0 = blockIdx.x * 128;
    int mq = (w >> 1) * 64, nq = (w & 1) * 64;
    int lm = l & 15, kq = l >> 4;
    f32x4 acc[4][4] = {};
    const ushort_t* Ap = A + (size_t)row0 * K;
    const ushort_t* Bp = Bt + (size_t)col0 * K;
    for (int kk = 0; kk < K; kk += 32) {
        __syncthreads();
#pragma unroll
        for (int r = 0; r < 2; r++) {
            int c = r * 256 + w * 64 + l;
            int row = c >> 2, kc = (c & 3) * 8;
            const ushort_t* ga = Ap + (size_t)row * K + kk + kc;
            const ushort_t* gb = Bp + (size_t)row * K + kk + kc;
            short* la = Al + (size_t)(r * 256 + w * 64) * 8;
            short* lb = Bl + (size_t)(r * 256 + w * 64) * 8;
            __builtin_amdgcn_global_load_lds((const __attribute__((address_space(1))) void*)ga,
                                             (__attribute__((address_space(3))) void*)la, 16, 0, 0);
            __builtin_amdgcn_global_load_lds((const __attribute__((address_space(1))) void*)gb,
                                             (__attribute__((address_space(3))) void*)lb, 16, 0, 0);
        }
        __builtin_amdgcn_s_waitcnt(0);
        __syncthreads();
        frag8 af[4], bfg[4];
#pragma unroll
        for (int i = 0; i < 4; i++)
            af[i] = *(const frag8*)&Al[(size_t)(mq + i * 16 + lm) * 32 + kq * 8];
#pragma unroll
        for (int j = 0; j < 4; j++)
            bfg[j] = *(const frag8*)&Bl[(size_t)(nq + j * 16 + lm) * 32 + kq * 8];
#pragma unroll
        for (int i = 0; i < 4; i++)
#pragma unroll
            for (int j = 0; j < 4; j++)
                acc[i][j] = MFMA16(af[i], bfg[j], acc[i][j]);
    }
#pragma unroll
    for (int i = 0; i < 4; i++)
#pragma unroll
        for (int j = 0; j < 4; j++)
#pragma unroll
            for (int r = 0; r < 4; r++) {
                int row = row0 + mq + i * 16 + kq * 4 + r;
                int col = col0 + nq + j * 16 + lm;
                float v = acc[i][j][r];
                if (OUT == 0) {
                    ((float*)Cout)[(size_t)row * N + col] = v;
                } else {
                    ushort_t* q = (ushort_t*)Cout;
                    int which = col >> 11, cl = col & 2047;
                    int hd = cl >> 6, d = cl & 63;
                    if (which == 0)
                        q[((size_t)hd * M + row) * 64 + d] = f2bf(v);
                    else if (which == 1)
                        q[(size_t)M * 2048 + ((size_t)hd * M + row) * 64 + d] = f2bf(v);
                    else
                        q[(size_t)M * 4096 + ((size_t)hd * 64 + d) * M + row] = f2bf(v);
                }
            }
}

// ---------------------------------------------------------------------------
__global__ void transpose_convert(const float* __restrict__ W, ushort_t* __restrict__ Wt,
                                  int R, int Cc)
{
    __shared__ float tile[32][33];
    int bx = blockIdx.x * 32, by = blockIdx.y * 32;
    int tx = threadIdx.x, ty = threadIdx.y;
    for (int i = ty; i < 32; i += 8)
        tile[i][tx] = W[(size_t)(by + i) * Cc + bx + tx];
    __syncthreads();
    for (int i = ty; i < 32; i += 8)
        Wt[(size_t)(bx + i) * R + by + tx] = f2bf(tile[tx][i]);
}

__global__ void transpose_f32(const float* __restrict__ W, float* __restrict__ Wt,
                              int R, int Cc)
{
    __shared__ float tile[32][33];
    int bx = blockIdx.x * 32, by = blockIdx.y * 32;
    int tx = threadIdx.x, ty = threadIdx.y;
    for (int i = ty; i < 32; i += 8)
        tile[i][tx] = W[(size_t)(by + i) * Cc + bx + tx];
    __syncthreads();
    for (int i = ty; i < 32; i += 8)
        Wt[(size_t)(bx + i) * R + by + tx] = tile[tx][i];
}

__global__ void convert_bf16(const float* __restrict__ in, ushort_t* __restrict__ out, int n)
{
    int i = blockIdx.x * 256 + threadIdx.x;
    if (i < n) out[i] = f2bf(in[i]);
}

// ---------------------------------------------------------------------------
// f32 tiled GEMM for wr = w1 @ Ww2 (K=32)
// ---------------------------------------------------------------------------
__global__ void gemm_tiled(int M, int N, int K,
                           const float* __restrict__ A, int lda,
                           const float* __restrict__ B, int ldb,
                           float* __restrict__ C, int ldc)
{
    int row0 = blockIdx.y * 64, col0 = blockIdx.x * 64;
    __shared__ float As[16][68];
    __shared__ float Bs[16][68];
    int tid = threadIdx.x;
    int rb = (tid >> 4) << 2;
    int cb = (tid & 15) << 2;
    float acc[4][4] = {};
    for (int kk = 0; kk < K; kk += 16) {
        for (int i = tid; i < 1024; i += 256) {
            int m = i >> 4, k = i & 15;
            As[k][m] = A[(size_t)(row0 + m) * lda + kk + k];
        }
        for (int i = tid; i < 1024; i += 256) {
            int k = i >> 6, n = i & 63;
            Bs[k][n] = B[(size_t)(kk + k) * ldb + col0 + n];
        }
        __syncthreads();
#pragma unroll
        for (int k = 0; k < 16; k++) {
            float a[4], b[4];
#pragma unroll
            for (int j = 0; j < 4; j++) { a[j] = As[k][rb + j]; b[j] = Bs[k][cb + j]; }
#pragma unroll
            for (int i2 = 0; i2 < 4; i2++)
#pragma unroll
                for (int j = 0; j < 4; j++) acc[i2][j] += a[i2] * b[j];
        }
        __syncthreads();
    }
#pragma unroll
    for (int i2 = 0; i2 < 4; i2++)
#pragma unroll
        for (int j = 0; j < 4; j++)
            C[(size_t)(row0 + rb + i2) * ldc + col0 + cb + j] = acc[i2][j];
}

// ---------------------------------------------------------------------------
// proj96: w1, beta, G(pre-cumsum). Wsm [96][2048] = [Ww1^T; Wbt^T; Wg^T].
// ---------------------------------------------------------------------------
__global__ __launch_bounds__(256) void proj96(
    const float* __restrict__ h, const float* __restrict__ Wsm,
    const float* __restrict__ bbt, const float* __restrict__ bgp,
    float* __restrict__ w1, float* __restrict__ betaB, float* __restrict__ Gb)
{
    int t = blockIdx.x;
    __shared__ float hrow[2048];
    int tid = threadIdx.x;
    for (int i = tid; i < 2048; i += 256) hrow[i] = h[(size_t)t * D_ + i];
    __syncthreads();
    int w = tid >> 6, l = tid & 63;
    for (int oi = 0; oi < 24; oi++) {
        int o = w * 24 + oi;
        const float* wrow = Wsm + (size_t)o * 2048;
        float acc = 0.f;
        for (int k = l; k < 2048; k += 64) acc += hrow[k] * wrow[k];
#pragma unroll
        for (int off = 32; off > 0; off >>= 1) acc += __shfl_xor(acc, off, 64);
        if (l == 0) {
            if (o < 32) {
                w1[(size_t)t * 32 + o] = acc;
            } else if (o < 64) {
                float xb = acc + bbt[o - 32];
                betaB[(size_t)t * H_ + (o - 32)] = 2.f / (1.f + expf(-xb));
            } else {
                float xg = acc + bgp[o - 64];
                Gb[(size_t)t * H_ + (o - 64)] =
                    (xg >= 0.f) ? -log1pf(expf(-xg)) : (xg - log1pf(expf(xg)));
            }
        }
    }
}

// parallel inclusive scan of G[:, h] per head. Grid (H_), block 256.
__global__ void scan_g(float* __restrict__ G)
{
    int h = blockIdx.x;
    int tid = threadIdx.x;
    __shared__ float psum[256];
    float v[4];
    float s = 0.f;
#pragma unroll
    for (int r = 0; r < 4; r++) {
        v[r] = G[(size_t)(tid * 4 + r) * H_ + h];
        s += v[r];
    }
    psum[tid] = s;
    __syncthreads();
    for (int off = 1; off < 256; off <<= 1) {
        float t = (tid >= off) ? psum[tid - off] : 0.f;
        __syncthreads();
        psum[tid] += t;
        __syncthreads();
    }
    float run = (tid > 0) ? psum[tid - 1] : 0.f;
#pragma unroll
    for (int r = 0; r < 4; r++) {
        run += v[r];
        G[(size_t)(tid * 4 + r) * H_ + h] = run;
    }
}

// conv(3) + silu + l2norm -> wh bf16 head-major [H][T][64]
__global__ void conv_silu_norm(const float* __restrict__ wr, const float* __restrict__ convw,
                               ushort_t* __restrict__ wh)
{
    int b = blockIdx.x;
    int t = b >> 5, h = b & 31;
    int d = threadIdx.x;
    int c = h * 64 + d;
    float c0 = convw[c * 3 + 0];
    float c1 = convw[c * 3 + 1];
    float c2 = convw[c * 3 + 2];
    float x = c2 * wr[(size_t)t * D_ + c];
    if (t >= 1) x += c1 * wr[(size_t)(t - 1) * D_ + c];
    if (t >= 2) x += c0 * wr[(size_t)(t - 2) * D_ + c];
    float y = x / (1.f + expf(-x));
    float ss = y * y;
    for (int off = 32; off > 0; off >>= 1) ss += __shfl_xor(ss, off, 64);
    wh[((size_t)h * T_ + t) * 64 + d] = f2bf(y * rsqrtf(ss));
}

// ---------------------------------------------------------------------------
// pairdot3_mfma: per lower tile (t0,s0):
//   Lb[t][s] = strict(w_t.w_s)*beta[s]   (bf16 row-major)
//   Ct[s][t] = strict(w_t.k_s)           (bf16 TRANSPOSED [s][t])
//   Em[t][s] = -causal(q_t.w_s)*beta[s]  (bf16 row-major, pre-negated)
// ---------------------------------------------------------------------------
__global__ __launch_bounds__(256) void pairdot3_mfma(
    const ushort_t* __restrict__ qh, const ushort_t* __restrict__ kh,
    const ushort_t* __restrict__ wh, const float* __restrict__ betaB,
    ushort_t* __restrict__ Lb, ushort_t* __restrict__ Ct, ushort_t* __restrict__ Em,
    int hs)
{
    int s0 = blockIdx.x * 64, t0 = blockIdx.y * 64, z = blockIdx.z;
    if (s0 > t0) return;
    int head = hs + z;
    const ushort_t* qb = qh + (size_t)head * T_ * 64;
    const ushort_t* kb = kh + (size_t)head * T_ * 64;
    const ushort_t* wb = wh + (size_t)head * T_ * 64;
    ushort_t* Lz = Lb + (size_t)z * TT_;
    ushort_t* Cz = Ct + (size_t)z * TT_;
    ushort_t* Ez = Em + (size_t)z * TT_;
    int tid = threadIdx.x;
    int w = tid >> 6, l = tid & 63;
    int lm = l & 15, kq = l >> 4;
    int rowA = t0 + w * 16 + lm;
    f32x4 accL[4] = {}, accS[4] = {}, accE[4] = {};
#pragma unroll
    for (int kk = 0; kk < 64; kk += 32) {
        frag8 aw = *(const frag8*)&wb[(size_t)rowA * 64 + kk + kq * 8];
        frag8 aq = *(const frag8*)&qb[(size_t)rowA * 64 + kk + kq * 8];
#pragma unroll
        for (int j = 0; j < 4; j++) {
            int colr = s0 + j * 16 + lm;
            frag8 bw = *(const frag8*)&wb[(size_t)colr * 64 + kk + kq * 8];
            frag8 bk = *(const frag8*)&kb[(size_t)colr * 64 + kk + kq * 8];
            accL[j] = MFMA16(aw, bw, accL[j]);
            accS[j] = MFMA16(aw, bk, accS[j]);
            accE[j] = MFMA16(aq, bw, accE[j]);
        }
    }
    int m0 = w * 16 + kq * 4;
#pragma unroll
    for (int j = 0; j < 4; j++) {
        int s = s0 + j * 16 + lm;
        float beta = betaB[(size_t)s * H_ + head];
        ushort_t cl[4];
#pragma unroll
        for (int r = 0; r < 4; r++) {
            int t = t0 + m0 + r;
            Lz[(size_t)t * T_ + s] = f2bf((s < t) ? accL[j][r] * beta : 0.f);
            Ez[(size_t)t * T_ + s] = f2bf((s <= t) ? -accE[j][r] * beta : 0.f);
            cl[r] = f2bf((s < t) ? accS[j][r] : 0.f);
        }
        *(u16x4*)&Cz[(size_t)s * T_ + t0 + m0] = *(u16x4*)cl;
    }
}

// ---------------------------------------------------------------------------
// diag_inv: invert 64x64 unit-lower diag blocks of (I + Lb); Minv bf16 out.
// ---------------------------------------------------------------------------
__global__ void diag_inv(const ushort_t* __restrict__ Lb, ushort_t* __restrict__ Minv)
{
    int bi = blockIdx.x, z = blockIdx.y;
    const ushort_t* Lh = Lb + (size_t)z * TT_;
    __shared__ float Nb[64][65];
    __shared__ float Xc[64][65];
    int tid = threadIdx.x;
    for (int i = tid; i < 4096; i += 64) {
        int r = i >> 6, c = i & 63;
        Nb[r][c] = (c < r) ? bf2f(Lh[(size_t)(bi * 64 + r) * T_ + bi * 64 + c]) : 0.f;
    }
    __syncthreads();
    int j = tid;
    for (int t = 0; t < 64; t++) {
        float v = (t == j) ? 1.f : 0.f;
        for (int i = j; i < t; i++) v -= Nb[t][i] * Xc[i][j];
        Xc[t][j] = v;
    }
    __syncthreads();
    ushort_t* Mo = Minv + ((size_t)z * 16 + bi) * 4096;
    for (int i = tid; i < 4096; i += 64) Mo[i] = f2bf(Xc[i >> 6][i & 63]);
}

// ---------------------------------------------------------------------------
// solve_mfma v2: block-forward solve for one 64-col strip with LDS-staged
// L and C chunks. Grid (16, NH), block 256.
// ---------------------------------------------------------------------------
__global__ __launch_bounds__(256) void solve_mfma(
    ushort_t* __restrict__ Ct, const ushort_t* __restrict__ Lb,
    const ushort_t* __restrict__ Minv)
{
    int ct = blockIdx.x, z = blockIdx.y;
    ushort_t* Cz = Ct + (size_t)z * TT_;
    const ushort_t* Lz = Lb + (size_t)z * TT_;
    __shared__ ushort_t Cl[64][136];
    __shared__ ushort_t Ll[64][136];
    __shared__ ushort_t Xbt[64][72];
    int tid = threadIdx.x;
    int w = tid >> 6, l = tid & 63;
    int lm = l & 15, kq = l >> 4;
    int s0 = ct * 64;
    int m0 = w * 16 + kq * 4;
    for (int bi = ct; bi < 16; bi++) {
        f32x4 acc[4] = {};
        for (int kkc = s0; kkc < bi * 64; kkc += 128) {
            int len = bi * 64 - kkc; if (len > 128) len = 128;
            int lsh = (len == 128) ? 4 : 3;
            __syncthreads();
            for (int i = tid; i < (64 << lsh); i += 256) {
                int r = i >> lsh, c = (i & ((1 << lsh) - 1)) * 8;
                *(u16x8*)&Cl[r][c] = *(const u16x8*)&Cz[(size_t)(s0 + r) * T_ + kkc + c];
                *(u16x8*)&Ll[r][c] = *(const u16x8*)&Lz[(size_t)(bi * 64 + r) * T_ + kkc + c];
            }
            __syncthreads();
            for (int kk2 = 0; kk2 < len; kk2 += 32) {
                frag8 a = *(const frag8*)&Ll[w * 16 + lm][kk2 + kq * 8];
#pragma unroll
                for (int j = 0; j < 4; j++) {
                    frag8 b = *(const frag8*)&Cl[j * 16 + lm][kk2 + kq * 8];
                    acc[j] = MFMA16(a, b, acc[j]);
                }
            }
        }
        __syncthreads();
#pragma unroll
        for (int j = 0; j < 4; j++) {
            int sc = s0 + j * 16 + lm;
            u16x4 rhs = *(const u16x4*)&Cz[(size_t)sc * T_ + bi * 64 + m0];
            ushort_t xb[4];
#pragma unroll
            for (int r = 0; r < 4; r++) xb[r] = f2bf(bf2f(rhs[r]) - acc[j][r]);
            *(u16x4*)&Xbt[j * 16 + lm][m0] = *(u16x4*)xb;
        }
        __syncthreads();
        f32x4 res[4] = {};
        const ushort_t* Mo = Minv + ((size_t)z * 16 + bi) * 4096;
#pragma unroll
        for (int kk = 0; kk < 64; kk += 32) {
            frag8 a = *(const frag8*)&Mo[(size_t)(w * 16 + lm) * 64 + kk + kq * 8];
#pragma unroll
            for (int j = 0; j < 4; j++) {
                frag8 b = *(const frag8*)&Xbt[j * 16 + lm][kk + kq * 8];
                res[j] = MFMA16(a, b, res[j]);
            }
        }
#pragma unroll
        for (int j = 0; j < 4; j++) {
            int sc = s0 + j * 16 + lm;
            ushort_t cr[4];
#pragma unroll
            for (int r = 0; r < 4; r++) cr[r] = f2bf(res[j][r]);
            *(u16x4*)&Cz[(size_t)sc * T_ + bi * 64 + m0] = *(u16x4*)cr;
        }
        __syncthreads();
    }
}

// ---------------------------------------------------------------------------
// flash_attn v2: LDS-staged K/V/C/Em, online softmax, PV. Grid (16, NH).
// Longest t-tiles dispatched first (tb = 15 - blockIdx.x).
// ---------------------------------------------------------------------------
__global__ __launch_bounds__(256) void flash_attn(
    const ushort_t* __restrict__ qh, const ushort_t* __restrict__ kh,
    const ushort_t* __restrict__ vt, const ushort_t* __restrict__ Em,
    const ushort_t* __restrict__ Ct, const float* __restrict__ Gb,
    float* __restrict__ of, int hs)
{
    int tb = (int)gridDim.x - 1 - (int)blockIdx.x;
    int z = blockIdx.y;
    int t0 = tb * 64;
    int head = hs + z;
    const ushort_t* qb = qh + (size_t)head * T_ * 64;
    const ushort_t* kb = kh + (size_t)head * T_ * 64;
    const ushort_t* vb = vt + (size_t)head * 64 * T_;
    const ushort_t* Ez = Em + (size_t)z * TT_;
    const ushort_t* Cz = Ct + (size_t)z * TT_;
    __shared__ ushort_t Kl[64][72];
    __shared__ ushort_t Vl[64][72];
    __shared__ ushort_t Cl[64][136];
    __shared__ ushort_t El[64][136];
    __shared__ ushort_t Pl[4][16][72];
    int tid = threadIdx.x;
    int w = tid >> 6, l = tid & 63;
    int lm = l & 15, kq = l >> 4;
    int rowA = t0 + w * 16 + lm;
    int m0 = w * 16 + kq * 4;
    frag8 aq0 = *(const frag8*)&qb[(size_t)rowA * 64 + kq * 8];
    frag8 aq1 = *(const frag8*)&qb[(size_t)rowA * 64 + 32 + kq * 8];
    f32x4 o[4] = {};
    float mrow[4], lrow[4];
#pragma unroll
    for (int r = 0; r < 4; r++) { mrow[r] = -1e30f; lrow[r] = 0.f; }
    for (int st = 0; st <= tb; st++) {
        int s0 = st * 64;
        __syncthreads();  // prev iter Vl/Kl reads done
        for (int i = tid; i < 512; i += 256) {
            int r = i >> 3, c = (i & 7) * 8;
            *(u16x8*)&Kl[r][c] = *(const u16x8*)&kb[(size_t)(s0 + r) * 64 + c];
            *(u16x8*)&Vl[r][c] = *(const u16x8*)&vb[(size_t)r * T_ + s0 + c];
        }
        __syncthreads();
        f32x4 x[4] = {};
        // Dqk
#pragma unroll
        for (int j = 0; j < 4; j++) {
            frag8 b0 = *(const frag8*)&Kl[j * 16 + lm][kq * 8];
            frag8 b1 = *(const frag8*)&Kl[j * 16 + lm][32 + kq * 8];
            x[j] = MFMA16(aq0, b0, x[j]);
            x[j] = MFMA16(aq1, b1, x[j]);
        }
        // correction: += (-E*beta)[t,k] * C[k,s], k in [s0, t0+64), chunks of 128
        for (int kkc = s0; kkc < t0 + 64; kkc += 128) {
            int len = t0 + 64 - kkc; if (len > 128) len = 128;
            int lsh = (len == 128) ? 4 : 3;
            __syncthreads();
            for (int i = tid; i < (64 << lsh); i += 256) {
                int r = i >> lsh, c = (i & ((1 << lsh) - 1)) * 8;
                *(u16x8*)&Cl[r][c] = *(const u16x8*)&Cz[(size_t)(s0 + r) * T_ + kkc + c];
                *(u16x8*)&El[r][c] = *(const u16x8*)&Ez[(size_t)(t0 + r) * T_ + kkc + c];
            }
            __syncthreads();
            for (int kk2 = 0; kk2 < len; kk2 += 32) {
                frag8 a = *(const frag8*)&El[w * 16 + lm][kk2 + kq * 8];
#pragma unroll
                for (int j = 0; j < 4; j++) {
                    frag8 b = *(const frag8*)&Cl[j * 16 + lm][kk2 + kq * 8];
                    x[j] = MFMA16(a, b, x[j]);
                }
            }
        }
        // logits with gate, causal mask on diagonal tile
        float lg[4][4];
#pragma unroll
        for (int j = 0; j < 4; j++) {
            int s = s0 + j * 16 + lm;
            float g = Gb[(size_t)s * H_ + head];
#pragma unroll
            for (int r = 0; r < 4; r++) {
                int t = t0 + m0 + r;
                lg[j][r] = (s <= t) ? (x[j][r] * 0.125f - g) : -1e30f;
            }
        }
        float rmax[4];
#pragma unroll
        for (int r = 0; r < 4; r++)
            rmax[r] = fmaxf(fmaxf(lg[0][r], lg[1][r]), fmaxf(lg[2][r], lg[3][r]));
#pragma unroll
        for (int d = 1; d < 16; d <<= 1)
#pragma unroll
            for (int r = 0; r < 4; r++) rmax[r] = fmaxf(rmax[r], __shfl_xor(rmax[r], d, 64));
        float mnew[4], alpha[4];
#pragma unroll
        for (int r = 0; r < 4; r++) {
            mnew[r] = fmaxf(mrow[r], rmax[r]);
            alpha[r] = __expf(mrow[r] - mnew[r]);
            mrow[r] = mnew[r];
        }
        float rsum[4] = {0.f, 0.f, 0.f, 0.f};
#pragma unroll
        for (int j = 0; j < 4; j++)
#pragma unroll
            for (int r = 0; r < 4; r++) {
                float p = __expf(lg[j][r] - mnew[r]);
                lg[j][r] = p;
                rsum[r] += p;
            }
#pragma unroll
        for (int d = 1; d < 16; d <<= 1)
#pragma unroll
            for (int r = 0; r < 4; r++) rsum[r] += __shfl_xor(rsum[r], d, 64);
#pragma unroll
        for (int r = 0; r < 4; r++) lrow[r] = lrow[r] * alpha[r] + rsum[r];
#pragma unroll
        for (int j = 0; j < 4; j++)
#pragma unroll
            for (int r = 0; r < 4; r++) o[j][r] *= alpha[r];
        // P -> per-wave LDS slab (same-wave write/read, no barrier)
#pragma unroll
        for (int j = 0; j < 4; j++)
#pragma unroll
            for (int r = 0; r < 4; r++)
                Pl[w][kq * 4 + r][j * 16 + lm] = f2bf(lg[j][r]);
        // O += P @ V
#pragma unroll
        for (int j = 0; j < 4; j++) {
            frag8 b0 = *(const frag8*)&Vl[j * 16 + lm][kq * 8];
            frag8 b1 = *(const frag8*)&Vl[j * 16 + lm][32 + kq * 8];
            frag8 a0 = *(const frag8*)&Pl[w][lm][kq * 8];
            frag8 a1 = *(const frag8*)&Pl[w][lm][32 + kq * 8];
            o[j] = MFMA16(a0, b0, o[j]);
            o[j] = MFMA16(a1, b1, o[j]);
        }
    }
#pragma unroll
    for (int j = 0; j < 4; j++) {
        int col = head * 64 + j * 16 + lm;
#pragma unroll
        for (int r = 0; r < 4; r++) {
            int t = t0 + m0 + r;
            of[(size_t)t * D_ + col] = o[j][r] / lrow[r];
        }
    }
}

// ---------------------------------------------------------------------------
extern "C" void kernel_launch(void* const* d_in, const int* in_sizes, int n_in,
                              void* d_out, int out_size, void* d_ws, size_t ws_size,
                              hipStream_t stream)
{
    const float* h     = (const float*)d_in[0];
    const float* Wq    = (const float*)d_in[1];
    const float* Wk    = (const float*)d_in[2];
    const float* Wv    = (const float*)d_in[3];
    const float* Ww1   = (const float*)d_in[4];
    const float* Ww2   = (const float*)d_in[5];
    const float* convw = (const float*)d_in[6];
    const float* Wbt   = (const float*)d_in[7];
    const float* bbt   = (const float*)d_in[8];
    const float* Wg    = (const float*)d_in[9];
    const float* bgp   = (const float*)d_in[10];
    const float* Wo    = (const float*)d_in[11];
    float* out = (float*)d_out;

    float* ws = (float*)d_ws;
    size_t off = 0;
    auto allocF = [&](size_t nf) { float* p = ws + off; off += (nf + 1023) & ~(size_t)1023; return p; };

    float*    wr    = allocF(TD_);
    float*    of    = allocF(TD_);
    float*    w1    = allocF((size_t)T_ * 32);
    float*    betaB = allocF((size_t)T_ * H_);
    float*    Gb    = allocF((size_t)T_ * H_);
    float*    Wsm   = allocF((size_t)96 * D_);
    ushort_t* h_bf  = (ushort_t*)allocF(TD_ / 2);
    ushort_t* of_bf = (ushort_t*)allocF(TD_ / 2);
    ushort_t* Wtc   = (ushort_t*)allocF((size_t)3 * D_ * D_ / 2);  // QKV cat; reused for Wo
    ushort_t* qkv   = (ushort_t*)allocF((size_t)3 * TD_ / 2);
    ushort_t* qh    = qkv;
    ushort_t* kh    = qkv + TD_;
    ushort_t* vt    = qkv + 2 * TD_;
    ushort_t* wh    = (ushort_t*)allocF(TD_ / 2);

    size_t fixedF = off;
    size_t capF = ws_size / 4;
    size_t perHead = 3 * (TT_ / 2) + ((size_t)16 * 4096) / 2 + 4096;
    int NH = 32;
    while (NH > 1 && fixedF + (size_t)NH * perHead > capF) NH >>= 1;
    ushort_t* Lb = (ushort_t*)allocF((size_t)NH * TT_ / 2);
    ushort_t* Ct = (ushort_t*)allocF((size_t)NH * TT_ / 2);
    ushort_t* Em = (ushort_t*)allocF((size_t)NH * TT_ / 2);
    ushort_t* Mv = (ushort_t*)allocF((size_t)NH * 16 * 4096 / 2);

    dim3 blk(256);
    dim3 tcvB(32, 8);
    dim3 tcvG(D_ / 32, D_ / 32);

    // fused QKV projection via MFMA (bf16)
    convert_bf16<<<dim3((TD_ + 255) / 256), blk, 0, stream>>>(h, h_bf, (int)TD_);
    transpose_convert<<<tcvG, tcvB, 0, stream>>>(Wq, Wtc, D_, D_);
    transpose_convert<<<tcvG, tcvB, 0, stream>>>(Wk, Wtc + (size_t)D_ * D_, D_, D_);
    transpose_convert<<<tcvG, tcvB, 0, stream>>>(Wv, Wtc + (size_t)2 * D_ * D_, D_, D_);
    mfma_gemm<3><<<dim3(3 * D_ / 128, T_ / 128), blk, 0, stream>>>(h_bf, Wtc, qkv, T_, 3 * D_, D_);

    // small projections + gates
    transpose_f32<<<dim3(1, D_ / 32), tcvB, 0, stream>>>(Ww1, Wsm + 0 * D_, D_, 32);
    transpose_f32<<<dim3(1, D_ / 32), tcvB, 0, stream>>>(Wbt, Wsm + (size_t)32 * D_, D_, 32);
    transpose_f32<<<dim3(1, D_ / 32), tcvB, 0, stream>>>(Wg,  Wsm + (size_t)64 * D_, D_, 32);
    proj96<<<dim3(T_), blk, 0, stream>>>(h, Wsm, bbt, bgp, w1, betaB, Gb);
    scan_g<<<dim3(H_), blk, 0, stream>>>(Gb);
    gemm_tiled<<<dim3(32, 16), blk, 0, stream>>>(T_, D_, 32, w1, 32, Ww2, D_, wr, D_);
    conv_silu_norm<<<dim3(T_ * H_), dim3(64), 0, stream>>>(wr, convw, wh);

    int nChunks = H_ / NH;
    for (int c = 0; c < nChunks; c++) {
        int hs = c * NH;
        pairdot3_mfma<<<dim3(16, 16, NH), blk, 0, stream>>>(qh, kh, wh, betaB, Lb, Ct, Em, hs);
        diag_inv<<<dim3(16, NH), dim3(64), 0, stream>>>(Lb, Mv);
        solve_mfma<<<dim3(16, NH), blk, 0, stream>>>(Ct, Lb, Mv);
        flash_attn<<<dim3(16, NH), blk, 0, stream>>>(qh, kh, vt, Em, Ct, Gb, of, hs);
    }

    // out = of @ Wo via MFMA
    convert_bf16<<<dim3((TD_ + 255) / 256), blk, 0, stream>>>(of, of_bf, (int)TD_);
    transpose_convert<<<tcvG, tcvB, 0, stream>>>(Wo, Wtc, D_, D_);
    mfma_gemm<0><<<dim3(D_ / 128, T_ / 128), blk, 0, stream>>>(of_bf, Wtc, out, T_, D_, D_);
}

// Round 7
// 1267.554 us; speedup vs baseline: 7.3024x; 1.1744x over previous
//
#include <hip/hip_runtime.h>
#include <hip/hip_bf16.h>

typedef __hip_bfloat16 bf16;
typedef unsigned short ushort_t;

#define T_  1024
#define D_  2048
#define H_  32
#define HD_ 64

static const size_t TT_ = (size_t)T_ * T_;
static const size_t TD_ = (size_t)T_ * D_;

__device__ __forceinline__ ushort_t f2bf(float v) {
    bf16 b = __float2bfloat16(v);
    return *(ushort_t*)&b;
}
__device__ __forceinline__ float bf2f(ushort_t u) {
    bf16 b = *(bf16*)&u;
    return __bfloat162float(b);
}

typedef __attribute__((ext_vector_type(8))) short frag8;
typedef __attribute__((ext_vector_type(4))) float f32x4;
typedef __attribute__((ext_vector_type(4))) unsigned short u16x4;
typedef __attribute__((ext_vector_type(8))) unsigned short u16x8;

#define MFMA16(a, b, c) __builtin_amdgcn_mfma_f32_16x16x32_bf16((a), (b), (c), 0, 0, 0)

// ---------------------------------------------------------------------------
// MFMA GEMM: C = A[M,K]bf16 @ Bt[N,K]^T. 128x128 tile, BK=32.
// OUT: 0 = f32 row-major [M,N]
//      3 = packed QKV+small: col<2048 -> qh head-major bf16; <4096 -> kh;
//          <6144 -> vt transposed [head][64][T]; >=6144 -> Cout2 f32 [M][128]
// ---------------------------------------------------------------------------
template <int OUT>
__global__ __launch_bounds__(256) void mfma_gemm(
    const ushort_t* __restrict__ A, const ushort_t* __restrict__ Bt,
    void* __restrict__ Cout, void* __restrict__ Cout2, int M, int N, int K)
{
    __shared__ short Al[128 * 32];
    __shared__ short Bl[128 * 32];
    int tid = threadIdx.x;
    int w = tid >> 6, l = tid & 63;
    int row0 = blockIdx.y * 128, col0 = blockIdx.x * 128;
    int mq = (w >> 1) * 64, nq = (w & 1) * 64;
    int lm = l & 15, kq = l >> 4;
    f32x4 acc[4][4] = {};
    const ushort_t* Ap = A + (size_t)row0 * K;
    const ushort_t* Bp = Bt + (size_t)col0 * K;
    for (int kk = 0; kk < K; kk += 32) {
        __syncthreads();
#pragma unroll
        for (int r = 0; r < 2; r++) {
            int c = r * 256 + w * 64 + l;
            int row = c >> 2, kc = (c & 3) * 8;
            const ushort_t* ga = Ap + (size_t)row * K + kk + kc;
            const ushort_t* gb = Bp + (size_t)row * K + kk + kc;
            short* la = Al + (size_t)(r * 256 + w * 64) * 8;
            short* lb = Bl + (size_t)(r * 256 + w * 64) * 8;
            __builtin_amdgcn_global_load_lds((const __attribute__((address_space(1))) void*)ga,
                                             (__attribute__((address_space(3))) void*)la, 16, 0, 0);
            __builtin_amdgcn_global_load_lds((const __attribute__((address_space(1))) void*)gb,
                                             (__attribute__((address_space(3))) void*)lb, 16, 0, 0);
        }
        __builtin_amdgcn_s_waitcnt(0);
        __syncthreads();
        frag8 af[4], bfg[4];
#pragma unroll
        for (int i = 0; i < 4; i++)
            af[i] = *(const frag8*)&Al[(size_t)(mq + i * 16 + lm) * 32 + kq * 8];
#pragma unroll
        for (int j = 0; j < 4; j++)
            bfg[j] = *(const frag8*)&Bl[(size_t)(nq + j * 16 + lm) * 32 + kq * 8];
#pragma unroll
        for (int i = 0; i < 4; i++)
#pragma unroll
            for (int j = 0; j < 4; j++)
                acc[i][j] = MFMA16(af[i], bfg[j], acc[i][j]);
    }
#pragma unroll
    for (int i = 0; i < 4; i++)
#pragma unroll
        for (int j = 0; j < 4; j++)
#pragma unroll
            for (int r = 0; r < 4; r++) {
                int row = row0 + mq + i * 16 + kq * 4 + r;
                int col = col0 + nq + j * 16 + lm;
                float v = acc[i][j][r];
                if (OUT == 0) {
                    ((float*)Cout)[(size_t)row * N + col] = v;
                } else {
                    ushort_t* q = (ushort_t*)Cout;
                    int which = col >> 11, cl = col & 2047;
                    int hd = cl >> 6, d = cl & 63;
                    if (which == 0)
                        q[((size_t)hd * M + row) * 64 + d] = f2bf(v);
                    else if (which == 1)
                        q[(size_t)M * 2048 + ((size_t)hd * M + row) * 64 + d] = f2bf(v);
                    else if (which == 2)
                        q[(size_t)M * 4096 + ((size_t)hd * 64 + d) * M + row] = f2bf(v);
                    else
                        ((float*)Cout2)[(size_t)row * 128 + (col - 6144)] = v;
                }
            }
}

// ---------------------------------------------------------------------------
__global__ void transpose_convert(const float* __restrict__ W, ushort_t* __restrict__ Wt,
                                  int R, int Cc)
{
    __shared__ float tile[32][33];
    int bx = blockIdx.x * 32, by = blockIdx.y * 32;
    int tx = threadIdx.x, ty = threadIdx.y;
    for (int i = ty; i < 32; i += 8)
        tile[i][tx] = W[(size_t)(by + i) * Cc + bx + tx];
    __syncthreads();
    for (int i = ty; i < 32; i += 8)
        Wt[(size_t)(bx + i) * R + by + tx] = f2bf(tile[tx][i]);
}

// pack Ww1^T/Wbt^T/Wg^T (+zero pad) into rows [0..128) of dst[128][2048]
__global__ void pack96(const float* __restrict__ Ww1, const float* __restrict__ Wbt,
                       const float* __restrict__ Wg, ushort_t* __restrict__ dst)
{
    int r = blockIdx.x;
    int k = blockIdx.y * 256 + threadIdx.x;
    float v = 0.f;
    if (r < 32)       v = Ww1[(size_t)k * 32 + r];
    else if (r < 64)  v = Wbt[(size_t)k * 32 + (r - 32)];
    else if (r < 96)  v = Wg[(size_t)k * 32 + (r - 64)];
    dst[(size_t)r * 2048 + k] = f2bf(v);
}

__global__ void convert_bf16(const float* __restrict__ in, ushort_t* __restrict__ out, int n)
{
    int i = blockIdx.x * 256 + threadIdx.x;
    if (i < n) out[i] = f2bf(in[i]);
}

// epilogue of the 96-proj: w1 bf16, beta, G(pre-scan)
__global__ void bg96(const float* __restrict__ s96, const float* __restrict__ bbt,
                     const float* __restrict__ bgp, ushort_t* __restrict__ w1bf,
                     float* __restrict__ betaB, float* __restrict__ Gb)
{
    int idx = blockIdx.x * 256 + threadIdx.x;   // over T_*128
    int t = idx >> 7, o = idx & 127;
    if (o >= 96) return;
    float v = s96[(size_t)t * 128 + o];
    if (o < 32) {
        w1bf[(size_t)t * 32 + o] = f2bf(v);
    } else if (o < 64) {
        float xb = v + bbt[o - 32];
        betaB[(size_t)t * H_ + (o - 32)] = 2.f / (1.f + expf(-xb));
    } else {
        float xg = v + bgp[o - 64];
        Gb[(size_t)t * H_ + (o - 64)] =
            (xg >= 0.f) ? -log1pf(expf(-xg)) : (xg - log1pf(expf(xg)));
    }
}

// parallel inclusive scan of G[:, h] per head. Grid (H_), block 256.
__global__ void scan_g(float* __restrict__ G)
{
    int h = blockIdx.x;
    int tid = threadIdx.x;
    __shared__ float psum[256];
    float v[4];
    float s = 0.f;
#pragma unroll
    for (int r = 0; r < 4; r++) {
        v[r] = G[(size_t)(tid * 4 + r) * H_ + h];
        s += v[r];
    }
    psum[tid] = s;
    __syncthreads();
    for (int off = 1; off < 256; off <<= 1) {
        float t = (tid >= off) ? psum[tid - off] : 0.f;
        __syncthreads();
        psum[tid] += t;
        __syncthreads();
    }
    float run = (tid > 0) ? psum[tid - 1] : 0.f;
#pragma unroll
    for (int r = 0; r < 4; r++) {
        run += v[r];
        G[(size_t)(tid * 4 + r) * H_ + h] = run;
    }
}

// conv(3) + silu + l2norm -> wh bf16 head-major [H][T][64]
__global__ void conv_silu_norm(const float* __restrict__ wr, const float* __restrict__ convw,
                               ushort_t* __restrict__ wh)
{
    int b = blockIdx.x;
    int t = b >> 5, h = b & 31;
    int d = threadIdx.x;
    int c = h * 64 + d;
    float c0 = convw[c * 3 + 0];
    float c1 = convw[c * 3 + 1];
    float c2 = convw[c * 3 + 2];
    float x = c2 * wr[(size_t)t * D_ + c];
    if (t >= 1) x += c1 * wr[(size_t)(t - 1) * D_ + c];
    if (t >= 2) x += c0 * wr[(size_t)(t - 2) * D_ + c];
    float y = x / (1.f + expf(-x));
    float ss = y * y;
    for (int off = 32; off > 0; off >>= 1) ss += __shfl_xor(ss, off, 64);
    wh[((size_t)h * T_ + t) * 64 + d] = f2bf(y * rsqrtf(ss));
}

// ---------------------------------------------------------------------------
// pairdot3_mfma: per lower tile (t0,s0):
//   Lb[t][s] = strict(w_t.w_s)*beta[s]   (bf16 row-major)
//   Ct[s][t] = strict(w_t.k_s)           (bf16 TRANSPOSED [s][t])
//   Em[t][s] = -causal(q_t.w_s)*beta[s]  (bf16 row-major, pre-negated)
// ---------------------------------------------------------------------------
__global__ __launch_bounds__(256) void pairdot3_mfma(
    const ushort_t* __restrict__ qh, const ushort_t* __restrict__ kh,
    const ushort_t* __restrict__ wh, const float* __restrict__ betaB,
    ushort_t* __restrict__ Lb, ushort_t* __restrict__ Ct, ushort_t* __restrict__ Em,
    int hs)
{
    int s0 = blockIdx.x * 64, t0 = blockIdx.y * 64, z = blockIdx.z;
    if (s0 > t0) return;
    int head = hs + z;
    const ushort_t* qb = qh + (size_t)head * T_ * 64;
    const ushort_t* kb = kh + (size_t)head * T_ * 64;
    const ushort_t* wb = wh + (size_t)head * T_ * 64;
    ushort_t* Lz = Lb + (size_t)z * TT_;
    ushort_t* Cz = Ct + (size_t)z * TT_;
    ushort_t* Ez = Em + (size_t)z * TT_;
    int tid = threadIdx.x;
    int w = tid >> 6, l = tid & 63;
    int lm = l & 15, kq = l >> 4;
    int rowA = t0 + w * 16 + lm;
    f32x4 accL[4] = {}, accS[4] = {}, accE[4] = {};
#pragma unroll
    for (int kk = 0; kk < 64; kk += 32) {
        frag8 aw = *(const frag8*)&wb[(size_t)rowA * 64 + kk + kq * 8];
        frag8 aq = *(const frag8*)&qb[(size_t)rowA * 64 + kk + kq * 8];
#pragma unroll
        for (int j = 0; j < 4; j++) {
            int colr = s0 + j * 16 + lm;
            frag8 bw = *(const frag8*)&wb[(size_t)colr * 64 + kk + kq * 8];
            frag8 bk = *(const frag8*)&kb[(size_t)colr * 64 + kk + kq * 8];
            accL[j] = MFMA16(aw, bw, accL[j]);
            accS[j] = MFMA16(aw, bk, accS[j]);
            accE[j] = MFMA16(aq, bw, accE[j]);
        }
    }
    int m0 = w * 16 + kq * 4;
#pragma unroll
    for (int j = 0; j < 4; j++) {
        int s = s0 + j * 16 + lm;
        float beta = betaB[(size_t)s * H_ + head];
        ushort_t cl[4];
#pragma unroll
        for (int r = 0; r < 4; r++) {
            int t = t0 + m0 + r;
            Lz[(size_t)t * T_ + s] = f2bf((s < t) ? accL[j][r] * beta : 0.f);
            Ez[(size_t)t * T_ + s] = f2bf((s <= t) ? -accE[j][r] * beta : 0.f);
            cl[r] = f2bf((s < t) ? accS[j][r] : 0.f);
        }
        *(u16x4*)&Cz[(size_t)s * T_ + t0 + m0] = *(u16x4*)cl;
    }
}

// ---------------------------------------------------------------------------
// diag_inv: invert 64x64 unit-lower diag blocks of (I + Lb); Minv bf16 out.
// ---------------------------------------------------------------------------
__global__ void diag_inv(const ushort_t* __restrict__ Lb, ushort_t* __restrict__ Minv)
{
    int bi = blockIdx.x, z = blockIdx.y;
    const ushort_t* Lh = Lb + (size_t)z * TT_;
    __shared__ float Nb[64][65];
    __shared__ float Xc[64][65];
    int tid = threadIdx.x;
    for (int i = tid; i < 4096; i += 64) {
        int r = i >> 6, c = i & 63;
        Nb[r][c] = (c < r) ? bf2f(Lh[(size_t)(bi * 64 + r) * T_ + bi * 64 + c]) : 0.f;
    }
    __syncthreads();
    int j = tid;
    for (int t = 0; t < 64; t++) {
        float v = (t == j) ? 1.f : 0.f;
        for (int i = j; i < t; i++) v -= Nb[t][i] * Xc[i][j];
        Xc[t][j] = v;
    }
    __syncthreads();
    ushort_t* Mo = Minv + ((size_t)z * 16 + bi) * 4096;
    for (int i = tid; i < 4096; i += 64) Mo[i] = f2bf(Xc[i >> 6][i & 63]);
}

// ---------------------------------------------------------------------------
// solve_mfma v2: block-forward solve for one 64-col strip with LDS-staged
// L and C chunks. Grid (16, NH), block 256.
// ---------------------------------------------------------------------------
__global__ __launch_bounds__(256) void solve_mfma(
    ushort_t* __restrict__ Ct, const ushort_t* __restrict__ Lb,
    const ushort_t* __restrict__ Minv)
{
    int ct = blockIdx.x, z = blockIdx.y;
    ushort_t* Cz = Ct + (size_t)z * TT_;
    const ushort_t* Lz = Lb + (size_t)z * TT_;
    __shared__ ushort_t Cl[64][136];
    __shared__ ushort_t Ll[64][136];
    __shared__ ushort_t Xbt[64][72];
    int tid = threadIdx.x;
    int w = tid >> 6, l = tid & 63;
    int lm = l & 15, kq = l >> 4;
    int s0 = ct * 64;
    int m0 = w * 16 + kq * 4;
    for (int bi = ct; bi < 16; bi++) {
        f32x4 acc[4] = {};
        for (int kkc = s0; kkc < bi * 64; kkc += 128) {
            int len = bi * 64 - kkc; if (len > 128) len = 128;
            int lsh = (len == 128) ? 4 : 3;
            __syncthreads();
            for (int i = tid; i < (64 << lsh); i += 256) {
                int r = i >> lsh, c = (i & ((1 << lsh) - 1)) * 8;
                *(u16x8*)&Cl[r][c] = *(const u16x8*)&Cz[(size_t)(s0 + r) * T_ + kkc + c];
                *(u16x8*)&Ll[r][c] = *(const u16x8*)&Lz[(size_t)(bi * 64 + r) * T_ + kkc + c];
            }
            __syncthreads();
            for (int kk2 = 0; kk2 < len; kk2 += 32) {
                frag8 a = *(const frag8*)&Ll[w * 16 + lm][kk2 + kq * 8];
#pragma unroll
                for (int j = 0; j < 4; j++) {
                    frag8 b = *(const frag8*)&Cl[j * 16 + lm][kk2 + kq * 8];
                    acc[j] = MFMA16(a, b, acc[j]);
                }
            }
        }
        __syncthreads();
#pragma unroll
        for (int j = 0; j < 4; j++) {
            int sc = s0 + j * 16 + lm;
            u16x4 rhs = *(const u16x4*)&Cz[(size_t)sc * T_ + bi * 64 + m0];
            ushort_t xb[4];
#pragma unroll
            for (int r = 0; r < 4; r++) xb[r] = f2bf(bf2f(rhs[r]) - acc[j][r]);
            *(u16x4*)&Xbt[j * 16 + lm][m0] = *(u16x4*)xb;
        }
        __syncthreads();
        f32x4 res[4] = {};
        const ushort_t* Mo = Minv + ((size_t)z * 16 + bi) * 4096;
#pragma unroll
        for (int kk = 0; kk < 64; kk += 32) {
            frag8 a = *(const frag8*)&Mo[(size_t)(w * 16 + lm) * 64 + kk + kq * 8];
#pragma unroll
            for (int j = 0; j < 4; j++) {
                frag8 b = *(const frag8*)&Xbt[j * 16 + lm][kk + kq * 8];
                res[j] = MFMA16(a, b, res[j]);
            }
        }
#pragma unroll
        for (int j = 0; j < 4; j++) {
            int sc = s0 + j * 16 + lm;
            ushort_t cr[4];
#pragma unroll
            for (int r = 0; r < 4; r++) cr[r] = f2bf(res[j][r]);
            *(u16x4*)&Cz[(size_t)sc * T_ + bi * 64 + m0] = *(u16x4*)cr;
        }
        __syncthreads();
    }
}

// ---------------------------------------------------------------------------
// flash_attn v2: LDS-staged K/V/C/Em, online softmax, PV. Grid (16, NH).
// Longest t-tiles dispatched first (tb = 15 - blockIdx.x).
// ---------------------------------------------------------------------------
__global__ __launch_bounds__(256) void flash_attn(
    const ushort_t* __restrict__ qh, const ushort_t* __restrict__ kh,
    const ushort_t* __restrict__ vt, const ushort_t* __restrict__ Em,
    const ushort_t* __restrict__ Ct, const float* __restrict__ Gb,
    float* __restrict__ of, int hs)
{
    int tb = (int)gridDim.x - 1 - (int)blockIdx.x;
    int z = blockIdx.y;
    int t0 = tb * 64;
    int head = hs + z;
    const ushort_t* qb = qh + (size_t)head * T_ * 64;
    const ushort_t* kb = kh + (size_t)head * T_ * 64;
    const ushort_t* vb = vt + (size_t)head * 64 * T_;
    const ushort_t* Ez = Em + (size_t)z * TT_;
    const ushort_t* Cz = Ct + (size_t)z * TT_;
    __shared__ ushort_t Kl[64][72];
    __shared__ ushort_t Vl[64][72];
    __shared__ ushort_t Cl[64][136];
    __shared__ ushort_t El[64][136];
    __shared__ ushort_t Pl[4][16][72];
    int tid = threadIdx.x;
    int w = tid >> 6, l = tid & 63;
    int lm = l & 15, kq = l >> 4;
    int rowA = t0 + w * 16 + lm;
    int m0 = w * 16 + kq * 4;
    frag8 aq0 = *(const frag8*)&qb[(size_t)rowA * 64 + kq * 8];
    frag8 aq1 = *(const frag8*)&qb[(size_t)rowA * 64 + 32 + kq * 8];
    f32x4 o[4] = {};
    float mrow[4], lrow[4];
#pragma unroll
    for (int r = 0; r < 4; r++) { mrow[r] = -1e30f; lrow[r] = 0.f; }
    for (int st = 0; st <= tb; st++) {
        int s0 = st * 64;
        __syncthreads();
        for (int i = tid; i < 512; i += 256) {
            int r = i >> 3, c = (i & 7) * 8;
            *(u16x8*)&Kl[r][c] = *(const u16x8*)&kb[(size_t)(s0 + r) * 64 + c];
            *(u16x8*)&Vl[r][c] = *(const u16x8*)&vb[(size_t)r * T_ + s0 + c];
        }
        __syncthreads();
        f32x4 x[4] = {};
#pragma unroll
        for (int j = 0; j < 4; j++) {
            frag8 b0 = *(const frag8*)&Kl[j * 16 + lm][kq * 8];
            frag8 b1 = *(const frag8*)&Kl[j * 16 + lm][32 + kq * 8];
            x[j] = MFMA16(aq0, b0, x[j]);
            x[j] = MFMA16(aq1, b1, x[j]);
        }
        for (int kkc = s0; kkc < t0 + 64; kkc += 128) {
            int len = t0 + 64 - kkc; if (len > 128) len = 128;
            int lsh = (len == 128) ? 4 : 3;
            __syncthreads();
            for (int i = tid; i < (64 << lsh); i += 256) {
                int r = i >> lsh, c = (i & ((1 << lsh) - 1)) * 8;
                *(u16x8*)&Cl[r][c] = *(const u16x8*)&Cz[(size_t)(s0 + r) * T_ + kkc + c];
                *(u16x8*)&El[r][c] = *(const u16x8*)&Ez[(size_t)(t0 + r) * T_ + kkc + c];
            }
            __syncthreads();
            for (int kk2 = 0; kk2 < len; kk2 += 32) {
                frag8 a = *(const frag8*)&El[w * 16 + lm][kk2 + kq * 8];
#pragma unroll
                for (int j = 0; j < 4; j++) {
                    frag8 b = *(const frag8*)&Cl[j * 16 + lm][kk2 + kq * 8];
                    x[j] = MFMA16(a, b, x[j]);
                }
            }
        }
        float lg[4][4];
#pragma unroll
        for (int j = 0; j < 4; j++) {
            int s = s0 + j * 16 + lm;
            float g = Gb[(size_t)s * H_ + head];
#pragma unroll
            for (int r = 0; r < 4; r++) {
                int t = t0 + m0 + r;
                lg[j][r] = (s <= t) ? (x[j][r] * 0.125f - g) : -1e30f;
            }
        }
        float rmax[4];
#pragma unroll
        for (int r = 0; r < 4; r++)
            rmax[r] = fmaxf(fmaxf(lg[0][r], lg[1][r]), fmaxf(lg[2][r], lg[3][r]));
#pragma unroll
        for (int d = 1; d < 16; d <<= 1)
#pragma unroll
            for (int r = 0; r < 4; r++) rmax[r] = fmaxf(rmax[r], __shfl_xor(rmax[r], d, 64));
        float mnew[4], alpha[4];
#pragma unroll
        for (int r = 0; r < 4; r++) {
            mnew[r] = fmaxf(mrow[r], rmax[r]);
            alpha[r] = __expf(mrow[r] - mnew[r]);
            mrow[r] = mnew[r];
        }
        float rsum[4] = {0.f, 0.f, 0.f, 0.f};
#pragma unroll
        for (int j = 0; j < 4; j++)
#pragma unroll
            for (int r = 0; r < 4; r++) {
                float p = __expf(lg[j][r] - mnew[r]);
                lg[j][r] = p;
                rsum[r] += p;
            }
#pragma unroll
        for (int d = 1; d < 16; d <<= 1)
#pragma unroll
            for (int r = 0; r < 4; r++) rsum[r] += __shfl_xor(rsum[r], d, 64);
#pragma unroll
        for (int r = 0; r < 4; r++) lrow[r] = lrow[r] * alpha[r] + rsum[r];
#pragma unroll
        for (int j = 0; j < 4; j++)
#pragma unroll
            for (int r = 0; r < 4; r++) o[j][r] *= alpha[r];
#pragma unroll
        for (int j = 0; j < 4; j++)
#pragma unroll
            for (int r = 0; r < 4; r++)
                Pl[w][kq * 4 + r][j * 16 + lm] = f2bf(lg[j][r]);
#pragma unroll
        for (int j = 0; j < 4; j++) {
            frag8 b0 = *(const frag8*)&Vl[j * 16 + lm][kq * 8];
            frag8 b1 = *(const frag8*)&Vl[j * 16 + lm][32 + kq * 8];
            frag8 a0 = *(const frag8*)&Pl[w][lm][kq * 8];
            frag8 a1 = *(const frag8*)&Pl[w][lm][32 + kq * 8];
            o[j] = MFMA16(a0, b0, o[j]);
            o[j] = MFMA16(a1, b1, o[j]);
        }
    }
#pragma unroll
    for (int j = 0; j < 4; j++) {
        int col = head * 64 + j * 16 + lm;
#pragma unroll
        for (int r = 0; r < 4; r++) {
            int t = t0 + m0 + r;
            of[(size_t)t * D_ + col] = o[j][r] / lrow[r];
        }
    }
}

// ---------------------------------------------------------------------------
extern "C" void kernel_launch(void* const* d_in, const int* in_sizes, int n_in,
                              void* d_out, int out_size, void* d_ws, size_t ws_size,
                              hipStream_t stream)
{
    const float* h     = (const float*)d_in[0];
    const float* Wq    = (const float*)d_in[1];
    const float* Wk    = (const float*)d_in[2];
    const float* Wv    = (const float*)d_in[3];
    const float* Ww1   = (const float*)d_in[4];
    const float* Ww2   = (const float*)d_in[5];
    const float* convw = (const float*)d_in[6];
    const float* Wbt   = (const float*)d_in[7];
    const float* bbt   = (const float*)d_in[8];
    const float* Wg    = (const float*)d_in[9];
    const float* bgp   = (const float*)d_in[10];
    const float* Wo    = (const float*)d_in[11];
    float* out = (float*)d_out;

    float* ws = (float*)d_ws;
    size_t off = 0;
    auto allocF = [&](size_t nf) { float* p = ws + off; off += (nf + 1023) & ~(size_t)1023; return p; };

    float*    wr    = allocF(TD_);
    float*    of    = allocF(TD_);
    float*    s96   = allocF((size_t)T_ * 128);
    float*    betaB = allocF((size_t)T_ * H_);
    float*    Gb    = allocF((size_t)T_ * H_);
    ushort_t* h_bf  = (ushort_t*)allocF(TD_ / 2);
    ushort_t* of_bf = (ushort_t*)allocF(TD_ / 2);
    ushort_t* w1bf  = (ushort_t*)allocF((size_t)T_ * 32 / 2);
    ushort_t* Ww2t  = (ushort_t*)allocF((size_t)D_ * 32 / 2);
    ushort_t* Wtc   = (ushort_t*)allocF((size_t)6272 * D_ / 2);  // QKV + 96-pack; reused for Wo
    ushort_t* qkv   = (ushort_t*)allocF((size_t)3 * TD_ / 2);
    ushort_t* qh    = qkv;
    ushort_t* kh    = qkv + TD_;
    ushort_t* vt    = qkv + 2 * TD_;
    ushort_t* wh    = (ushort_t*)allocF(TD_ / 2);

    size_t fixedF = off;
    size_t capF = ws_size / 4;
    size_t perHead = 3 * (TT_ / 2) + ((size_t)16 * 4096) / 2 + 4096;
    int NH = 32;
    while (NH > 1 && fixedF + (size_t)NH * perHead > capF) NH >>= 1;
    ushort_t* Lb = (ushort_t*)allocF((size_t)NH * TT_ / 2);
    ushort_t* Ct = (ushort_t*)allocF((size_t)NH * TT_ / 2);
    ushort_t* Em = (ushort_t*)allocF((size_t)NH * TT_ / 2);
    ushort_t* Mv = (ushort_t*)allocF((size_t)NH * 16 * 4096 / 2);

    dim3 blk(256);
    dim3 tcvB(32, 8);
    dim3 tcvG(D_ / 32, D_ / 32);

    // fused QKV + 96-proj via one MFMA GEMM (N = 6272)
    convert_bf16<<<dim3((TD_ + 255) / 256), blk, 0, stream>>>(h, h_bf, (int)TD_);
    transpose_convert<<<tcvG, tcvB, 0, stream>>>(Wq, Wtc, D_, D_);
    transpose_convert<<<tcvG, tcvB, 0, stream>>>(Wk, Wtc + (size_t)D_ * D_, D_, D_);
    transpose_convert<<<tcvG, tcvB, 0, stream>>>(Wv, Wtc + (size_t)2 * D_ * D_, D_, D_);
    pack96<<<dim3(128, 8), blk, 0, stream>>>(Ww1, Wbt, Wg, Wtc + (size_t)3 * D_ * D_);
    mfma_gemm<3><<<dim3(6272 / 128, T_ / 128), blk, 0, stream>>>(
        h_bf, Wtc, qkv, s96, T_, 6272, D_);

    // gates + w path
    bg96<<<dim3(T_ * 128 / 256), blk, 0, stream>>>(s96, bbt, bgp, w1bf, betaB, Gb);
    scan_g<<<dim3(H_), blk, 0, stream>>>(Gb);
    transpose_convert<<<dim3(D_ / 32, 1), tcvB, 0, stream>>>(Ww2, Ww2t, 32, D_);
    mfma_gemm<0><<<dim3(D_ / 128, T_ / 128), blk, 0, stream>>>(
        w1bf, Ww2t, wr, nullptr, T_, D_, 32);
    conv_silu_norm<<<dim3(T_ * H_), dim3(64), 0, stream>>>(wr, convw, wh);

    int nChunks = H_ / NH;
    for (int c = 0; c < nChunks; c++) {
        int hs = c * NH;
        pairdot3_mfma<<<dim3(16, 16, NH), blk, 0, stream>>>(qh, kh, wh, betaB, Lb, Ct, Em, hs);
        diag_inv<<<dim3(16, NH), dim3(64), 0, stream>>>(Lb, Mv);
        solve_mfma<<<dim3(16, NH), blk, 0, stream>>>(Ct, Lb, Mv);
        flash_attn<<<dim3(16, NH), blk, 0, stream>>>(qh, kh, vt, Em, Ct, Gb, of, hs);
    }

    // out = of @ Wo via MFMA
    convert_bf16<<<dim3((TD_ + 255) / 256), blk, 0, stream>>>(of, of_bf, (int)TD_);
    transpose_convert<<<tcvG, tcvB, 0, stream>>>(Wo, Wtc, D_, D_);
    mfma_gemm<0><<<dim3(D_ / 128, T_ / 128), blk, 0, stream>>>(
        of_bf, Wtc, out, nullptr, T_, D_, D_);
}

// Round 8
// 903.058 us; speedup vs baseline: 10.2498x; 1.4036x over previous
//
#include <hip/hip_runtime.h>
#include <hip/hip_bf16.h>

typedef __hip_bfloat16 bf16;
typedef unsigned short ushort_t;

#define T_  1024
#define D_  2048
#define H_  32
#define HD_ 64

static const size_t TT_ = (size_t)T_ * T_;
static const size_t TD_ = (size_t)T_ * D_;

__device__ __forceinline__ ushort_t f2bf(float v) {
    bf16 b = __float2bfloat16(v);
    return *(ushort_t*)&b;
}
__device__ __forceinline__ float bf2f(ushort_t u) {
    bf16 b = *(bf16*)&u;
    return __bfloat162float(b);
}

typedef __attribute__((ext_vector_type(8))) short frag8;
typedef __attribute__((ext_vector_type(4))) float f32x4;
typedef __attribute__((ext_vector_type(4))) unsigned short u16x4;
typedef __attribute__((ext_vector_type(8))) unsigned short u16x8;

#define MFMA16(a, b, c) __builtin_amdgcn_mfma_f32_16x16x32_bf16((a), (b), (c), 0, 0, 0)

// ---------------------------------------------------------------------------
// MFMA GEMM: C = A[M,K]bf16 @ Bt[N,K]^T. 128x128 tile, BK=32.
// OUT: 0 = f32 row-major [M,N]
//      3 = packed QKV+small: col<2048 -> qh head-major bf16; <4096 -> kh;
//          <6144 -> vt transposed [head][64][T]; >=6144 -> Cout2 f32 [M][128]
// ---------------------------------------------------------------------------
template <int OUT>
__global__ __launch_bounds__(256) void mfma_gemm(
    const ushort_t* __restrict__ A, const ushort_t* __restrict__ Bt,
    void* __restrict__ Cout, void* __restrict__ Cout2, int M, int N, int K)
{
    __shared__ short Al[128 * 32];
    __shared__ short Bl[128 * 32];
    int tid = threadIdx.x;
    int w = tid >> 6, l = tid & 63;
    int row0 = blockIdx.y * 128, col0 = blockIdx.x * 128;
    int mq = (w >> 1) * 64, nq = (w & 1) * 64;
    int lm = l & 15, kq = l >> 4;
    f32x4 acc[4][4] = {};
    const ushort_t* Ap = A + (size_t)row0 * K;
    const ushort_t* Bp = Bt + (size_t)col0 * K;
    for (int kk = 0; kk < K; kk += 32) {
        __syncthreads();
#pragma unroll
        for (int r = 0; r < 2; r++) {
            int c = r * 256 + w * 64 + l;
            int row = c >> 2, kc = (c & 3) * 8;
            const ushort_t* ga = Ap + (size_t)row * K + kk + kc;
            const ushort_t* gb = Bp + (size_t)row * K + kk + kc;
            short* la = Al + (size_t)(r * 256 + w * 64) * 8;
            short* lb = Bl + (size_t)(r * 256 + w * 64) * 8;
            __builtin_amdgcn_global_load_lds((const __attribute__((address_space(1))) void*)ga,
                                             (__attribute__((address_space(3))) void*)la, 16, 0, 0);
            __builtin_amdgcn_global_load_lds((const __attribute__((address_space(1))) void*)gb,
                                             (__attribute__((address_space(3))) void*)lb, 16, 0, 0);
        }
        __builtin_amdgcn_s_waitcnt(0);
        __syncthreads();
        frag8 af[4], bfg[4];
#pragma unroll
        for (int i = 0; i < 4; i++)
            af[i] = *(const frag8*)&Al[(size_t)(mq + i * 16 + lm) * 32 + kq * 8];
#pragma unroll
        for (int j = 0; j < 4; j++)
            bfg[j] = *(const frag8*)&Bl[(size_t)(nq + j * 16 + lm) * 32 + kq * 8];
#pragma unroll
        for (int i = 0; i < 4; i++)
#pragma unroll
            for (int j = 0; j < 4; j++)
                acc[i][j] = MFMA16(af[i], bfg[j], acc[i][j]);
    }
#pragma unroll
    for (int i = 0; i < 4; i++)
#pragma unroll
        for (int j = 0; j < 4; j++)
#pragma unroll
            for (int r = 0; r < 4; r++) {
                int row = row0 + mq + i * 16 + kq * 4 + r;
                int col = col0 + nq + j * 16 + lm;
                float v = acc[i][j][r];
                if (OUT == 0) {
                    ((float*)Cout)[(size_t)row * N + col] = v;
                } else {
                    ushort_t* q = (ushort_t*)Cout;
                    int which = col >> 11, cl = col & 2047;
                    int hd = cl >> 6, d = cl & 63;
                    if (which == 0)
                        q[((size_t)hd * M + row) * 64 + d] = f2bf(v);
                    else if (which == 1)
                        q[(size_t)M * 2048 + ((size_t)hd * M + row) * 64 + d] = f2bf(v);
                    else if (which == 2)
                        q[(size_t)M * 4096 + ((size_t)hd * 64 + d) * M + row] = f2bf(v);
                    else
                        ((float*)Cout2)[(size_t)row * 128 + (col - 6144)] = v;
                }
            }
}

// ---------------------------------------------------------------------------
__global__ void transpose_convert(const float* __restrict__ W, ushort_t* __restrict__ Wt,
                                  int R, int Cc)
{
    __shared__ float tile[32][33];
    int bx = blockIdx.x * 32, by = blockIdx.y * 32;
    int tx = threadIdx.x, ty = threadIdx.y;
    for (int i = ty; i < 32; i += 8)
        tile[i][tx] = W[(size_t)(by + i) * Cc + bx + tx];
    __syncthreads();
    for (int i = ty; i < 32; i += 8)
        Wt[(size_t)(bx + i) * R + by + tx] = f2bf(tile[tx][i]);
}

// pack Ww1^T/Wbt^T/Wg^T (+zero pad) into rows [0..128) of dst[128][2048]
__global__ void pack96(const float* __restrict__ Ww1, const float* __restrict__ Wbt,
                       const float* __restrict__ Wg, ushort_t* __restrict__ dst)
{
    int r = blockIdx.x;
    int k = blockIdx.y * 256 + threadIdx.x;
    float v = 0.f;
    if (r < 32)       v = Ww1[(size_t)k * 32 + r];
    else if (r < 64)  v = Wbt[(size_t)k * 32 + (r - 32)];
    else if (r < 96)  v = Wg[(size_t)k * 32 + (r - 64)];
    dst[(size_t)r * 2048 + k] = f2bf(v);
}

__global__ void convert_bf16(const float* __restrict__ in, ushort_t* __restrict__ out, int n)
{
    int i = blockIdx.x * 256 + threadIdx.x;
    if (i < n) out[i] = f2bf(in[i]);
}

// epilogue of the 96-proj: w1 bf16, beta, G(pre-scan)
__global__ void bg96(const float* __restrict__ s96, const float* __restrict__ bbt,
                     const float* __restrict__ bgp, ushort_t* __restrict__ w1bf,
                     float* __restrict__ betaB, float* __restrict__ Gb)
{
    int idx = blockIdx.x * 256 + threadIdx.x;   // over T_*128
    int t = idx >> 7, o = idx & 127;
    if (o >= 96) return;
    float v = s96[(size_t)t * 128 + o];
    if (o < 32) {
        w1bf[(size_t)t * 32 + o] = f2bf(v);
    } else if (o < 64) {
        float xb = v + bbt[o - 32];
        betaB[(size_t)t * H_ + (o - 32)] = 2.f / (1.f + expf(-xb));
    } else {
        float xg = v + bgp[o - 64];
        Gb[(size_t)t * H_ + (o - 64)] =
            (xg >= 0.f) ? -log1pf(expf(-xg)) : (xg - log1pf(expf(xg)));
    }
}

// parallel inclusive scan of G[:, h] per head. Grid (H_), block 256.
__global__ void scan_g(float* __restrict__ G)
{
    int h = blockIdx.x;
    int tid = threadIdx.x;
    __shared__ float psum[256];
    float v[4];
    float s = 0.f;
#pragma unroll
    for (int r = 0; r < 4; r++) {
        v[r] = G[(size_t)(tid * 4 + r) * H_ + h];
        s += v[r];
    }
    psum[tid] = s;
    __syncthreads();
    for (int off = 1; off < 256; off <<= 1) {
        float t = (tid >= off) ? psum[tid - off] : 0.f;
        __syncthreads();
        psum[tid] += t;
        __syncthreads();
    }
    float run = (tid > 0) ? psum[tid - 1] : 0.f;
#pragma unroll
    for (int r = 0; r < 4; r++) {
        run += v[r];
        G[(size_t)(tid * 4 + r) * H_ + h] = run;
    }
}

// conv(3) + silu + l2norm -> wh bf16 head-major [H][T][64]
__global__ void conv_silu_norm(const float* __restrict__ wr, const float* __restrict__ convw,
                               ushort_t* __restrict__ wh)
{
    int b = blockIdx.x;
    int t = b >> 5, h = b & 31;
    int d = threadIdx.x;
    int c = h * 64 + d;
    float c0 = convw[c * 3 + 0];
    float c1 = convw[c * 3 + 1];
    float c2 = convw[c * 3 + 2];
    float x = c2 * wr[(size_t)t * D_ + c];
    if (t >= 1) x += c1 * wr[(size_t)(t - 1) * D_ + c];
    if (t >= 2) x += c0 * wr[(size_t)(t - 2) * D_ + c];
    float y = x / (1.f + expf(-x));
    float ss = y * y;
    for (int off = 32; off > 0; off >>= 1) ss += __shfl_xor(ss, off, 64);
    wh[((size_t)h * T_ + t) * 64 + d] = f2bf(y * rsqrtf(ss));
}

// ---------------------------------------------------------------------------
// pairdotLC: per lower tile (t0,s0):
//   Lb[t][s] = strict(w_t.w_s)*beta[s]   (bf16 row-major, into ELb)
//   Ct[s][t] = strict(w_t.k_s)           (bf16 TRANSPOSED [s][t])
// ---------------------------------------------------------------------------
__global__ __launch_bounds__(256) void pairdotLC(
    const ushort_t* __restrict__ kh, const ushort_t* __restrict__ wh,
    const float* __restrict__ betaB,
    ushort_t* __restrict__ ELb, ushort_t* __restrict__ Ct, int hs)
{
    int s0 = blockIdx.x * 64, t0 = blockIdx.y * 64, z = blockIdx.z;
    if (s0 > t0) return;
    int head = hs + z;
    const ushort_t* kb = kh + (size_t)head * T_ * 64;
    const ushort_t* wb = wh + (size_t)head * T_ * 64;
    ushort_t* Lz = ELb + (size_t)z * TT_;
    ushort_t* Cz = Ct + (size_t)z * TT_;
    int tid = threadIdx.x;
    int w = tid >> 6, l = tid & 63;
    int lm = l & 15, kq = l >> 4;
    int rowA = t0 + w * 16 + lm;
    f32x4 accL[4] = {}, accS[4] = {};
#pragma unroll
    for (int kk = 0; kk < 64; kk += 32) {
        frag8 aw = *(const frag8*)&wb[(size_t)rowA * 64 + kk + kq * 8];
#pragma unroll
        for (int j = 0; j < 4; j++) {
            int colr = s0 + j * 16 + lm;
            frag8 bw = *(const frag8*)&wb[(size_t)colr * 64 + kk + kq * 8];
            frag8 bk = *(const frag8*)&kb[(size_t)colr * 64 + kk + kq * 8];
            accL[j] = MFMA16(aw, bw, accL[j]);
            accS[j] = MFMA16(aw, bk, accS[j]);
        }
    }
    int m0 = w * 16 + kq * 4;
#pragma unroll
    for (int j = 0; j < 4; j++) {
        int s = s0 + j * 16 + lm;
        float beta = betaB[(size_t)s * H_ + head];
        ushort_t cl[4];
#pragma unroll
        for (int r = 0; r < 4; r++) {
            int t = t0 + m0 + r;
            Lz[(size_t)t * T_ + s] = f2bf((s < t) ? accL[j][r] * beta : 0.f);
            cl[r] = f2bf((s < t) ? accS[j][r] : 0.f);
        }
        *(u16x4*)&Cz[(size_t)s * T_ + t0 + m0] = *(u16x4*)cl;
    }
}

// pairdotE: Em[t][s] = -causal(q_t.w_s)*beta[s] into ELb (L is dead post-solve)
__global__ __launch_bounds__(256) void pairdotE(
    const ushort_t* __restrict__ qh, const ushort_t* __restrict__ wh,
    const float* __restrict__ betaB, ushort_t* __restrict__ ELb, int hs)
{
    int s0 = blockIdx.x * 64, t0 = blockIdx.y * 64, z = blockIdx.z;
    if (s0 > t0) return;
    int head = hs + z;
    const ushort_t* qb = qh + (size_t)head * T_ * 64;
    const ushort_t* wb = wh + (size_t)head * T_ * 64;
    ushort_t* Ez = ELb + (size_t)z * TT_;
    int tid = threadIdx.x;
    int w = tid >> 6, l = tid & 63;
    int lm = l & 15, kq = l >> 4;
    int rowA = t0 + w * 16 + lm;
    f32x4 accE[4] = {};
#pragma unroll
    for (int kk = 0; kk < 64; kk += 32) {
        frag8 aq = *(const frag8*)&qb[(size_t)rowA * 64 + kk + kq * 8];
#pragma unroll
        for (int j = 0; j < 4; j++) {
            frag8 bw = *(const frag8*)&wb[(size_t)(s0 + j * 16 + lm) * 64 + kk + kq * 8];
            accE[j] = MFMA16(aq, bw, accE[j]);
        }
    }
    int m0 = w * 16 + kq * 4;
#pragma unroll
    for (int j = 0; j < 4; j++) {
        int s = s0 + j * 16 + lm;
        float beta = betaB[(size_t)s * H_ + head];
#pragma unroll
        for (int r = 0; r < 4; r++) {
            int t = t0 + m0 + r;
            Ez[(size_t)t * T_ + s] = f2bf((s <= t) ? -accE[j][r] * beta : 0.f);
        }
    }
}

// ---------------------------------------------------------------------------
// diag_inv: invert 64x64 unit-lower diag blocks of (I + L); Minv bf16 out.
// ---------------------------------------------------------------------------
__global__ void diag_inv(const ushort_t* __restrict__ Lb, ushort_t* __restrict__ Minv)
{
    int bi = blockIdx.x, z = blockIdx.y;
    const ushort_t* Lh = Lb + (size_t)z * TT_;
    __shared__ float Nb[64][65];
    __shared__ float Xc[64][65];
    int tid = threadIdx.x;
    for (int i = tid; i < 4096; i += 64) {
        int r = i >> 6, c = i & 63;
        Nb[r][c] = (c < r) ? bf2f(Lh[(size_t)(bi * 64 + r) * T_ + bi * 64 + c]) : 0.f;
    }
    __syncthreads();
    int j = tid;
    for (int t = 0; t < 64; t++) {
        float v = (t == j) ? 1.f : 0.f;
        for (int i = j; i < t; i++) v -= Nb[t][i] * Xc[i][j];
        Xc[t][j] = v;
    }
    __syncthreads();
    ushort_t* Mo = Minv + ((size_t)z * 16 + bi) * 4096;
    for (int i = tid; i < 4096; i += 64) Mo[i] = f2bf(Xc[i >> 6][i & 63]);
}

// ---------------------------------------------------------------------------
// solve_mfma: block-forward solve for one 64-col strip with LDS-staged
// L and C chunks. Grid (16, NH), block 256.
// ---------------------------------------------------------------------------
__global__ __launch_bounds__(256) void solve_mfma(
    ushort_t* __restrict__ Ct, const ushort_t* __restrict__ Lb,
    const ushort_t* __restrict__ Minv)
{
    int ct = blockIdx.x, z = blockIdx.y;
    ushort_t* Cz = Ct + (size_t)z * TT_;
    const ushort_t* Lz = Lb + (size_t)z * TT_;
    __shared__ ushort_t Cl[64][136];
    __shared__ ushort_t Ll[64][136];
    __shared__ ushort_t Xbt[64][72];
    int tid = threadIdx.x;
    int w = tid >> 6, l = tid & 63;
    int lm = l & 15, kq = l >> 4;
    int s0 = ct * 64;
    int m0 = w * 16 + kq * 4;
    for (int bi = ct; bi < 16; bi++) {
        f32x4 acc[4] = {};
        for (int kkc = s0; kkc < bi * 64; kkc += 128) {
            int len = bi * 64 - kkc; if (len > 128) len = 128;
            int lsh = (len == 128) ? 4 : 3;
            __syncthreads();
            for (int i = tid; i < (64 << lsh); i += 256) {
                int r = i >> lsh, c = (i & ((1 << lsh) - 1)) * 8;
                *(u16x8*)&Cl[r][c] = *(const u16x8*)&Cz[(size_t)(s0 + r) * T_ + kkc + c];
                *(u16x8*)&Ll[r][c] = *(const u16x8*)&Lz[(size_t)(bi * 64 + r) * T_ + kkc + c];
            }
            __syncthreads();
            for (int kk2 = 0; kk2 < len; kk2 += 32) {
                frag8 a = *(const frag8*)&Ll[w * 16 + lm][kk2 + kq * 8];
#pragma unroll
                for (int j = 0; j < 4; j++) {
                    frag8 b = *(const frag8*)&Cl[j * 16 + lm][kk2 + kq * 8];
                    acc[j] = MFMA16(a, b, acc[j]);
                }
            }
        }
        __syncthreads();
#pragma unroll
        for (int j = 0; j < 4; j++) {
            int sc = s0 + j * 16 + lm;
            u16x4 rhs = *(const u16x4*)&Cz[(size_t)sc * T_ + bi * 64 + m0];
            ushort_t xb[4];
#pragma unroll
            for (int r = 0; r < 4; r++) xb[r] = f2bf(bf2f(rhs[r]) - acc[j][r]);
            *(u16x4*)&Xbt[j * 16 + lm][m0] = *(u16x4*)xb;
        }
        __syncthreads();
        f32x4 res[4] = {};
        const ushort_t* Mo = Minv + ((size_t)z * 16 + bi) * 4096;
#pragma unroll
        for (int kk = 0; kk < 64; kk += 32) {
            frag8 a = *(const frag8*)&Mo[(size_t)(w * 16 + lm) * 64 + kk + kq * 8];
#pragma unroll
            for (int j = 0; j < 4; j++) {
                frag8 b = *(const frag8*)&Xbt[j * 16 + lm][kk + kq * 8];
                res[j] = MFMA16(a, b, res[j]);
            }
        }
#pragma unroll
        for (int j = 0; j < 4; j++) {
            int sc = s0 + j * 16 + lm;
            ushort_t cr[4];
#pragma unroll
            for (int r = 0; r < 4; r++) cr[r] = f2bf(res[j][r]);
            *(u16x4*)&Cz[(size_t)sc * T_ + bi * 64 + m0] = *(u16x4*)cr;
        }
        __syncthreads();
    }
}

// ---------------------------------------------------------------------------
// flash_attn v3: LDS-staged K/V/C/Em (64-wide chunks, 46 KB LDS -> 3 blk/CU),
// online softmax, PV; of written bf16. Grid (16, NH), longest t first.
// ---------------------------------------------------------------------------
__global__ __launch_bounds__(256) void flash_attn(
    const ushort_t* __restrict__ qh, const ushort_t* __restrict__ kh,
    const ushort_t* __restrict__ vt, const ushort_t* __restrict__ Em,
    const ushort_t* __restrict__ Ct, const float* __restrict__ Gb,
    ushort_t* __restrict__ of, int hs)
{
    int tb = (int)gridDim.x - 1 - (int)blockIdx.x;
    int z = blockIdx.y;
    int t0 = tb * 64;
    int head = hs + z;
    const ushort_t* qb = qh + (size_t)head * T_ * 64;
    const ushort_t* kb = kh + (size_t)head * T_ * 64;
    const ushort_t* vb = vt + (size_t)head * 64 * T_;
    const ushort_t* Ez = Em + (size_t)z * TT_;
    const ushort_t* Cz = Ct + (size_t)z * TT_;
    __shared__ ushort_t Kl[64][72];
    __shared__ ushort_t Vl[64][72];
    __shared__ ushort_t Cl[64][72];
    __shared__ ushort_t El[64][72];
    __shared__ ushort_t Pl[4][16][72];
    int tid = threadIdx.x;
    int w = tid >> 6, l = tid & 63;
    int lm = l & 15, kq = l >> 4;
    int rowA = t0 + w * 16 + lm;
    int m0 = w * 16 + kq * 4;
    frag8 aq0 = *(const frag8*)&qb[(size_t)rowA * 64 + kq * 8];
    frag8 aq1 = *(const frag8*)&qb[(size_t)rowA * 64 + 32 + kq * 8];
    f32x4 o[4] = {};
    float mrow[4], lrow[4];
#pragma unroll
    for (int r = 0; r < 4; r++) { mrow[r] = -1e30f; lrow[r] = 0.f; }
    for (int st = 0; st <= tb; st++) {
        int s0 = st * 64;
        __syncthreads();
        for (int i = tid; i < 512; i += 256) {
            int r = i >> 3, c = (i & 7) * 8;
            *(u16x8*)&Kl[r][c] = *(const u16x8*)&kb[(size_t)(s0 + r) * 64 + c];
            *(u16x8*)&Vl[r][c] = *(const u16x8*)&vb[(size_t)r * T_ + s0 + c];
        }
        __syncthreads();
        f32x4 x[4] = {};
#pragma unroll
        for (int j = 0; j < 4; j++) {
            frag8 b0 = *(const frag8*)&Kl[j * 16 + lm][kq * 8];
            frag8 b1 = *(const frag8*)&Kl[j * 16 + lm][32 + kq * 8];
            x[j] = MFMA16(aq0, b0, x[j]);
            x[j] = MFMA16(aq1, b1, x[j]);
        }
        // correction: += (-E*beta)[t,k] * C[k,s], k in [s0, t0+64), 64-wide chunks
        for (int kkc = s0; kkc < t0 + 64; kkc += 64) {
            __syncthreads();
            for (int i = tid; i < 512; i += 256) {
                int r = i >> 3, c = (i & 7) * 8;
                *(u16x8*)&Cl[r][c] = *(const u16x8*)&Cz[(size_t)(s0 + r) * T_ + kkc + c];
                *(u16x8*)&El[r][c] = *(const u16x8*)&Ez[(size_t)(t0 + r) * T_ + kkc + c];
            }
            __syncthreads();
#pragma unroll
            for (int kk2 = 0; kk2 < 64; kk2 += 32) {
                frag8 a = *(const frag8*)&El[w * 16 + lm][kk2 + kq * 8];
#pragma unroll
                for (int j = 0; j < 4; j++) {
                    frag8 b = *(const frag8*)&Cl[j * 16 + lm][kk2 + kq * 8];
                    x[j] = MFMA16(a, b, x[j]);
                }
            }
        }
        float lg[4][4];
#pragma unroll
        for (int j = 0; j < 4; j++) {
            int s = s0 + j * 16 + lm;
            float g = Gb[(size_t)s * H_ + head];
#pragma unroll
            for (int r = 0; r < 4; r++) {
                int t = t0 + m0 + r;
                lg[j][r] = (s <= t) ? (x[j][r] * 0.125f - g) : -1e30f;
            }
        }
        float rmax[4];
#pragma unroll
        for (int r = 0; r < 4; r++)
            rmax[r] = fmaxf(fmaxf(lg[0][r], lg[1][r]), fmaxf(lg[2][r], lg[3][r]));
#pragma unroll
        for (int d = 1; d < 16; d <<= 1)
#pragma unroll
            for (int r = 0; r < 4; r++) rmax[r] = fmaxf(rmax[r], __shfl_xor(rmax[r], d, 64));
        float mnew[4], alpha[4];
#pragma unroll
        for (int r = 0; r < 4; r++) {
            mnew[r] = fmaxf(mrow[r], rmax[r]);
            alpha[r] = __expf(mrow[r] - mnew[r]);
            mrow[r] = mnew[r];
        }
        float rsum[4] = {0.f, 0.f, 0.f, 0.f};
#pragma unroll
        for (int j = 0; j < 4; j++)
#pragma unroll
            for (int r = 0; r < 4; r++) {
                float p = __expf(lg[j][r] - mnew[r]);
                lg[j][r] = p;
                rsum[r] += p;
            }
#pragma unroll
        for (int d = 1; d < 16; d <<= 1)
#pragma unroll
            for (int r = 0; r < 4; r++) rsum[r] += __shfl_xor(rsum[r], d, 64);
#pragma unroll
        for (int r = 0; r < 4; r++) lrow[r] = lrow[r] * alpha[r] + rsum[r];
#pragma unroll
        for (int j = 0; j < 4; j++)
#pragma unroll
            for (int r = 0; r < 4; r++) o[j][r] *= alpha[r];
#pragma unroll
        for (int j = 0; j < 4; j++)
#pragma unroll
            for (int r = 0; r < 4; r++)
                Pl[w][kq * 4 + r][j * 16 + lm] = f2bf(lg[j][r]);
#pragma unroll
        for (int j = 0; j < 4; j++) {
            frag8 b0 = *(const frag8*)&Vl[j * 16 + lm][kq * 8];
            frag8 b1 = *(const frag8*)&Vl[j * 16 + lm][32 + kq * 8];
            frag8 a0 = *(const frag8*)&Pl[w][lm][kq * 8];
            frag8 a1 = *(const frag8*)&Pl[w][lm][32 + kq * 8];
            o[j] = MFMA16(a0, b0, o[j]);
            o[j] = MFMA16(a1, b1, o[j]);
        }
    }
#pragma unroll
    for (int j = 0; j < 4; j++) {
        int col = head * 64 + j * 16 + lm;
#pragma unroll
        for (int r = 0; r < 4; r++) {
            int t = t0 + m0 + r;
            of[(size_t)t * D_ + col] = f2bf(o[j][r] / lrow[r]);
        }
    }
}

// ---------------------------------------------------------------------------
extern "C" void kernel_launch(void* const* d_in, const int* in_sizes, int n_in,
                              void* d_out, int out_size, void* d_ws, size_t ws_size,
                              hipStream_t stream)
{
    const float* h     = (const float*)d_in[0];
    const float* Wq    = (const float*)d_in[1];
    const float* Wk    = (const float*)d_in[2];
    const float* Wv    = (const float*)d_in[3];
    const float* Ww1   = (const float*)d_in[4];
    const float* Ww2   = (const float*)d_in[5];
    const float* convw = (const float*)d_in[6];
    const float* Wbt   = (const float*)d_in[7];
    const float* bbt   = (const float*)d_in[8];
    const float* Wg    = (const float*)d_in[9];
    const float* bgp   = (const float*)d_in[10];
    const float* Wo    = (const float*)d_in[11];
    float* out = (float*)d_out;

    float* ws = (float*)d_ws;
    size_t off = 0;
    auto allocF = [&](size_t nf) { float* p = ws + off; off += (nf + 1023) & ~(size_t)1023; return p; };

    float*    wr    = allocF(TD_);
    float*    s96   = allocF((size_t)T_ * 128);
    float*    betaB = allocF((size_t)T_ * H_);
    float*    Gb    = allocF((size_t)T_ * H_);
    ushort_t* h_bf  = (ushort_t*)allocF(TD_ / 2);   // reused as of_bf after QKV GEMM
    ushort_t* of_bf = h_bf;
    ushort_t* w1bf  = (ushort_t*)allocF((size_t)T_ * 32 / 2);
    ushort_t* Ww2t  = (ushort_t*)allocF((size_t)D_ * 32 / 2);
    ushort_t* Wtc   = (ushort_t*)allocF((size_t)6272 * D_ / 2);  // QKV + 96-pack; reused for Wo
    ushort_t* qkv   = (ushort_t*)allocF((size_t)3 * TD_ / 2);
    ushort_t* qh    = qkv;
    ushort_t* kh    = qkv + TD_;
    ushort_t* vt    = qkv + 2 * TD_;
    ushort_t* wh    = (ushort_t*)allocF(TD_ / 2);

    size_t fixedF = off;
    size_t capF = ws_size / 4;
    size_t perHead = TT_ + ((size_t)16 * 4096) / 2 + 2048;  // ELb+Ct (bf16) + Mv
    int NH = 32;
    while (NH > 1 && fixedF + (size_t)NH * perHead > capF) NH >>= 1;
    ushort_t* ELb = (ushort_t*)allocF((size_t)NH * TT_ / 2);  // L then Em
    ushort_t* Ct  = (ushort_t*)allocF((size_t)NH * TT_ / 2);
    ushort_t* Mv  = (ushort_t*)allocF((size_t)NH * 16 * 4096 / 2);

    dim3 blk(256);
    dim3 tcvB(32, 8);
    dim3 tcvG(D_ / 32, D_ / 32);

    // fused QKV + 96-proj via one MFMA GEMM (N = 6272)
    convert_bf16<<<dim3((TD_ + 255) / 256), blk, 0, stream>>>(h, h_bf, (int)TD_);
    transpose_convert<<<tcvG, tcvB, 0, stream>>>(Wq, Wtc, D_, D_);
    transpose_convert<<<tcvG, tcvB, 0, stream>>>(Wk, Wtc + (size_t)D_ * D_, D_, D_);
    transpose_convert<<<tcvG, tcvB, 0, stream>>>(Wv, Wtc + (size_t)2 * D_ * D_, D_, D_);
    pack96<<<dim3(128, 8), blk, 0, stream>>>(Ww1, Wbt, Wg, Wtc + (size_t)3 * D_ * D_);
    mfma_gemm<3><<<dim3(6272 / 128, T_ / 128), blk, 0, stream>>>(
        h_bf, Wtc, qkv, s96, T_, 6272, D_);

    // gates + w path
    bg96<<<dim3(T_ * 128 / 256), blk, 0, stream>>>(s96, bbt, bgp, w1bf, betaB, Gb);
    scan_g<<<dim3(H_), blk, 0, stream>>>(Gb);
    transpose_convert<<<dim3(D_ / 32, 1), tcvB, 0, stream>>>(Ww2, Ww2t, 32, D_);
    mfma_gemm<0><<<dim3(D_ / 128, T_ / 128), blk, 0, stream>>>(
        w1bf, Ww2t, wr, nullptr, T_, D_, 32);
    conv_silu_norm<<<dim3(T_ * H_), dim3(64), 0, stream>>>(wr, convw, wh);

    int nChunks = H_ / NH;
    for (int c = 0; c < nChunks; c++) {
        int hs = c * NH;
        pairdotLC<<<dim3(16, 16, NH), blk, 0, stream>>>(kh, wh, betaB, ELb, Ct, hs);
        diag_inv<<<dim3(16, NH), dim3(64), 0, stream>>>(ELb, Mv);
        solve_mfma<<<dim3(16, NH), blk, 0, stream>>>(Ct, ELb, Mv);
        pairdotE<<<dim3(16, 16, NH), blk, 0, stream>>>(qh, wh, betaB, ELb, hs);
        flash_attn<<<dim3(16, NH), blk, 0, stream>>>(qh, kh, vt, ELb, Ct, Gb, of_bf, hs);
    }

    // out = of @ Wo via MFMA
    transpose_convert<<<tcvG, tcvB, 0, stream>>>(Wo, Wtc, D_, D_);
    mfma_gemm<0><<<dim3(D_ / 128, T_ / 128), blk, 0, stream>>>(
        of_bf, Wtc, out, nullptr, T_, D_, D_);
}

// Round 9
// 900.338 us; speedup vs baseline: 10.2808x; 1.0030x over previous
//
#include <hip/hip_runtime.h>
#include <hip/hip_bf16.h>

typedef __hip_bfloat16 bf16;
typedef unsigned short ushort_t;

#define T_  1024
#define D_  2048
#define H_  32
#define HD_ 64

static const size_t TT_ = (size_t)T_ * T_;
static const size_t TD_ = (size_t)T_ * D_;

__device__ __forceinline__ ushort_t f2bf(float v) {
    bf16 b = __float2bfloat16(v);
    return *(ushort_t*)&b;
}
__device__ __forceinline__ float bf2f(ushort_t u) {
    bf16 b = *(bf16*)&u;
    return __bfloat162float(b);
}

typedef __attribute__((ext_vector_type(8))) short frag8;
typedef __attribute__((ext_vector_type(4))) float f32x4;
typedef __attribute__((ext_vector_type(4))) unsigned short u16x4;
typedef __attribute__((ext_vector_type(8))) unsigned short u16x8;

#define MFMA16(a, b, c) __builtin_amdgcn_mfma_f32_16x16x32_bf16((a), (b), (c), 0, 0, 0)

// ---------------------------------------------------------------------------
// MFMA GEMM: C = A[M,K]bf16 @ Bt[N,K]^T. 128x128 tile, BK=32.
// OUT: 0 = f32 row-major [M,N]
//      3 = packed QKV+small: col<2048 -> qh head-major bf16; <4096 -> kh;
//          <6144 -> vt transposed [head][64][T]; >=6144 -> Cout2 f32 [M][128]
// ---------------------------------------------------------------------------
template <int OUT>
__global__ __launch_bounds__(256) void mfma_gemm(
    const ushort_t* __restrict__ A, const ushort_t* __restrict__ Bt,
    void* __restrict__ Cout, void* __restrict__ Cout2, int M, int N, int K)
{
    __shared__ short Al[128 * 32];
    __shared__ short Bl[128 * 32];
    int tid = threadIdx.x;
    int w = tid >> 6, l = tid & 63;
    int row0 = blockIdx.y * 128, col0 = blockIdx.x * 128;
    int mq = (w >> 1) * 64, nq = (w & 1) * 64;
    int lm = l & 15, kq = l >> 4;
    f32x4 acc[4][4] = {};
    const ushort_t* Ap = A + (size_t)row0 * K;
    const ushort_t* Bp = Bt + (size_t)col0 * K;
    for (int kk = 0; kk < K; kk += 32) {
        __syncthreads();
#pragma unroll
        for (int r = 0; r < 2; r++) {
            int c = r * 256 + w * 64 + l;
            int row = c >> 2, kc = (c & 3) * 8;
            const ushort_t* ga = Ap + (size_t)row * K + kk + kc;
            const ushort_t* gb = Bp + (size_t)row * K + kk + kc;
            short* la = Al + (size_t)(r * 256 + w * 64) * 8;
            short* lb = Bl + (size_t)(r * 256 + w * 64) * 8;
            __builtin_amdgcn_global_load_lds((const __attribute__((address_space(1))) void*)ga,
                                             (__attribute__((address_space(3))) void*)la, 16, 0, 0);
            __builtin_amdgcn_global_load_lds((const __attribute__((address_space(1))) void*)gb,
                                             (__attribute__((address_space(3))) void*)lb, 16, 0, 0);
        }
        __builtin_amdgcn_s_waitcnt(0);
        __syncthreads();
        frag8 af[4], bfg[4];
#pragma unroll
        for (int i = 0; i < 4; i++)
            af[i] = *(const frag8*)&Al[(size_t)(mq + i * 16 + lm) * 32 + kq * 8];
#pragma unroll
        for (int j = 0; j < 4; j++)
            bfg[j] = *(const frag8*)&Bl[(size_t)(nq + j * 16 + lm) * 32 + kq * 8];
#pragma unroll
        for (int i = 0; i < 4; i++)
#pragma unroll
            for (int j = 0; j < 4; j++)
                acc[i][j] = MFMA16(af[i], bfg[j], acc[i][j]);
    }
#pragma unroll
    for (int i = 0; i < 4; i++)
#pragma unroll
        for (int j = 0; j < 4; j++)
#pragma unroll
            for (int r = 0; r < 4; r++) {
                int row = row0 + mq + i * 16 + kq * 4 + r;
                int col = col0 + nq + j * 16 + lm;
                float v = acc[i][j][r];
                if (OUT == 0) {
                    ((float*)Cout)[(size_t)row * N + col] = v;
                } else {
                    ushort_t* q = (ushort_t*)Cout;
                    int which = col >> 11, cl = col & 2047;
                    int hd = cl >> 6, d = cl & 63;
                    if (which == 0)
                        q[((size_t)hd * M + row) * 64 + d] = f2bf(v);
                    else if (which == 1)
                        q[(size_t)M * 2048 + ((size_t)hd * M + row) * 64 + d] = f2bf(v);
                    else if (which == 2)
                        q[(size_t)M * 4096 + ((size_t)hd * 64 + d) * M + row] = f2bf(v);
                    else
                        ((float*)Cout2)[(size_t)row * 128 + (col - 6144)] = v;
                }
            }
}

// ---------------------------------------------------------------------------
__global__ void transpose_convert(const float* __restrict__ W, ushort_t* __restrict__ Wt,
                                  int R, int Cc)
{
    __shared__ float tile[32][33];
    int bx = blockIdx.x * 32, by = blockIdx.y * 32;
    int tx = threadIdx.x, ty = threadIdx.y;
    for (int i = ty; i < 32; i += 8)
        tile[i][tx] = W[(size_t)(by + i) * Cc + bx + tx];
    __syncthreads();
    for (int i = ty; i < 32; i += 8)
        Wt[(size_t)(bx + i) * R + by + tx] = f2bf(tile[tx][i]);
}

// pack Ww1^T/Wbt^T/Wg^T (+zero pad) into rows [0..128) of dst[128][2048]
__global__ void pack96(const float* __restrict__ Ww1, const float* __restrict__ Wbt,
                       const float* __restrict__ Wg, ushort_t* __restrict__ dst)
{
    int r = blockIdx.x;
    int k = blockIdx.y * 256 + threadIdx.x;
    float v = 0.f;
    if (r < 32)       v = Ww1[(size_t)k * 32 + r];
    else if (r < 64)  v = Wbt[(size_t)k * 32 + (r - 32)];
    else if (r < 96)  v = Wg[(size_t)k * 32 + (r - 64)];
    dst[(size_t)r * 2048 + k] = f2bf(v);
}

__global__ void convert_bf16(const float* __restrict__ in, ushort_t* __restrict__ out, int n)
{
    int i = blockIdx.x * 256 + threadIdx.x;
    if (i < n) out[i] = f2bf(in[i]);
}

// epilogue of the 96-proj: w1 bf16, beta, G(pre-scan)
__global__ void bg96(const float* __restrict__ s96, const float* __restrict__ bbt,
                     const float* __restrict__ bgp, ushort_t* __restrict__ w1bf,
                     float* __restrict__ betaB, float* __restrict__ Gb)
{
    int idx = blockIdx.x * 256 + threadIdx.x;   // over T_*128
    int t = idx >> 7, o = idx & 127;
    if (o >= 96) return;
    float v = s96[(size_t)t * 128 + o];
    if (o < 32) {
        w1bf[(size_t)t * 32 + o] = f2bf(v);
    } else if (o < 64) {
        float xb = v + bbt[o - 32];
        betaB[(size_t)t * H_ + (o - 32)] = 2.f / (1.f + expf(-xb));
    } else {
        float xg = v + bgp[o - 64];
        Gb[(size_t)t * H_ + (o - 64)] =
            (xg >= 0.f) ? -log1pf(expf(-xg)) : (xg - log1pf(expf(xg)));
    }
}

// parallel inclusive scan of G[:, h] per head. Grid (H_), block 256.
__global__ void scan_g(float* __restrict__ G)
{
    int h = blockIdx.x;
    int tid = threadIdx.x;
    __shared__ float psum[256];
    float v[4];
    float s = 0.f;
#pragma unroll
    for (int r = 0; r < 4; r++) {
        v[r] = G[(size_t)(tid * 4 + r) * H_ + h];
        s += v[r];
    }
    psum[tid] = s;
    __syncthreads();
    for (int off = 1; off < 256; off <<= 1) {
        float t = (tid >= off) ? psum[tid - off] : 0.f;
        __syncthreads();
        psum[tid] += t;
        __syncthreads();
    }
    float run = (tid > 0) ? psum[tid - 1] : 0.f;
#pragma unroll
    for (int r = 0; r < 4; r++) {
        run += v[r];
        G[(size_t)(tid * 4 + r) * H_ + h] = run;
    }
}

// conv(3) + silu + l2norm -> wh bf16 head-major [H][T][64]
__global__ void conv_silu_norm(const float* __restrict__ wr, const float* __restrict__ convw,
                               ushort_t* __restrict__ wh)
{
    int b = blockIdx.x;
    int t = b >> 5, h = b & 31;
    int d = threadIdx.x;
    int c = h * 64 + d;
    float c0 = convw[c * 3 + 0];
    float c1 = convw[c * 3 + 1];
    float c2 = convw[c * 3 + 2];
    float x = c2 * wr[(size_t)t * D_ + c];
    if (t >= 1) x += c1 * wr[(size_t)(t - 1) * D_ + c];
    if (t >= 2) x += c0 * wr[(size_t)(t - 2) * D_ + c];
    float y = x / (1.f + expf(-x));
    float ss = y * y;
    for (int off = 32; off > 0; off >>= 1) ss += __shfl_xor(ss, off, 64);
    wh[((size_t)h * T_ + t) * 64 + d] = f2bf(y * rsqrtf(ss));
}

// ---------------------------------------------------------------------------
// pairdotLC: per lower tile (t0,s0):
//   L[t][s]  = strict(w_t.w_s)*beta[s]   (bf16 row-major, into ELb)
//   Ct[s][t] = strict(w_t.k_s)           (bf16 TRANSPOSED [s][t])
// ---------------------------------------------------------------------------
__global__ __launch_bounds__(256) void pairdotLC(
    const ushort_t* __restrict__ kh, const ushort_t* __restrict__ wh,
    const float* __restrict__ betaB,
    ushort_t* __restrict__ ELb, ushort_t* __restrict__ Ct, int hs)
{
    int s0 = blockIdx.x * 64, t0 = blockIdx.y * 64, z = blockIdx.z;
    if (s0 > t0) return;
    int head = hs + z;
    const ushort_t* kb = kh + (size_t)head * T_ * 64;
    const ushort_t* wb = wh + (size_t)head * T_ * 64;
    ushort_t* Lz = ELb + (size_t)z * TT_;
    ushort_t* Cz = Ct + (size_t)z * TT_;
    int tid = threadIdx.x;
    int w = tid >> 6, l = tid & 63;
    int lm = l & 15, kq = l >> 4;
    int rowA = t0 + w * 16 + lm;
    f32x4 accL[4] = {}, accS[4] = {};
#pragma unroll
    for (int kk = 0; kk < 64; kk += 32) {
        frag8 aw = *(const frag8*)&wb[(size_t)rowA * 64 + kk + kq * 8];
#pragma unroll
        for (int j = 0; j < 4; j++) {
            int colr = s0 + j * 16 + lm;
            frag8 bw = *(const frag8*)&wb[(size_t)colr * 64 + kk + kq * 8];
            frag8 bk = *(const frag8*)&kb[(size_t)colr * 64 + kk + kq * 8];
            accL[j] = MFMA16(aw, bw, accL[j]);
            accS[j] = MFMA16(aw, bk, accS[j]);
        }
    }
    int m0 = w * 16 + kq * 4;
#pragma unroll
    for (int j = 0; j < 4; j++) {
        int s = s0 + j * 16 + lm;
        float beta = betaB[(size_t)s * H_ + head];
        ushort_t cl[4];
#pragma unroll
        for (int r = 0; r < 4; r++) {
            int t = t0 + m0 + r;
            Lz[(size_t)t * T_ + s] = f2bf((s < t) ? accL[j][r] * beta : 0.f);
            cl[r] = f2bf((s < t) ? accS[j][r] : 0.f);
        }
        *(u16x4*)&Cz[(size_t)s * T_ + t0 + m0] = *(u16x4*)cl;
    }
}

// ---------------------------------------------------------------------------
// diag_inv: invert 64x64 unit-lower diag blocks of (I + L); Minv bf16 out.
// ---------------------------------------------------------------------------
__global__ void diag_inv(const ushort_t* __restrict__ Lb, ushort_t* __restrict__ Minv)
{
    int bi = blockIdx.x, z = blockIdx.y;
    const ushort_t* Lh = Lb + (size_t)z * TT_;
    __shared__ float Nb[64][65];
    __shared__ float Xc[64][65];
    int tid = threadIdx.x;
    for (int i = tid; i < 4096; i += 64) {
        int r = i >> 6, c = i & 63;
        Nb[r][c] = (c < r) ? bf2f(Lh[(size_t)(bi * 64 + r) * T_ + bi * 64 + c]) : 0.f;
    }
    __syncthreads();
    int j = tid;
    for (int t = 0; t < 64; t++) {
        float v = (t == j) ? 1.f : 0.f;
        for (int i = j; i < t; i++) v -= Nb[t][i] * Xc[i][j];
        Xc[t][j] = v;
    }
    __syncthreads();
    ushort_t* Mo = Minv + ((size_t)z * 16 + bi) * 4096;
    for (int i = tid; i < 4096; i += 64) Mo[i] = f2bf(Xc[i >> 6][i & 63]);
}

// ---------------------------------------------------------------------------
// solve_mfma: block-forward solve for one 64-col strip with LDS-staged
// L and C chunks. Grid (16, NH), block 256.
// ---------------------------------------------------------------------------
__global__ __launch_bounds__(256) void solve_mfma(
    ushort_t* __restrict__ Ct, const ushort_t* __restrict__ Lb,
    const ushort_t* __restrict__ Minv)
{
    int ct = blockIdx.x, z = blockIdx.y;
    ushort_t* Cz = Ct + (size_t)z * TT_;
    const ushort_t* Lz = Lb + (size_t)z * TT_;
    __shared__ ushort_t Cl[64][136];
    __shared__ ushort_t Ll[64][136];
    __shared__ ushort_t Xbt[64][72];
    int tid = threadIdx.x;
    int w = tid >> 6, l = tid & 63;
    int lm = l & 15, kq = l >> 4;
    int s0 = ct * 64;
    int m0 = w * 16 + kq * 4;
    for (int bi = ct; bi < 16; bi++) {
        f32x4 acc[4] = {};
        for (int kkc = s0; kkc < bi * 64; kkc += 128) {
            int len = bi * 64 - kkc; if (len > 128) len = 128;
            int lsh = (len == 128) ? 4 : 3;
            __syncthreads();
            for (int i = tid; i < (64 << lsh); i += 256) {
                int r = i >> lsh, c = (i & ((1 << lsh) - 1)) * 8;
                *(u16x8*)&Cl[r][c] = *(const u16x8*)&Cz[(size_t)(s0 + r) * T_ + kkc + c];
                *(u16x8*)&Ll[r][c] = *(const u16x8*)&Lz[(size_t)(bi * 64 + r) * T_ + kkc + c];
            }
            __syncthreads();
            for (int kk2 = 0; kk2 < len; kk2 += 32) {
                frag8 a = *(const frag8*)&Ll[w * 16 + lm][kk2 + kq * 8];
#pragma unroll
                for (int j = 0; j < 4; j++) {
                    frag8 b = *(const frag8*)&Cl[j * 16 + lm][kk2 + kq * 8];
                    acc[j] = MFMA16(a, b, acc[j]);
                }
            }
        }
        __syncthreads();
#pragma unroll
        for (int j = 0; j < 4; j++) {
            int sc = s0 + j * 16 + lm;
            u16x4 rhs = *(const u16x4*)&Cz[(size_t)sc * T_ + bi * 64 + m0];
            ushort_t xb[4];
#pragma unroll
            for (int r = 0; r < 4; r++) xb[r] = f2bf(bf2f(rhs[r]) - acc[j][r]);
            *(u16x4*)&Xbt[j * 16 + lm][m0] = *(u16x4*)xb;
        }
        __syncthreads();
        f32x4 res[4] = {};
        const ushort_t* Mo = Minv + ((size_t)z * 16 + bi) * 4096;
#pragma unroll
        for (int kk = 0; kk < 64; kk += 32) {
            frag8 a = *(const frag8*)&Mo[(size_t)(w * 16 + lm) * 64 + kk + kq * 8];
#pragma unroll
            for (int j = 0; j < 4; j++) {
                frag8 b = *(const frag8*)&Xbt[j * 16 + lm][kk + kq * 8];
                res[j] = MFMA16(a, b, res[j]);
            }
        }
#pragma unroll
        for (int j = 0; j < 4; j++) {
            int sc = s0 + j * 16 + lm;
            ushort_t cr[4];
#pragma unroll
            for (int r = 0; r < 4; r++) cr[r] = f2bf(res[j][r]);
            *(u16x4*)&Cz[(size_t)sc * T_ + bi * 64 + m0] = *(u16x4*)cr;
        }
        __syncthreads();
    }
}

// ---------------------------------------------------------------------------
// flash_split: one (t-tile, s-tile, head) per block. Computes
//   x = q.k^T + sum_k Em[t,k] C[k,s]  with Em computed on the fly from q,w,beta
// then single-tile softmax partial (m, l, unnormalized O) -> Op/ml buffers.
// Grid (16, 16, NH) with st>tb early-out. Block 256 (4 waves x 16 t-rows).
// ---------------------------------------------------------------------------
__global__ __launch_bounds__(256) void flash_split(
    const ushort_t* __restrict__ qh, const ushort_t* __restrict__ kh,
    const ushort_t* __restrict__ vt, const ushort_t* __restrict__ wh,
    const ushort_t* __restrict__ Ct, const float* __restrict__ betaB,
    const float* __restrict__ Gb, ushort_t* __restrict__ Op,
    float* __restrict__ ml, int hs)
{
    int st = blockIdx.x, tb = blockIdx.y, z = blockIdx.z;
    if (st > tb) return;
    int t0 = tb * 64, s0 = st * 64;
    int head = hs + z;
    const ushort_t* qb = qh + (size_t)head * T_ * 64;
    const ushort_t* kb = kh + (size_t)head * T_ * 64;
    const ushort_t* vb = vt + (size_t)head * 64 * T_;
    const ushort_t* wb = wh + (size_t)head * T_ * 64;
    const ushort_t* Cz = Ct + (size_t)z * TT_;
    __shared__ ushort_t Kl[64][72];
    __shared__ ushort_t Vl[64][72];
    __shared__ ushort_t Wl[64][72];
    __shared__ ushort_t Cl[64][72];
    __shared__ ushort_t Pl[4][16][72];
    int tid = threadIdx.x;
    int w = tid >> 6, l = tid & 63;
    int lm = l & 15, kq = l >> 4;
    int rowA = t0 + w * 16 + lm;
    int m0 = w * 16 + kq * 4;
    // stage K (rows s0..s0+63) and V^T (d rows, cols s0..s0+63)
    for (int i = tid; i < 512; i += 256) {
        int r = i >> 3, c = (i & 7) * 8;
        *(u16x8*)&Kl[r][c] = *(const u16x8*)&kb[(size_t)(s0 + r) * 64 + c];
        *(u16x8*)&Vl[r][c] = *(const u16x8*)&vb[(size_t)r * T_ + s0 + c];
    }
    frag8 aq0 = *(const frag8*)&qb[(size_t)rowA * 64 + kq * 8];
    frag8 aq1 = *(const frag8*)&qb[(size_t)rowA * 64 + 32 + kq * 8];
    __syncthreads();
    f32x4 x[4] = {};
#pragma unroll
    for (int j = 0; j < 4; j++) {
        frag8 b0 = *(const frag8*)&Kl[j * 16 + lm][kq * 8];
        frag8 b1 = *(const frag8*)&Kl[j * 16 + lm][32 + kq * 8];
        x[j] = MFMA16(aq0, b0, x[j]);
        x[j] = MFMA16(aq1, b1, x[j]);
    }
    // correction: x += sum over k-chunks of Em(t,k) * C(k,s)
    for (int kc = s0; kc < t0 + 64; kc += 64) {
        __syncthreads();
        for (int i = tid; i < 512; i += 256) {
            int r = i >> 3, c = (i & 7) * 8;
            *(u16x8*)&Wl[r][c] = *(const u16x8*)&wb[(size_t)(kc + r) * 64 + c];
            *(u16x8*)&Cl[r][c] = *(const u16x8*)&Cz[(size_t)(s0 + r) * T_ + kc + c];
        }
        __syncthreads();
        // Eq = q . w^T for this k-chunk (C-layout), then mask * (-beta) -> slab
        f32x4 eq[4] = {};
#pragma unroll
        for (int jj = 0; jj < 4; jj++) {
            frag8 b0 = *(const frag8*)&Wl[jj * 16 + lm][kq * 8];
            frag8 b1 = *(const frag8*)&Wl[jj * 16 + lm][32 + kq * 8];
            eq[jj] = MFMA16(aq0, b0, eq[jj]);
            eq[jj] = MFMA16(aq1, b1, eq[jj]);
        }
#pragma unroll
        for (int jj = 0; jj < 4; jj++) {
            int k = kc + jj * 16 + lm;
            float beta = betaB[(size_t)k * H_ + head];
#pragma unroll
            for (int r = 0; r < 4; r++) {
                int t = t0 + m0 + r;
                float v = (k <= t) ? -eq[jj][r] * beta : 0.f;
                Pl[w][kq * 4 + r][jj * 16 + lm] = f2bf(v);
            }
        }
        // same-wave slab write/read: no barrier needed
#pragma unroll
        for (int kk2 = 0; kk2 < 64; kk2 += 32) {
            frag8 a = *(const frag8*)&Pl[w][lm][kk2 + kq * 8];
#pragma unroll
            for (int j = 0; j < 4; j++) {
                frag8 b = *(const frag8*)&Cl[j * 16 + lm][kk2 + kq * 8];
                x[j] = MFMA16(a, b, x[j]);
            }
        }
    }
    // single-tile softmax partial
    float lg[4][4];
#pragma unroll
    for (int j = 0; j < 4; j++) {
        int s = s0 + j * 16 + lm;
        float g = Gb[(size_t)s * H_ + head];
#pragma unroll
        for (int r = 0; r < 4; r++) {
            int t = t0 + m0 + r;
            lg[j][r] = (s <= t) ? (x[j][r] * 0.125f - g) : -1e30f;
        }
    }
    float mrow[4];
#pragma unroll
    for (int r = 0; r < 4; r++)
        mrow[r] = fmaxf(fmaxf(lg[0][r], lg[1][r]), fmaxf(lg[2][r], lg[3][r]));
#pragma unroll
    for (int d = 1; d < 16; d <<= 1)
#pragma unroll
        for (int r = 0; r < 4; r++) mrow[r] = fmaxf(mrow[r], __shfl_xor(mrow[r], d, 64));
    float lrow[4] = {0.f, 0.f, 0.f, 0.f};
#pragma unroll
    for (int j = 0; j < 4; j++)
#pragma unroll
        for (int r = 0; r < 4; r++) {
            float p = __expf(lg[j][r] - mrow[r]);
            lg[j][r] = p;
            lrow[r] += p;
        }
#pragma unroll
    for (int d = 1; d < 16; d <<= 1)
#pragma unroll
        for (int r = 0; r < 4; r++) lrow[r] += __shfl_xor(lrow[r], d, 64);
    // P -> slab, O = P @ V
#pragma unroll
    for (int j = 0; j < 4; j++)
#pragma unroll
        for (int r = 0; r < 4; r++)
            Pl[w][kq * 4 + r][j * 16 + lm] = f2bf(lg[j][r]);
    f32x4 o[4] = {};
#pragma unroll
    for (int j = 0; j < 4; j++) {
        frag8 b0 = *(const frag8*)&Vl[j * 16 + lm][kq * 8];
        frag8 b1 = *(const frag8*)&Vl[j * 16 + lm][32 + kq * 8];
        frag8 a0 = *(const frag8*)&Pl[w][lm][kq * 8];
        frag8 a1 = *(const frag8*)&Pl[w][lm][32 + kq * 8];
        o[j] = MFMA16(a0, b0, o[j]);
        o[j] = MFMA16(a1, b1, o[j]);
    }
    // write partial O (unnormalized, bf16) + m/l
    size_t pbase = (((size_t)z * 16 + tb) * 16 + st) * 4096;
#pragma unroll
    for (int j = 0; j < 4; j++)
#pragma unroll
        for (int r = 0; r < 4; r++)
            Op[pbase + (size_t)(m0 + r) * 64 + j * 16 + lm] = f2bf(o[j][r]);
    if (lm == 0) {
        size_t mbase = (((size_t)z * 16 + tb) * 16 + st) * 128;
#pragma unroll
        for (int r = 0; r < 4; r++) {
            ml[mbase + m0 + r] = mrow[r];
            ml[mbase + 64 + m0 + r] = lrow[r];
        }
    }
}

// ---------------------------------------------------------------------------
// combine: merge <=16 partials per (t-tile, head) -> of bf16.
// Grid (16, NH), block 256: thread = (row = tid>>2, colgroup = (tid&3)*16).
// ---------------------------------------------------------------------------
__global__ __launch_bounds__(256) void combine(
    const ushort_t* __restrict__ Op, const float* __restrict__ ml,
    ushort_t* __restrict__ of, int hs)
{
    int tb = blockIdx.x, z = blockIdx.y;
    int head = hs + z;
    int tid = threadIdx.x;
    int row = tid >> 2, cg = (tid & 3) * 16;
    size_t mb0 = (((size_t)z * 16 + tb) * 16) * 128;
    float M = -1e30f;
    for (int st = 0; st <= tb; st++)
        M = fmaxf(M, ml[mb0 + (size_t)st * 128 + row]);
    float acc[16] = {};
    float lsum = 0.f;
    for (int st = 0; st <= tb; st++) {
        float mp = ml[mb0 + (size_t)st * 128 + row];
        float lp = ml[mb0 + (size_t)st * 128 + 64 + row];
        float sc = __expf(mp - M);
        lsum += lp * sc;
        const ushort_t* op = Op + (((size_t)z * 16 + tb) * 16 + st) * 4096 + (size_t)row * 64 + cg;
#pragma unroll
        for (int i = 0; i < 16; i++) acc[i] += bf2f(op[i]) * sc;
    }
    float inv = 1.f / lsum;
    int t = tb * 64 + row;
    ushort_t* dst = of + (size_t)t * D_ + (size_t)head * 64 + cg;
#pragma unroll
    for (int i = 0; i < 16; i++) dst[i] = f2bf(acc[i] * inv);
}

// ---------------------------------------------------------------------------
extern "C" void kernel_launch(void* const* d_in, const int* in_sizes, int n_in,
                              void* d_out, int out_size, void* d_ws, size_t ws_size,
                              hipStream_t stream)
{
    const float* h     = (const float*)d_in[0];
    const float* Wq    = (const float*)d_in[1];
    const float* Wk    = (const float*)d_in[2];
    const float* Wv    = (const float*)d_in[3];
    const float* Ww1   = (const float*)d_in[4];
    const float* Ww2   = (const float*)d_in[5];
    const float* convw = (const float*)d_in[6];
    const float* Wbt   = (const float*)d_in[7];
    const float* bbt   = (const float*)d_in[8];
    const float* Wg    = (const float*)d_in[9];
    const float* bgp   = (const float*)d_in[10];
    const float* Wo    = (const float*)d_in[11];
    float* out = (float*)d_out;

    float* ws = (float*)d_ws;
    size_t off = 0;
    auto allocF = [&](size_t nf) { float* p = ws + off; off += (nf + 1023) & ~(size_t)1023; return p; };

    float*    wr    = allocF(TD_);
    float*    s96   = allocF((size_t)T_ * 128);
    float*    betaB = allocF((size_t)T_ * H_);
    float*    Gb    = allocF((size_t)T_ * H_);
    ushort_t* h_bf  = (ushort_t*)allocF(TD_ / 2);   // reused as of_bf after QKV GEMM
    ushort_t* of_bf = h_bf;
    ushort_t* w1bf  = (ushort_t*)allocF((size_t)T_ * 32 / 2);
    ushort_t* Ww2t  = (ushort_t*)allocF((size_t)D_ * 32 / 2);
    ushort_t* Wtc   = (ushort_t*)allocF((size_t)6272 * D_ / 2);  // QKV + 96-pack; reused for Wo
    ushort_t* qkv   = (ushort_t*)allocF((size_t)3 * TD_ / 2);
    ushort_t* qh    = qkv;
    ushort_t* kh    = qkv + TD_;
    ushort_t* vt    = qkv + 2 * TD_;
    ushort_t* wh    = (ushort_t*)allocF(TD_ / 2);

    size_t fixedF = off;
    size_t capF = ws_size / 4;
    // perHead: ELb (TT_ bf16, reused as Op partials) + Ct (TT_ bf16) + Mv + ml
    size_t perHead = TT_ + ((size_t)16 * 4096) / 2 + (size_t)16 * 16 * 128 + 2048;
    int NH = 32;
    while (NH > 1 && fixedF + (size_t)NH * perHead > capF) NH >>= 1;
    ushort_t* ELb = (ushort_t*)allocF((size_t)NH * TT_ / 2);  // L, then Op partials
    ushort_t* Ct  = (ushort_t*)allocF((size_t)NH * TT_ / 2);
    ushort_t* Mv  = (ushort_t*)allocF((size_t)NH * 16 * 4096 / 2);
    float*    mlB = allocF((size_t)NH * 16 * 16 * 128);

    dim3 blk(256);
    dim3 tcvB(32, 8);
    dim3 tcvG(D_ / 32, D_ / 32);

    // fused QKV + 96-proj via one MFMA GEMM (N = 6272)
    convert_bf16<<<dim3((TD_ + 255) / 256), blk, 0, stream>>>(h, h_bf, (int)TD_);
    transpose_convert<<<tcvG, tcvB, 0, stream>>>(Wq, Wtc, D_, D_);
    transpose_convert<<<tcvG, tcvB, 0, stream>>>(Wk, Wtc + (size_t)D_ * D_, D_, D_);
    transpose_convert<<<tcvG, tcvB, 0, stream>>>(Wv, Wtc + (size_t)2 * D_ * D_, D_, D_);
    pack96<<<dim3(128, 8), blk, 0, stream>>>(Ww1, Wbt, Wg, Wtc + (size_t)3 * D_ * D_);
    mfma_gemm<3><<<dim3(6272 / 128, T_ / 128), blk, 0, stream>>>(
        h_bf, Wtc, qkv, s96, T_, 6272, D_);

    // gates + w path
    bg96<<<dim3(T_ * 128 / 256), blk, 0, stream>>>(s96, bbt, bgp, w1bf, betaB, Gb);
    scan_g<<<dim3(H_), blk, 0, stream>>>(Gb);
    transpose_convert<<<dim3(D_ / 32, 1), tcvB, 0, stream>>>(Ww2, Ww2t, 32, D_);
    mfma_gemm<0><<<dim3(D_ / 128, T_ / 128), blk, 0, stream>>>(
        w1bf, Ww2t, wr, nullptr, T_, D_, 32);
    conv_silu_norm<<<dim3(T_ * H_), dim3(64), 0, stream>>>(wr, convw, wh);

    int nChunks = H_ / NH;
    for (int c = 0; c < nChunks; c++) {
        int hs = c * NH;
        pairdotLC<<<dim3(16, 16, NH), blk, 0, stream>>>(kh, wh, betaB, ELb, Ct, hs);
        diag_inv<<<dim3(16, NH), dim3(64), 0, stream>>>(ELb, Mv);
        solve_mfma<<<dim3(16, NH), blk, 0, stream>>>(Ct, ELb, Mv);
        // ELb (L) dead now -> reuse as Op partial buffer
        flash_split<<<dim3(16, 16, NH), blk, 0, stream>>>(
            qh, kh, vt, wh, Ct, betaB, Gb, ELb, mlB, hs);
        combine<<<dim3(16, NH), blk, 0, stream>>>(ELb, mlB, of_bf, hs);
    }

    // out = of @ Wo via MFMA
    transpose_convert<<<tcvG, tcvB, 0, stream>>>(Wo, Wtc, D_, D_);
    mfma_gemm<0><<<dim3(D_ / 128, T_ / 128), blk, 0, stream>>>(
        of_bf, Wtc, out, nullptr, T_, D_, D_);
}

// Round 10
// 882.922 us; speedup vs baseline: 10.4836x; 1.0197x over previous
//
#include <hip/hip_runtime.h>
#include <hip/hip_bf16.h>

typedef __hip_bfloat16 bf16;
typedef unsigned short ushort_t;

#define T_  1024
#define D_  2048
#define H_  32
#define HD_ 64

static const size_t TT_ = (size_t)T_ * T_;
static const size_t TD_ = (size_t)T_ * D_;

__device__ __forceinline__ ushort_t f2bf(float v) {
    bf16 b = __float2bfloat16(v);
    return *(ushort_t*)&b;
}
__device__ __forceinline__ float bf2f(ushort_t u) {
    bf16 b = *(bf16*)&u;
    return __bfloat162float(b);
}

typedef __attribute__((ext_vector_type(8))) short frag8;
typedef __attribute__((ext_vector_type(4))) float f32x4;
typedef __attribute__((ext_vector_type(4))) unsigned short u16x4;
typedef __attribute__((ext_vector_type(8))) unsigned short u16x8;

#define MFMA16(a, b, c) __builtin_amdgcn_mfma_f32_16x16x32_bf16((a), (b), (c), 0, 0, 0)

// ---------------------------------------------------------------------------
// MFMA GEMM: C = A[M,K]bf16 @ Bt[N,K]^T. 128x128 tile, BK=32.
// OUT: 0 = f32 row-major [M,N]
//      3 = packed QKV+small: col<2048 -> qh head-major bf16; <4096 -> kh;
//          <6144 -> vt transposed [head][64][T]; >=6144 -> Cout2 f32 [M][128]
// ---------------------------------------------------------------------------
template <int OUT>
__global__ __launch_bounds__(256) void mfma_gemm(
    const ushort_t* __restrict__ A, const ushort_t* __restrict__ Bt,
    void* __restrict__ Cout, void* __restrict__ Cout2, int M, int N, int K)
{
    __shared__ short Al[128 * 32];
    __shared__ short Bl[128 * 32];
    int tid = threadIdx.x;
    int w = tid >> 6, l = tid & 63;
    int row0 = blockIdx.y * 128, col0 = blockIdx.x * 128;
    int mq = (w >> 1) * 64, nq = (w & 1) * 64;
    int lm = l & 15, kq = l >> 4;
    f32x4 acc[4][4] = {};
    const ushort_t* Ap = A + (size_t)row0 * K;
    const ushort_t* Bp = Bt + (size_t)col0 * K;
    for (int kk = 0; kk < K; kk += 32) {
        __syncthreads();
#pragma unroll
        for (int r = 0; r < 2; r++) {
            int c = r * 256 + w * 64 + l;
            int row = c >> 2, kc = (c & 3) * 8;
            const ushort_t* ga = Ap + (size_t)row * K + kk + kc;
            const ushort_t* gb = Bp + (size_t)row * K + kk + kc;
            short* la = Al + (size_t)(r * 256 + w * 64) * 8;
            short* lb = Bl + (size_t)(r * 256 + w * 64) * 8;
            __builtin_amdgcn_global_load_lds((const __attribute__((address_space(1))) void*)ga,
                                             (__attribute__((address_space(3))) void*)la, 16, 0, 0);
            __builtin_amdgcn_global_load_lds((const __attribute__((address_space(1))) void*)gb,
                                             (__attribute__((address_space(3))) void*)lb, 16, 0, 0);
        }
        __builtin_amdgcn_s_waitcnt(0);
        __syncthreads();
        frag8 af[4], bfg[4];
#pragma unroll
        for (int i = 0; i < 4; i++)
            af[i] = *(const frag8*)&Al[(size_t)(mq + i * 16 + lm) * 32 + kq * 8];
#pragma unroll
        for (int j = 0; j < 4; j++)
            bfg[j] = *(const frag8*)&Bl[(size_t)(nq + j * 16 + lm) * 32 + kq * 8];
#pragma unroll
        for (int i = 0; i < 4; i++)
#pragma unroll
            for (int j = 0; j < 4; j++)
                acc[i][j] = MFMA16(af[i], bfg[j], acc[i][j]);
    }
#pragma unroll
    for (int i = 0; i < 4; i++)
#pragma unroll
        for (int j = 0; j < 4; j++)
#pragma unroll
            for (int r = 0; r < 4; r++) {
                int row = row0 + mq + i * 16 + kq * 4 + r;
                int col = col0 + nq + j * 16 + lm;
                float v = acc[i][j][r];
                if (OUT == 0) {
                    ((float*)Cout)[(size_t)row * N + col] = v;
                } else {
                    ushort_t* q = (ushort_t*)Cout;
                    int which = col >> 11, cl = col & 2047;
                    int hd = cl >> 6, d = cl & 63;
                    if (which == 0)
                        q[((size_t)hd * M + row) * 64 + d] = f2bf(v);
                    else if (which == 1)
                        q[(size_t)M * 2048 + ((size_t)hd * M + row) * 64 + d] = f2bf(v);
                    else if (which == 2)
                        q[(size_t)M * 4096 + ((size_t)hd * 64 + d) * M + row] = f2bf(v);
                    else
                        ((float*)Cout2)[(size_t)row * 128 + (col - 6144)] = v;
                }
            }
}

// ---------------------------------------------------------------------------
__global__ void transpose_convert(const float* __restrict__ W, ushort_t* __restrict__ Wt,
                                  int R, int Cc)
{
    __shared__ float tile[32][33];
    int bx = blockIdx.x * 32, by = blockIdx.y * 32;
    int tx = threadIdx.x, ty = threadIdx.y;
    for (int i = ty; i < 32; i += 8)
        tile[i][tx] = W[(size_t)(by + i) * Cc + bx + tx];
    __syncthreads();
    for (int i = ty; i < 32; i += 8)
        Wt[(size_t)(bx + i) * R + by + tx] = f2bf(tile[tx][i]);
}

// pack Ww1^T/Wbt^T/Wg^T (+zero pad) into rows [0..128) of dst[128][2048]
__global__ void pack96(const float* __restrict__ Ww1, const float* __restrict__ Wbt,
                       const float* __restrict__ Wg, ushort_t* __restrict__ dst)
{
    int r = blockIdx.x;
    int k = blockIdx.y * 256 + threadIdx.x;
    float v = 0.f;
    if (r < 32)       v = Ww1[(size_t)k * 32 + r];
    else if (r < 64)  v = Wbt[(size_t)k * 32 + (r - 32)];
    else if (r < 96)  v = Wg[(size_t)k * 32 + (r - 64)];
    dst[(size_t)r * 2048 + k] = f2bf(v);
}

__global__ void convert_bf16(const float* __restrict__ in, ushort_t* __restrict__ out, int n)
{
    int i = blockIdx.x * 256 + threadIdx.x;
    if (i < n) out[i] = f2bf(in[i]);
}

// epilogue of the 96-proj: w1 bf16, beta, G(pre-scan)
__global__ void bg96(const float* __restrict__ s96, const float* __restrict__ bbt,
                     const float* __restrict__ bgp, ushort_t* __restrict__ w1bf,
                     float* __restrict__ betaB, float* __restrict__ Gb)
{
    int idx = blockIdx.x * 256 + threadIdx.x;   // over T_*128
    int t = idx >> 7, o = idx & 127;
    if (o >= 96) return;
    float v = s96[(size_t)t * 128 + o];
    if (o < 32) {
        w1bf[(size_t)t * 32 + o] = f2bf(v);
    } else if (o < 64) {
        float xb = v + bbt[o - 32];
        betaB[(size_t)t * H_ + (o - 32)] = 2.f / (1.f + expf(-xb));
    } else {
        float xg = v + bgp[o - 64];
        Gb[(size_t)t * H_ + (o - 64)] =
            (xg >= 0.f) ? -log1pf(expf(-xg)) : (xg - log1pf(expf(xg)));
    }
}

// parallel inclusive scan of G[:, h] per head. Grid (H_), block 256.
__global__ void scan_g(float* __restrict__ G)
{
    int h = blockIdx.x;
    int tid = threadIdx.x;
    __shared__ float psum[256];
    float v[4];
    float s = 0.f;
#pragma unroll
    for (int r = 0; r < 4; r++) {
        v[r] = G[(size_t)(tid * 4 + r) * H_ + h];
        s += v[r];
    }
    psum[tid] = s;
    __syncthreads();
    for (int off = 1; off < 256; off <<= 1) {
        float t = (tid >= off) ? psum[tid - off] : 0.f;
        __syncthreads();
        psum[tid] += t;
        __syncthreads();
    }
    float run = (tid > 0) ? psum[tid - 1] : 0.f;
#pragma unroll
    for (int r = 0; r < 4; r++) {
        run += v[r];
        G[(size_t)(tid * 4 + r) * H_ + h] = run;
    }
}

// conv(3) + silu + l2norm -> wh bf16 head-major [H][T][64]
__global__ void conv_silu_norm(const float* __restrict__ wr, const float* __restrict__ convw,
                               ushort_t* __restrict__ wh)
{
    int b = blockIdx.x;
    int t = b >> 5, h = b & 31;
    int d = threadIdx.x;
    int c = h * 64 + d;
    float c0 = convw[c * 3 + 0];
    float c1 = convw[c * 3 + 1];
    float c2 = convw[c * 3 + 2];
    float x = c2 * wr[(size_t)t * D_ + c];
    if (t >= 1) x += c1 * wr[(size_t)(t - 1) * D_ + c];
    if (t >= 2) x += c0 * wr[(size_t)(t - 2) * D_ + c];
    float y = x / (1.f + expf(-x));
    float ss = y * y;
    for (int off = 32; off > 0; off >>= 1) ss += __shfl_xor(ss, off, 64);
    wh[((size_t)h * T_ + t) * 64 + d] = f2bf(y * rsqrtf(ss));
}

// ---------------------------------------------------------------------------
// pairdotLC: per lower tile (t0,s0):
//   L[t][s]  = strict(w_t.w_s)*beta[s]   (bf16 row-major, into ELb)
//   Ct[s][t] = strict(w_t.k_s)           (bf16 TRANSPOSED [s][t])
// ---------------------------------------------------------------------------
__global__ __launch_bounds__(256) void pairdotLC(
    const ushort_t* __restrict__ kh, const ushort_t* __restrict__ wh,
    const float* __restrict__ betaB,
    ushort_t* __restrict__ ELb, ushort_t* __restrict__ Ct, int hs)
{
    int s0 = blockIdx.x * 64, t0 = blockIdx.y * 64, z = blockIdx.z;
    if (s0 > t0) return;
    int head = hs + z;
    const ushort_t* kb = kh + (size_t)head * T_ * 64;
    const ushort_t* wb = wh + (size_t)head * T_ * 64;
    ushort_t* Lz = ELb + (size_t)z * TT_;
    ushort_t* Cz = Ct + (size_t)z * TT_;
    int tid = threadIdx.x;
    int w = tid >> 6, l = tid & 63;
    int lm = l & 15, kq = l >> 4;
    int rowA = t0 + w * 16 + lm;
    f32x4 accL[4] = {}, accS[4] = {};
#pragma unroll
    for (int kk = 0; kk < 64; kk += 32) {
        frag8 aw = *(const frag8*)&wb[(size_t)rowA * 64 + kk + kq * 8];
#pragma unroll
        for (int j = 0; j < 4; j++) {
            int colr = s0 + j * 16 + lm;
            frag8 bw = *(const frag8*)&wb[(size_t)colr * 64 + kk + kq * 8];
            frag8 bk = *(const frag8*)&kb[(size_t)colr * 64 + kk + kq * 8];
            accL[j] = MFMA16(aw, bw, accL[j]);
            accS[j] = MFMA16(aw, bk, accS[j]);
        }
    }
    int m0 = w * 16 + kq * 4;
#pragma unroll
    for (int j = 0; j < 4; j++) {
        int s = s0 + j * 16 + lm;
        float beta = betaB[(size_t)s * H_ + head];
        ushort_t cl[4];
#pragma unroll
        for (int r = 0; r < 4; r++) {
            int t = t0 + m0 + r;
            Lz[(size_t)t * T_ + s] = f2bf((s < t) ? accL[j][r] * beta : 0.f);
            cl[r] = f2bf((s < t) ? accS[j][r] : 0.f);
        }
        *(u16x4*)&Cz[(size_t)s * T_ + t0 + m0] = *(u16x4*)cl;
    }
}

// pairdotE: Em[t][s] = -causal(q_t.w_s)*beta[s] into ELb (L dead post-solve)
__global__ __launch_bounds__(256) void pairdotE(
    const ushort_t* __restrict__ qh, const ushort_t* __restrict__ wh,
    const float* __restrict__ betaB, ushort_t* __restrict__ ELb, int hs)
{
    int s0 = blockIdx.x * 64, t0 = blockIdx.y * 64, z = blockIdx.z;
    if (s0 > t0) return;
    int head = hs + z;
    const ushort_t* qb = qh + (size_t)head * T_ * 64;
    const ushort_t* wb = wh + (size_t)head * T_ * 64;
    ushort_t* Ez = ELb + (size_t)z * TT_;
    int tid = threadIdx.x;
    int w = tid >> 6, l = tid & 63;
    int lm = l & 15, kq = l >> 4;
    int rowA = t0 + w * 16 + lm;
    f32x4 accE[4] = {};
#pragma unroll
    for (int kk = 0; kk < 64; kk += 32) {
        frag8 aq = *(const frag8*)&qb[(size_t)rowA * 64 + kk + kq * 8];
#pragma unroll
        for (int j = 0; j < 4; j++) {
            frag8 bw = *(const frag8*)&wb[(size_t)(s0 + j * 16 + lm) * 64 + kk + kq * 8];
            accE[j] = MFMA16(aq, bw, accE[j]);
        }
    }
    int m0 = w * 16 + kq * 4;
#pragma unroll
    for (int j = 0; j < 4; j++) {
        int s = s0 + j * 16 + lm;
        float beta = betaB[(size_t)s * H_ + head];
#pragma unroll
        for (int r = 0; r < 4; r++) {
            int t = t0 + m0 + r;
            Ez[(size_t)t * T_ + s] = f2bf((s <= t) ? -accE[j][r] * beta : 0.f);
        }
    }
}

// ---------------------------------------------------------------------------
// diag_inv: invert 64x64 unit-lower diag blocks of (I + L); Minv bf16 out.
// ---------------------------------------------------------------------------
__global__ void diag_inv(const ushort_t* __restrict__ Lb, ushort_t* __restrict__ Minv)
{
    int bi = blockIdx.x, z = blockIdx.y;
    const ushort_t* Lh = Lb + (size_t)z * TT_;
    __shared__ float Nb[64][65];
    __shared__ float Xc[64][65];
    int tid = threadIdx.x;
    for (int i = tid; i < 4096; i += 64) {
        int r = i >> 6, c = i & 63;
        Nb[r][c] = (c < r) ? bf2f(Lh[(size_t)(bi * 64 + r) * T_ + bi * 64 + c]) : 0.f;
    }
    __syncthreads();
    int j = tid;
    for (int t = 0; t < 64; t++) {
        float v = (t == j) ? 1.f : 0.f;
        for (int i = j; i < t; i++) v -= Nb[t][i] * Xc[i][j];
        Xc[t][j] = v;
    }
    __syncthreads();
    ushort_t* Mo = Minv + ((size_t)z * 16 + bi) * 4096;
    for (int i = tid; i < 4096; i += 64) Mo[i] = f2bf(Xc[i >> 6][i & 63]);
}

// ---------------------------------------------------------------------------
// solve_mfma: block-forward solve for one 64-col strip with LDS-staged
// L and C chunks. Grid (16, NH), block 256.
// ---------------------------------------------------------------------------
__global__ __launch_bounds__(256) void solve_mfma(
    ushort_t* __restrict__ Ct, const ushort_t* __restrict__ Lb,
    const ushort_t* __restrict__ Minv)
{
    int ct = blockIdx.x, z = blockIdx.y;
    ushort_t* Cz = Ct + (size_t)z * TT_;
    const ushort_t* Lz = Lb + (size_t)z * TT_;
    __shared__ ushort_t Cl[64][136];
    __shared__ ushort_t Ll[64][136];
    __shared__ ushort_t Xbt[64][72];
    int tid = threadIdx.x;
    int w = tid >> 6, l = tid & 63;
    int lm = l & 15, kq = l >> 4;
    int s0 = ct * 64;
    int m0 = w * 16 + kq * 4;
    for (int bi = ct; bi < 16; bi++) {
        f32x4 acc[4] = {};
        for (int kkc = s0; kkc < bi * 64; kkc += 128) {
            int len = bi * 64 - kkc; if (len > 128) len = 128;
            int lsh = (len == 128) ? 4 : 3;
            __syncthreads();
            for (int i = tid; i < (64 << lsh); i += 256) {
                int r = i >> lsh, c = (i & ((1 << lsh) - 1)) * 8;
                *(u16x8*)&Cl[r][c] = *(const u16x8*)&Cz[(size_t)(s0 + r) * T_ + kkc + c];
                *(u16x8*)&Ll[r][c] = *(const u16x8*)&Lz[(size_t)(bi * 64 + r) * T_ + kkc + c];
            }
            __syncthreads();
            for (int kk2 = 0; kk2 < len; kk2 += 32) {
                frag8 a = *(const frag8*)&Ll[w * 16 + lm][kk2 + kq * 8];
#pragma unroll
                for (int j = 0; j < 4; j++) {
                    frag8 b = *(const frag8*)&Cl[j * 16 + lm][kk2 + kq * 8];
                    acc[j] = MFMA16(a, b, acc[j]);
                }
            }
        }
        __syncthreads();
#pragma unroll
        for (int j = 0; j < 4; j++) {
            int sc = s0 + j * 16 + lm;
            u16x4 rhs = *(const u16x4*)&Cz[(size_t)sc * T_ + bi * 64 + m0];
            ushort_t xb[4];
#pragma unroll
            for (int r = 0; r < 4; r++) xb[r] = f2bf(bf2f(rhs[r]) - acc[j][r]);
            *(u16x4*)&Xbt[j * 16 + lm][m0] = *(u16x4*)xb;
        }
        __syncthreads();
        f32x4 res[4] = {};
        const ushort_t* Mo = Minv + ((size_t)z * 16 + bi) * 4096;
#pragma unroll
        for (int kk = 0; kk < 64; kk += 32) {
            frag8 a = *(const frag8*)&Mo[(size_t)(w * 16 + lm) * 64 + kk + kq * 8];
#pragma unroll
            for (int j = 0; j < 4; j++) {
                frag8 b = *(const frag8*)&Xbt[j * 16 + lm][kk + kq * 8];
                res[j] = MFMA16(a, b, res[j]);
            }
        }
#pragma unroll
        for (int j = 0; j < 4; j++) {
            int sc = s0 + j * 16 + lm;
            ushort_t cr[4];
#pragma unroll
            for (int r = 0; r < 4; r++) cr[r] = f2bf(res[j][r]);
            *(u16x4*)&Cz[(size_t)sc * T_ + bi * 64 + m0] = *(u16x4*)cr;
        }
        __syncthreads();
    }
}

// ---------------------------------------------------------------------------
// flash_split: one (s-tile, t-tile, head) per block; Em precomputed.
//   x = q.k^T + sum_k Em[t,k] C[k,s]; single-tile softmax partial -> Op/ml.
// Grid (16, 16, NH) with st>tb early-out. Block 256.
// ---------------------------------------------------------------------------
__global__ __launch_bounds__(256) void flash_split(
    const ushort_t* __restrict__ qh, const ushort_t* __restrict__ kh,
    const ushort_t* __restrict__ vt, const ushort_t* __restrict__ Em,
    const ushort_t* __restrict__ Ct, const float* __restrict__ Gb,
    ushort_t* __restrict__ Op, float* __restrict__ ml, int hs)
{
    int st = blockIdx.x, tb = blockIdx.y, z = blockIdx.z;
    if (st > tb) return;
    int t0 = tb * 64, s0 = st * 64;
    int head = hs + z;
    const ushort_t* qb = qh + (size_t)head * T_ * 64;
    const ushort_t* kb = kh + (size_t)head * T_ * 64;
    const ushort_t* vb = vt + (size_t)head * 64 * T_;
    const ushort_t* Ez = Em + (size_t)z * TT_;
    const ushort_t* Cz = Ct + (size_t)z * TT_;
    __shared__ ushort_t Kl[64][72];
    __shared__ ushort_t Vl[64][72];
    __shared__ ushort_t El[64][72];
    __shared__ ushort_t Cl[64][72];
    __shared__ ushort_t Pl[4][16][76];
    int tid = threadIdx.x;
    int w = tid >> 6, l = tid & 63;
    int lm = l & 15, kq = l >> 4;
    int rowA = t0 + w * 16 + lm;
    int m0 = w * 16 + kq * 4;
    for (int i = tid; i < 512; i += 256) {
        int r = i >> 3, c = (i & 7) * 8;
        *(u16x8*)&Kl[r][c] = *(const u16x8*)&kb[(size_t)(s0 + r) * 64 + c];
        *(u16x8*)&Vl[r][c] = *(const u16x8*)&vb[(size_t)r * T_ + s0 + c];
    }
    frag8 aq0 = *(const frag8*)&qb[(size_t)rowA * 64 + kq * 8];
    frag8 aq1 = *(const frag8*)&qb[(size_t)rowA * 64 + 32 + kq * 8];
    __syncthreads();
    f32x4 x[4] = {};
#pragma unroll
    for (int j = 0; j < 4; j++) {
        frag8 b0 = *(const frag8*)&Kl[j * 16 + lm][kq * 8];
        frag8 b1 = *(const frag8*)&Kl[j * 16 + lm][32 + kq * 8];
        x[j] = MFMA16(aq0, b0, x[j]);
        x[j] = MFMA16(aq1, b1, x[j]);
    }
    // correction: x += sum over k-chunks of Em(t,k) * C(k,s)
    for (int kc = s0; kc < t0 + 64; kc += 64) {
        __syncthreads();
        for (int i = tid; i < 512; i += 256) {
            int r = i >> 3, c = (i & 7) * 8;
            *(u16x8*)&El[r][c] = *(const u16x8*)&Ez[(size_t)(t0 + r) * T_ + kc + c];
            *(u16x8*)&Cl[r][c] = *(const u16x8*)&Cz[(size_t)(s0 + r) * T_ + kc + c];
        }
        __syncthreads();
#pragma unroll
        for (int kk2 = 0; kk2 < 64; kk2 += 32) {
            frag8 a = *(const frag8*)&El[w * 16 + lm][kk2 + kq * 8];
#pragma unroll
            for (int j = 0; j < 4; j++) {
                frag8 b = *(const frag8*)&Cl[j * 16 + lm][kk2 + kq * 8];
                x[j] = MFMA16(a, b, x[j]);
            }
        }
    }
    // single-tile softmax partial
    float lg[4][4];
#pragma unroll
    for (int j = 0; j < 4; j++) {
        int s = s0 + j * 16 + lm;
        float g = Gb[(size_t)s * H_ + head];
#pragma unroll
        for (int r = 0; r < 4; r++) {
            int t = t0 + m0 + r;
            lg[j][r] = (s <= t) ? (x[j][r] * 0.125f - g) : -1e30f;
        }
    }
    float mrow[4];
#pragma unroll
    for (int r = 0; r < 4; r++)
        mrow[r] = fmaxf(fmaxf(lg[0][r], lg[1][r]), fmaxf(lg[2][r], lg[3][r]));
#pragma unroll
    for (int d = 1; d < 16; d <<= 1)
#pragma unroll
        for (int r = 0; r < 4; r++) mrow[r] = fmaxf(mrow[r], __shfl_xor(mrow[r], d, 64));
    float lrow[4] = {0.f, 0.f, 0.f, 0.f};
#pragma unroll
    for (int j = 0; j < 4; j++)
#pragma unroll
        for (int r = 0; r < 4; r++) {
            float p = __expf(lg[j][r] - mrow[r]);
            lg[j][r] = p;
            lrow[r] += p;
        }
#pragma unroll
    for (int d = 1; d < 16; d <<= 1)
#pragma unroll
        for (int r = 0; r < 4; r++) lrow[r] += __shfl_xor(lrow[r], d, 64);
    // P -> per-wave slab (same-wave ordering), O = P @ V
#pragma unroll
    for (int j = 0; j < 4; j++)
#pragma unroll
        for (int r = 0; r < 4; r++)
            Pl[w][kq * 4 + r][j * 16 + lm] = f2bf(lg[j][r]);
    f32x4 o[4] = {};
#pragma unroll
    for (int j = 0; j < 4; j++) {
        frag8 b0 = *(const frag8*)&Vl[j * 16 + lm][kq * 8];
        frag8 b1 = *(const frag8*)&Vl[j * 16 + lm][32 + kq * 8];
        frag8 a0 = *(const frag8*)&Pl[w][lm][kq * 8];
        frag8 a1 = *(const frag8*)&Pl[w][lm][32 + kq * 8];
        o[j] = MFMA16(a0, b0, o[j]);
        o[j] = MFMA16(a1, b1, o[j]);
    }
    size_t pbase = (((size_t)z * 16 + tb) * 16 + st) * 4096;
#pragma unroll
    for (int j = 0; j < 4; j++)
#pragma unroll
        for (int r = 0; r < 4; r++)
            Op[pbase + (size_t)(m0 + r) * 64 + j * 16 + lm] = f2bf(o[j][r]);
    if (lm == 0) {
        size_t mbase = (((size_t)z * 16 + tb) * 16 + st) * 128;
#pragma unroll
        for (int r = 0; r < 4; r++) {
            ml[mbase + m0 + r] = mrow[r];
            ml[mbase + 64 + m0 + r] = lrow[r];
        }
    }
}

// ---------------------------------------------------------------------------
// combine: merge <=16 partials per (t-tile, head) -> of bf16.
// ---------------------------------------------------------------------------
__global__ __launch_bounds__(256) void combine(
    const ushort_t* __restrict__ Op, const float* __restrict__ ml,
    ushort_t* __restrict__ of, int hs)
{
    int tb = blockIdx.x, z = blockIdx.y;
    int head = hs + z;
    int tid = threadIdx.x;
    int row = tid >> 2, cg = (tid & 3) * 16;
    size_t mb0 = (((size_t)z * 16 + tb) * 16) * 128;
    float M = -1e30f;
    for (int st = 0; st <= tb; st++)
        M = fmaxf(M, ml[mb0 + (size_t)st * 128 + row]);
    float acc[16] = {};
    float lsum = 0.f;
    for (int st = 0; st <= tb; st++) {
        float mp = ml[mb0 + (size_t)st * 128 + row];
        float lp = ml[mb0 + (size_t)st * 128 + 64 + row];
        float sc = __expf(mp - M);
        lsum += lp * sc;
        const ushort_t* op = Op + (((size_t)z * 16 + tb) * 16 + st) * 4096 + (size_t)row * 64 + cg;
#pragma unroll
        for (int i = 0; i < 16; i++) acc[i] += bf2f(op[i]) * sc;
    }
    float inv = 1.f / lsum;
    int t = tb * 64 + row;
    ushort_t* dst = of + (size_t)t * D_ + (size_t)head * 64 + cg;
#pragma unroll
    for (int i = 0; i < 16; i++) dst[i] = f2bf(acc[i] * inv);
}

// ---------------------------------------------------------------------------
extern "C" void kernel_launch(void* const* d_in, const int* in_sizes, int n_in,
                              void* d_out, int out_size, void* d_ws, size_t ws_size,
                              hipStream_t stream)
{
    const float* h     = (const float*)d_in[0];
    const float* Wq    = (const float*)d_in[1];
    const float* Wk    = (const float*)d_in[2];
    const float* Wv    = (const float*)d_in[3];
    const float* Ww1   = (const float*)d_in[4];
    const float* Ww2   = (const float*)d_in[5];
    const float* convw = (const float*)d_in[6];
    const float* Wbt   = (const float*)d_in[7];
    const float* bbt   = (const float*)d_in[8];
    const float* Wg    = (const float*)d_in[9];
    const float* bgp   = (const float*)d_in[10];
    const float* Wo    = (const float*)d_in[11];
    float* out = (float*)d_out;

    float* ws = (float*)d_ws;
    size_t off = 0;
    auto allocF = [&](size_t nf) { float* p = ws + off; off += (nf + 1023) & ~(size_t)1023; return p; };

    float*    wr    = allocF(TD_);
    float*    s96   = allocF((size_t)T_ * 128);
    float*    betaB = allocF((size_t)T_ * H_);
    float*    Gb    = allocF((size_t)T_ * H_);
    ushort_t* h_bf  = (ushort_t*)allocF(TD_ / 2);   // reused as of_bf after QKV GEMM
    ushort_t* of_bf = h_bf;
    ushort_t* w1bf  = (ushort_t*)allocF((size_t)T_ * 32 / 2);
    ushort_t* Ww2t  = (ushort_t*)allocF((size_t)D_ * 32 / 2);
    ushort_t* Wtc   = (ushort_t*)allocF((size_t)6272 * D_ / 2);  // QKV + 96-pack; reused for Wo
    ushort_t* qkv   = (ushort_t*)allocF((size_t)3 * TD_ / 2);
    ushort_t* qh    = qkv;
    ushort_t* kh    = qkv + TD_;
    ushort_t* vt    = qkv + 2 * TD_;
    ushort_t* wh    = (ushort_t*)allocF(TD_ / 2);

    size_t fixedF = off;
    size_t capF = ws_size / 4;
    // perHead: ELb (L then Em) + Ct + Op (all TT_ bf16) + Mv + ml
    size_t perHead = 3 * (TT_ / 2) + ((size_t)16 * 4096) / 2 + (size_t)16 * 16 * 128 + 3072;
    int NH = 32;
    while (NH > 1 && fixedF + (size_t)NH * perHead > capF) NH >>= 1;
    ushort_t* ELb = (ushort_t*)allocF((size_t)NH * TT_ / 2);  // L, then Em
    ushort_t* Ct  = (ushort_t*)allocF((size_t)NH * TT_ / 2);
    ushort_t* OpB = (ushort_t*)allocF((size_t)NH * TT_ / 2);
    ushort_t* Mv  = (ushort_t*)allocF((size_t)NH * 16 * 4096 / 2);
    float*    mlB = allocF((size_t)NH * 16 * 16 * 128);

    dim3 blk(256);
    dim3 tcvB(32, 8);
    dim3 tcvG(D_ / 32, D_ / 32);

    // fused QKV + 96-proj via one MFMA GEMM (N = 6272)
    convert_bf16<<<dim3((TD_ + 255) / 256), blk, 0, stream>>>(h, h_bf, (int)TD_);
    transpose_convert<<<tcvG, tcvB, 0, stream>>>(Wq, Wtc, D_, D_);
    transpose_convert<<<tcvG, tcvB, 0, stream>>>(Wk, Wtc + (size_t)D_ * D_, D_, D_);
    transpose_convert<<<tcvG, tcvB, 0, stream>>>(Wv, Wtc + (size_t)2 * D_ * D_, D_, D_);
    pack96<<<dim3(128, 8), blk, 0, stream>>>(Ww1, Wbt, Wg, Wtc + (size_t)3 * D_ * D_);
    mfma_gemm<3><<<dim3(6272 / 128, T_ / 128), blk, 0, stream>>>(
        h_bf, Wtc, qkv, s96, T_, 6272, D_);

    // gates + w path
    bg96<<<dim3(T_ * 128 / 256), blk, 0, stream>>>(s96, bbt, bgp, w1bf, betaB, Gb);
    scan_g<<<dim3(H_), blk, 0, stream>>>(Gb);
    transpose_convert<<<dim3(D_ / 32, 1), tcvB, 0, stream>>>(Ww2, Ww2t, 32, D_);
    mfma_gemm<0><<<dim3(D_ / 128, T_ / 128), blk, 0, stream>>>(
        w1bf, Ww2t, wr, nullptr, T_, D_, 32);
    conv_silu_norm<<<dim3(T_ * H_), dim3(64), 0, stream>>>(wr, convw, wh);

    int nChunks = H_ / NH;
    for (int c = 0; c < nChunks; c++) {
        int hs = c * NH;
        pairdotLC<<<dim3(16, 16, NH), blk, 0, stream>>>(kh, wh, betaB, ELb, Ct, hs);
        diag_inv<<<dim3(16, NH), dim3(64), 0, stream>>>(ELb, Mv);
        solve_mfma<<<dim3(16, NH), blk, 0, stream>>>(Ct, ELb, Mv);
        pairdotE<<<dim3(16, 16, NH), blk, 0, stream>>>(qh, wh, betaB, ELb, hs);
        flash_split<<<dim3(16, 16, NH), blk, 0, stream>>>(
            qh, kh, vt, ELb, Ct, Gb, OpB, mlB, hs);
        combine<<<dim3(16, NH), blk, 0, stream>>>(OpB, mlB, of_bf, hs);
    }

    // out = of @ Wo via MFMA
    transpose_convert<<<tcvG, tcvB, 0, stream>>>(Wo, Wtc, D_, D_);
    mfma_gemm<0><<<dim3(D_ / 128, T_ / 128), blk, 0, stream>>>(
        of_bf, Wtc, out, nullptr, T_, D_, D_);
}